// Round 7
// baseline (545.980 us; speedup 1.0000x reference)
//
#include <hip/hip_runtime.h>
#include <cstdint>
#include <cstddef>

typedef _Float16 half8  __attribute__((ext_vector_type(8)));
typedef _Float16 half4v __attribute__((ext_vector_type(4)));
typedef float    f32x4  __attribute__((ext_vector_type(4)));

static constexpr int HWPX = 1024;
static constexpr int NPX  = 16384;
static constexpr int DBB  = 768;
static constexpr int DD   = 512;
static constexpr int KC   = 201;
static constexpr int KM   = 2010;   // KC * 10
static constexpr int KMP  = 2048;   // padded

// ---- workspace offsets (bytes) ----
static constexpr size_t OFF_XCH    = 0;        // [10][8][768] f64 W partials
static constexpr size_t OFF_TP     = 491520;   // [10][8] f64 T partials
static constexpr size_t OFF_COLP   = 492160;   // [8][768] f64 colsum partials
static constexpr size_t OFF_ROW16  = 541312;   // [16][2016] f32
static constexpr size_t OFF_ROW3   = 670336;   // [2016] f32
static constexpr size_t OFF_ROW5   = 678400;   // [2016] f32
static constexpr size_t OFF_BK     = 686464;   // 256 i32
static constexpr size_t OFF_NCNT   = 687488;   // 2016 i32
static constexpr size_t OFF_DONE   = 695552;   // 16 i32 per-pass done counters
static constexpr size_t OFF_FPROTO = 695616;   // 2010*512 f32
static constexpr size_t ZTOTAL     = 4812096;  // single memset covers all above
static constexpr size_t OFF_VSF    = 4812096;  // [10][768] f64 finalized vs per pass
static constexpr size_t OFF_MFIN   = 4873536;  // 768 f64 final mean
static constexpr size_t OFF_SSC    = 4879680;  // 8 f64 (s scalar)
static constexpr size_t OFF_GTSEG  = 4879744;  // 16384 i32
static constexpr size_t OFF_CORR   = 4945280;  // 16384 i32
static constexpr size_t OFF_U      = 5010816;  // 16384 f64
static constexpr size_t OFF_PN     = 5141888;  // 2010*512 f32
static constexpr size_t OFF_P16    = 9258368;  // 2048*512 f16
static constexpr size_t OFF_C16    = 11355520; // 16384*512 f16
static constexpr size_t OFF_QD     = 28132736; // 16384*10 f32
static constexpr size_t OFF_W16    = 28788096; // 512*768 f16

// ---- d_out offsets (floats) ----
static constexpr size_t OUT_SEG = 0;
static constexpr size_t OUT_PL  = 3293184;
static constexpr size_t OUT_PT  = 36225024;
static constexpr size_t OUT_PG  = 36241408;
static constexpr size_t OUT_NP  = 36257792;

#define GLDS16(gp, lp) __builtin_amdgcn_global_load_lds( \
    (__attribute__((address_space(1))) const void*)(gp), \
    (__attribute__((address_space(3))) void*)(lp), 16, 0, 0)

static __device__ __forceinline__ float  wredf(float x){
  #pragma unroll
  for (int o=32;o;o>>=1) x += __shfl_down(x,o);
  return x;
}
static __device__ __forceinline__ double wredd(double x){
  #pragma unroll
  for (int o=32;o;o>>=1) x += __shfl_down(x,o);
  return x;
}

// ================= PCA =================
// y = Ac^T Ac x = A^T(Ax) - m*sum(Ax)  (exact for any x).  Blocks accumulate 8 partial
// buffers; the LAST block (done-counter) reduces them once, applies the mean correction,
// and writes the 6KB vs vector for the next pass.  FIRST pass also accumulates colsums
// (x0 = const) and finalizes m.  LASTP pass also precomputes s = m.v for the u-pass.
// Un-normalized iteration is direction-equivalent (f64 iterates peak ~1e44 << f64 range).
template<bool FIRST, bool LASTP>
__global__ __launch_bounds__(256) void kPIter3(const float* __restrict__ A,
    const double* __restrict__ vsin, double* __restrict__ mfin,
    double* __restrict__ Wout, double* __restrict__ Tout, double* __restrict__ colout,
    double* __restrict__ vsout, double* __restrict__ sout, int* __restrict__ donecnt){
  __shared__ double vs[768];
  __shared__ double red[4][12][64];
  __shared__ double sT[4];
  __shared__ double sTs;
  __shared__ int isLast;
  int tid=threadIdx.x, lane=tid&63, w=tid>>6;
  if (FIRST){
    for (int cc=tid; cc<768; cc+=256) vs[cc] = 1.0/sqrt(768.0);
  } else {
    for (int cc=tid; cc<768; cc+=256) vs[cc] = vsin[cc];
  }
  __syncthreads();
  int rbase = blockIdx.x*16 + w*4;
  double acc[12], cacc[12]; double tloc=0.0;
  #pragma unroll
  for (int j=0;j<12;j++){ acc[j]=0.0; cacc[j]=0.0; }
  for (int i=0;i<4;i++){
    const float* Ar = A + (size_t)(rbase+i)*DBB;
    double a[12]; double wp=0.0;
    #pragma unroll
    for (int j=0;j<12;j++){ int c=j*64+lane; a[j]=(double)Ar[c]; wp += a[j]*vs[c]; }
    wp = wredd(wp); wp = __shfl(wp,0);
    #pragma unroll
    for (int j=0;j<12;j++) acc[j] += wp*a[j];
    if (FIRST){
      #pragma unroll
      for (int j=0;j<12;j++) cacc[j] += a[j];
    }
    tloc += wp;
  }
  #pragma unroll
  for (int j=0;j<12;j++) red[w][j][lane]=acc[j];
  if (lane==0) sT[w]=tloc;
  __syncthreads();
  double* dst = Wout + (size_t)(blockIdx.x&7)*768;
  for (int cc=tid; cc<768; cc+=256){
    int j=cc>>6, l=cc&63;
    atomicAdd(&dst[cc], red[0][j][l]+red[1][j][l]+red[2][j][l]+red[3][j][l]);
  }
  if (tid==0) atomicAdd(&Tout[blockIdx.x&7], sT[0]+sT[1]+sT[2]+sT[3]);
  if (FIRST){
    __syncthreads();
    #pragma unroll
    for (int j=0;j<12;j++) red[w][j][lane]=cacc[j];
    __syncthreads();
    double* cdst = colout + (size_t)(blockIdx.x&7)*768;
    for (int cc=tid; cc<768; cc+=256){
      int j=cc>>6, l=cc&63;
      atomicAdd(&cdst[cc], red[0][j][l]+red[1][j][l]+red[2][j][l]+red[3][j][l]);
    }
  }
  // ---- last-block finalize ----
  if (tid==0){
    __threadfence();
    int prev = atomicAdd(donecnt, 1);
    isLast = (prev == (int)gridDim.x - 1);
  }
  __syncthreads();
  if (!isLast) return;
  if (tid==0){
    double Ts=0.0;
    #pragma unroll
    for (int p=0;p<8;p++) Ts += atomicAdd(&Tout[p], 0.0);   // coherent read
    sTs = Ts;
  }
  __syncthreads();
  double Ts = sTs;
  double sloc = 0.0;
  for (int cc=tid; cc<768; cc+=256){
    double sw=0.0;
    #pragma unroll
    for (int p=0;p<8;p++) sw += atomicAdd(&Wout[p*768+cc], 0.0);  // coherent read
    double m;
    if (FIRST){
      double mc=0.0;
      #pragma unroll
      for (int p=0;p<8;p++) mc += atomicAdd(&colout[p*768+cc], 0.0);
      m = mc*(1.0/16384.0);
      mfin[cc] = m;
    } else {
      m = mfin[cc];   // written by pass0's kernel -> visible (kernel boundary)
    }
    double v = sw - m*Ts;
    vsout[cc] = v;
    if (LASTP) sloc += m*v;
  }
  if (LASTP){
    sloc = wredd(sloc);
    if (lane==0) sT[w]=sloc;
    __syncthreads();
    if (tid==0) sout[0] = sT[0]+sT[1]+sT[2]+sT[3];
  }
}

// u = Ac v = A v - (m.v):  vs and s precomputed by pass 9's last block.
__global__ __launch_bounds__(256) void kPU3(const float* __restrict__ A,
    const double* __restrict__ vsin, const double* __restrict__ ssc, double* __restrict__ u){
  __shared__ double vs[768];
  int tid=threadIdx.x, lane=tid&63, w=tid>>6;
  for (int cc=tid; cc<768; cc+=256) vs[cc] = vsin[cc];
  __syncthreads();
  double s = ssc[0];
  int rbase = blockIdx.x*16 + w*4;
  for (int i=0;i<4;i++){
    const float* Ar = A + (size_t)(rbase+i)*DBB;
    double wp=0.0;
    #pragma unroll
    for (int j=0;j<12;j++){ int c=j*64+lane; wp += (double)Ar[c]*vs[c]; }
    wp = wredd(wp);
    if (lane==0) u[rbase+i] = wp - s;
  }
}

// fused global minmax + pseudo-gt + Bk (single block)
__global__ __launch_bounds__(1024) void kFin(const double* __restrict__ u, const int* __restrict__ gt,
      float* __restrict__ outPG, int* __restrict__ gtseg, int* __restrict__ Bk){
  __shared__ double smn[16], smx[16];
  __shared__ double sres[2];
  int t = threadIdx.x;
  double mn=1e300, mx=-1e300;
  for (int k=0;k<16;k++){ double x=u[k*1024+t]; mn=fmin(mn,x); mx=fmax(mx,x); }
  #pragma unroll
  for (int o=32;o;o>>=1){ mn=fmin(mn,__shfl_down(mn,o)); mx=fmax(mx,__shfl_down(mx,o)); }
  if ((t&63)==0){ smn[t>>6]=mn; smx[t>>6]=mx; }
  __syncthreads();
  if (t==0){
    for (int i=1;i<16;i++){ mn=fmin(mn,smn[i]); mx=fmax(mx,smx[i]); }
    sres[0]=mn; sres[1]=mx;
  }
  __syncthreads();
  mn=sres[0]; mx=sres[1];
  double inv = 1.0/(mx-mn);
  for (int k=0;k<16;k++){
    int n = k*1024 + t;
    int c0 = gt[k];
    double us = (u[n]-mn)*inv;
    int g = (us < 0.5) ? c0 : 200;
    outPG[n] = (float)g;
    gtseg[n] = g;
    unsigned long long b0 = __ballot(g==c0);
    unsigned long long b1 = __ballot(g==200);
    if ((t&63)==0){
      atomicAdd(&Bk[c0], (int)__popcll(b0));
      atomicAdd(&Bk[200], (int)__popcll(b1));
    }
  }
}

// ================= prep: W f32->f16 (blocks 0..383) + proto l2-normalize (blocks 384..895) =================
__global__ __launch_bounds__(256) void kPrep(const float* __restrict__ Wp, _Float16* __restrict__ W16,
    const float* __restrict__ PR, float* __restrict__ Pn, _Float16* __restrict__ P16){
  int b = blockIdx.x;
  if (b < 384){
    int i = b*256 + threadIdx.x;
    float4 vv = ((const float4*)Wp)[i];
    half4v h; h[0]=(_Float16)vv.x; h[1]=(_Float16)vv.y; h[2]=(_Float16)vv.z; h[3]=(_Float16)vv.w;
    ((half4v*)W16)[i] = h;
    return;
  }
  int w=threadIdx.x>>6, lane=threadIdx.x&63;
  int km = (b-384)*4 + w;
  if (km >= KM){
    if (km < KMP){
      half8 z;
      #pragma unroll
      for (int i=0;i<8;i++) z[i]=(_Float16)0.0f;
      *(half8*)(P16 + (size_t)km*DD + lane*8) = z;
    }
    return;
  }
  const float* r = PR + (size_t)km*DD + lane*8;
  float4 a = *(const float4*)r, b2 = *(const float4*)(r+4);
  float x[8] = {a.x,a.y,a.z,a.w,b2.x,b2.y,b2.z,b2.w};
  float ss=0;
  #pragma unroll
  for (int i=0;i<8;i++) ss += x[i]*x[i];
  ss = __shfl(wredf(ss),0);
  float nrm = fmaxf(sqrtf(ss), 1e-12f);
  float* pw = Pn + (size_t)km*DD + lane*8;
  half8 h;
  #pragma unroll
  for (int i=0;i<8;i++){ float vv = x[i]/nrm; pw[i]=vv; h[i]=(_Float16)vv; }
  *(half8*)(P16 + (size_t)km*DD + lane*8) = h;
}

// ================= GEMM1: C16[16384,512] = f16( A_f32 @ W16^T + b ) =================
__global__ __launch_bounds__(256) void gemm1(const float* __restrict__ Af, const _Float16* __restrict__ Bm,
    _Float16* __restrict__ Ch, const float* __restrict__ bias){
  __shared__ __align__(16) char As[128*128];
  __shared__ __align__(16) char Bs[128*128];
  const int tid = threadIdx.x;
  const int lane = tid & 63, w = tid >> 6;
  const int wr = w >> 1, wc = w & 1;
  const int lrow = lane & 15, kg = lane >> 4;
  const int id = blockIdx.x;
  const int xcd = id & 7, pos = id >> 3;
  const int m0 = ((xcd<<4) | (pos>>2)) * 128;
  const int n0 = (pos & 3) * 128;

  f32x4 acc[4][4];
  #pragma unroll
  for (int i=0;i<4;i++)
    #pragma unroll
    for (int j=0;j<4;j++){ f32x4 z = {0.f,0.f,0.f,0.f}; acc[i][j]=z; }

  for (int k0 = 0; k0 < DBB; k0 += 64){
    #pragma unroll
    for (int i=0;i<4;i++){
      int slot = (i*4 + w)*64 + lane;
      int r = slot >> 3, c = slot & 7;
      int cs = c ^ (r & 7);
      GLDS16(Bm + (size_t)(n0+r)*DBB + k0 + cs*8, Bs + (i*4+w)*1024);
    }
    #pragma unroll
    for (int i=0;i<8;i++){
      int slot = i*256 + tid;
      int r = slot >> 4, c4 = slot & 15;
      float4 v = *(const float4*)(Af + (size_t)(m0+r)*DBB + k0 + c4*4);
      half4v h; h[0]=(_Float16)v.x; h[1]=(_Float16)v.y; h[2]=(_Float16)v.z; h[3]=(_Float16)v.w;
      *(half4v*)(As + r*128 + (((c4>>1)^(r&7))<<4) + (c4&1)*8) = h;
    }
    __syncthreads();
    #pragma unroll
    for (int h=0; h<2; h++){
      half8 af[4], bf[4];
      #pragma unroll
      for (int mi=0;mi<4;mi++){
        int ar = wr*64 + mi*16 + lrow;
        af[mi] = *(const half8*)(As + ar*128 + (((h*4+kg) ^ (ar&7))<<4));
      }
      #pragma unroll
      for (int nj=0;nj<4;nj++){
        int br = wc*64 + nj*16 + lrow;
        bf[nj] = *(const half8*)(Bs + br*128 + (((h*4+kg) ^ (br&7))<<4));
      }
      #pragma unroll
      for (int mi=0;mi<4;mi++)
        #pragma unroll
        for (int nj=0;nj<4;nj++)
          acc[mi][nj] = __builtin_amdgcn_mfma_f32_16x16x32_f16(af[mi], bf[nj], acc[mi][nj], 0,0,0);
    }
    __syncthreads();
  }
  #pragma unroll
  for (int mi=0;mi<4;mi++){
    int gr = m0 + wr*64 + mi*16 + kg*4;
    #pragma unroll
    for (int nj=0;nj<4;nj++){
      int gc = n0 + wc*64 + nj*16 + lrow;
      float bv = bias[gc];
      #pragma unroll
      for (int r2=0;r2<4;r2++)
        Ch[(size_t)(gr+r2)*DD + gc] = (_Float16)(acc[mi][nj][r2] + bv);
    }
  }
}

// ================= GEMM2: PL[16384,2010] = _c @ protos^T =================
__global__ __launch_bounds__(256) void gemm2(const _Float16* __restrict__ Am, const _Float16* __restrict__ Bm,
    float* __restrict__ Cf){
  __shared__ __align__(16) char As[128*128];
  __shared__ __align__(16) char Bs[128*128];
  const int tid = threadIdx.x;
  const int lane = tid & 63, w = tid >> 6;
  const int wr = w >> 1, wc = w & 1;
  const int lrow = lane & 15, kg = lane >> 4;
  const int id = blockIdx.x;
  const int xcd = id & 7, pos = id >> 3;
  const int m0 = ((xcd<<4) | (pos>>4)) * 128;
  const int n0 = (pos & 15) * 128;

  f32x4 acc[4][4];
  #pragma unroll
  for (int i=0;i<4;i++)
    #pragma unroll
    for (int j=0;j<4;j++){ f32x4 z = {0.f,0.f,0.f,0.f}; acc[i][j]=z; }

  for (int k0 = 0; k0 < DD; k0 += 64){
    #pragma unroll
    for (int i=0;i<4;i++){
      int slot = (i*4 + w)*64 + lane;
      int r = slot >> 3, c = slot & 7;
      int cs = c ^ (r & 7);
      GLDS16(Am + (size_t)(m0+r)*DD + k0 + cs*8, As + (i*4+w)*1024);
      GLDS16(Bm + (size_t)(n0+r)*DD + k0 + cs*8, Bs + (i*4+w)*1024);
    }
    __syncthreads();
    #pragma unroll
    for (int h=0; h<2; h++){
      half8 af[4], bf[4];
      #pragma unroll
      for (int mi=0;mi<4;mi++){
        int ar = wr*64 + mi*16 + lrow;
        af[mi] = *(const half8*)(As + ar*128 + (((h*4+kg) ^ (ar&7))<<4));
      }
      #pragma unroll
      for (int nj=0;nj<4;nj++){
        int br = wc*64 + nj*16 + lrow;
        bf[nj] = *(const half8*)(Bs + br*128 + (((h*4+kg) ^ (br&7))<<4));
      }
      #pragma unroll
      for (int mi=0;mi<4;mi++)
        #pragma unroll
        for (int nj=0;nj<4;nj++)
          acc[mi][nj] = __builtin_amdgcn_mfma_f32_16x16x32_f16(af[mi], bf[nj], acc[mi][nj], 0,0,0);
    }
    __syncthreads();
  }
  #pragma unroll
  for (int mi=0;mi<4;mi++){
    int gr = m0 + wr*64 + mi*16 + kg*4;
    #pragma unroll
    for (int nj=0;nj<4;nj++){
      int gc = n0 + wc*64 + nj*16 + lrow;
      if (gc < KM){
        #pragma unroll
        for (int r2=0;r2<4;r2++)
          Cf[(size_t)(gr+r2)*KM + gc] = acc[mi][nj][r2];
      }
    }
  }
}

// ================= LN + l2 normalize (in-place on C16) =================
__global__ __launch_bounds__(256) void kLNl2n(_Float16* __restrict__ C16,
      const float* __restrict__ fg, const float* __restrict__ fb){
  int w=threadIdx.x>>6, lane=threadIdx.x&63;
  int n = blockIdx.x*4 + w;
  _Float16* row = C16 + (size_t)n*DD + lane*8;
  half8 h = *(const half8*)row;
  float x[8];
  #pragma unroll
  for (int i=0;i<8;i++) x[i] = (float)h[i];
  float s=0;
  #pragma unroll
  for (int i=0;i<8;i++) s += x[i];
  float mu = __shfl(wredf(s),0)/512.f;
  float q=0;
  #pragma unroll
  for (int i=0;i<8;i++){ float d=x[i]-mu; q+=d*d; }
  float var = __shfl(wredf(q),0)/512.f;
  float inv = 1.f/sqrtf(var+1e-5f);
  float4 g0 = *(const float4*)(fg+lane*8), g1 = *(const float4*)(fg+lane*8+4);
  float4 b0 = *(const float4*)(fb+lane*8), b1 = *(const float4*)(fb+lane*8+4);
  float gg[8] = {g0.x,g0.y,g0.z,g0.w,g1.x,g1.y,g1.z,g1.w};
  float bb[8] = {b0.x,b0.y,b0.z,b0.w,b1.x,b1.y,b1.z,b1.w};
  float y[8]; float ss=0;
  #pragma unroll
  for (int i=0;i<8;i++){ y[i] = (x[i]-mu)*inv*gg[i]+bb[i]; ss += y[i]*y[i]; }
  float nrm = fmaxf(sqrtf(__shfl(wredf(ss),0)), 1e-12f);
  half8 o;
  #pragma unroll
  for (int i=0;i<8;i++) o[i] = (_Float16)(y[i]/nrm);
  *(half8*)row = o;
}

// ===== fused per-class max + mask LN + pred + transpose-out + sinkhorn Qd/row0 partials =====
// 1024 blocks x 16 rows.  Phase A: thread = class (tid<201), 10 contiguous cosines in regs.
__global__ __launch_bounds__(256) void kMaxSK(const float* __restrict__ PL, const float* __restrict__ mg,
    const float* __restrict__ mb, const int* __restrict__ gtseg, const int* __restrict__ gt,
    float* __restrict__ outseg, int* __restrict__ corr, float* __restrict__ Qd, float* __restrict__ row16){
  __shared__ float tile[16][205];
  __shared__ float qpart[10][2];
  int tid=threadIdx.x, lane=tid&63, w=tid>>6;
  int n0 = blockIdx.x*16;
  int b = n0>>10, hw0 = n0&1023;
  int c0 = gt[b];
  if (tid<20) qpart[tid>>1][tid&1]=0.f;
  __syncthreads();
  for (int r=0;r<16;r++){
    int n = n0 + r;
    int g = gtseg[n];
    if (tid < KC){
      const float* src = PL + (size_t)n*KM + tid*10;
      float v[10];
      #pragma unroll
      for (int m2=0;m2<5;m2++){
        float2 t2 = *(const float2*)(src + m2*2);
        v[m2*2]=t2.x; v[m2*2+1]=t2.y;
      }
      float mx = v[0];
      #pragma unroll
      for (int m=1;m<10;m++) mx = fmaxf(mx,v[m]);
      tile[r][tid] = mx;
      if (tid == g){
        int cl = (g==200)?1:0;
        #pragma unroll
        for (int m=0;m<10;m++){
          float e = expf(v[m]*20.f);
          Qd[(size_t)n*10+m] = e;
          atomicAdd(&qpart[m][cl], e);
        }
      }
    }
  }
  __syncthreads();
  for (int rr=0; rr<4; ++rr){
    int r = w*4 + rr;
    int n = n0 + r;
    float xv[4]; int ncl=0;
    for (int c=lane;c<KC;c+=64) xv[ncl++] = tile[r][c];
    float ps=0;
    for (int i=0;i<ncl;i++) ps += xv[i];
    float mu = __shfl(wredf(ps),0)*(1.f/201.f);
    float pv=0;
    for (int i=0;i<ncl;i++){ float d=xv[i]-mu; pv+=d*d; }
    float var = __shfl(wredf(pv),0)*(1.f/201.f);
    float inv = 1.f/sqrtf(var+1e-5f);
    float bv=-3.0e38f; int bi=1<<30;
    ncl=0;
    for (int c=lane;c<KC;c+=64){
      float o = (xv[ncl]-mu)*inv*mg[c]+mb[c]; ncl++;
      tile[r][c] = o;
      if (o>bv){ bv=o; bi=c; }
    }
    #pragma unroll
    for (int o2=32;o2;o2>>=1){
      float ov=__shfl_down(bv,o2); int oi=__shfl_down(bi,o2);
      if (ov>bv||(ov==bv&&oi<bi)){bv=ov;bi=oi;}
    }
    if (lane==0) corr[n] = (bi==gtseg[n])?1:0;
  }
  __syncthreads();
  if (tid<20){
    int m=tid>>1, cl=tid&1;
    atomicAdd(&row16[(size_t)(blockIdx.x&15)*2016 + m*KC + (cl?200:c0)], qpart[m][cl]);
  }
  for (int idx=tid; idx<KC*16; idx+=256){
    int c=idx>>4, j=idx&15;
    outseg[(((size_t)b*KC+c)<<10) + hw0 + j] = tile[j][c];
  }
}

// one sinkhorn iteration; rin has rin_parts partial buffers of stride 2016
__global__ __launch_bounds__(256) void kSKpass(float* __restrict__ Qd, const int* __restrict__ gtseg,
      const int* __restrict__ gt, const float* __restrict__ rin, int rin_parts,
      float* __restrict__ rout, const int* __restrict__ Bk){
  __shared__ float rin2[10][2];
  __shared__ double part[4][10][2];
  int n = blockIdx.x*256+threadIdx.x;
  int c0 = gt[blockIdx.x>>2];
  if (threadIdx.x < 20){
    int m = threadIdx.x>>1, cl = threadIdx.x&1;
    int cls = cl?200:c0;
    float s=0;
    for (int p=0;p<rin_parts;p++) s += rin[(size_t)p*2016 + m*KC + cls];
    rin2[m][cl]=s;
  }
  __syncthreads();
  int g = gtseg[n];
  int cl = (g==200)?1:0;
  double q[10]; double col=0.0;
  #pragma unroll
  for (int m=0;m<10;m++){
    double r = (double)rin2[m][cl];
    double t = (double)Qd[(size_t)n*10+m];
    if (r>0.0) t = t/r;
    t = t/10.0;
    q[m]=t; col+=t;
  }
  double cs = (col>0.0)? col : 1.0;
  int bk = Bk[g];
  double bs = (bk>0)? (double)bk : 1.0;
  double inv = 1.0/(cs*bs);
  int w=threadIdx.x>>6, lane=threadIdx.x&63;
  #pragma unroll
  for (int m=0;m<10;m++){
    double t = q[m]*inv;
    Qd[(size_t)n*10+m] = (float)t;
    double p0 = (g==c0)? t:0.0;
    double p1 = (g==200)? t:0.0;
    p0=wredd(p0); p1=wredd(p1);
    if (lane==0){ part[w][m][0]=p0; part[w][m][1]=p1; }
  }
  __syncthreads();
  if (threadIdx.x < 20){
    int m = threadIdx.x>>1, cl2 = threadIdx.x&1;
    double t = part[0][m][cl2]+part[1][m][cl2]+part[2][m][cl2]+part[3][m][cl2];
    atomicAdd(&rout[m*KC + (cl2?200:c0)], (float)t);
  }
}

// fused final argmax + proto_target write + EMA accumulation (wave per pixel)
__global__ __launch_bounds__(256) void kSKEMA(const float* __restrict__ Qd, const int* __restrict__ gtseg,
      const float* __restrict__ r5, const int* __restrict__ corr, const _Float16* __restrict__ C16,
      float* __restrict__ outPT, float* __restrict__ fproto, int* __restrict__ ncnt){
  int w=threadIdx.x>>6, lane=threadIdx.x&63;
  int n = blockIdx.x*4+w;
  int g = gtseg[n];
  float tv = -1.0f;
  if (lane<10){
    float r = r5[lane*KC+g];
    float t = Qd[(size_t)n*10+lane];
    if (r>0.f) t = t/r;
    tv = t*0.1f;
  }
  float bv = tv; int bi = lane;
  #pragma unroll
  for (int o=8;o;o>>=1){
    float ov = __shfl_down(bv,o); int oi = __shfl_down(bi,o);
    if (ov>bv || (ov==bv && oi<bi)){ bv=ov; bi=oi; }
  }
  bi = __shfl(bi, 0);
  if (lane==0) outPT[n] = (float)(bi + 10*g);
  if (corr[n]){
    half8 hc = *(const half8*)(C16 + (size_t)n*DD + lane*8);
    float* dst = fproto + ((size_t)g*10+bi)*DD + lane*8;
    #pragma unroll
    for (int i=0;i<8;i++) atomicAdd(dst+i, (float)hc[i]);
    if (lane==0) atomicAdd(&ncnt[g*10+bi], 1);
  }
}

__global__ __launch_bounds__(256) void kEMAfin(const float* __restrict__ fproto, const int* __restrict__ ncnt,
     const float* __restrict__ Pn, float* __restrict__ outNP){
  int w=threadIdx.x>>6, lane=threadIdx.x&63;
  int km = blockIdx.x*4+w;
  if (km>=KM) return;
  const float* fr = fproto + (size_t)km*DD + lane*8;
  float fp[8]; float ss=0;
  #pragma unroll
  for (int i=0;i<8;i++){ fp[i]=fr[i]; ss+=fp[i]*fp[i]; }
  float n1 = fmaxf(sqrtf(__shfl(wredf(ss),0)), 1e-12f);
  int cnt = ncnt[km];
  const float* pr = Pn + (size_t)km*DD + lane*8;
  float t[8]; float s2=0;
  #pragma unroll
  for (int i=0;i<8;i++){
    float pv = pr[i];
    float tv = cnt ? (0.999f*pv + 0.001f*(fp[i]/n1)) : pv;
    t[i]=tv; s2+=tv*tv;
  }
  float n2 = fmaxf(sqrtf(__shfl(wredf(s2),0)), 1e-12f);
  float* dst = outNP + (size_t)km*DD + lane*8;
  #pragma unroll
  for (int i=0;i<8;i++) dst[i] = t[i]/n2;
}

// ================= launch =================
extern "C" void kernel_launch(void* const* d_in, const int* in_sizes, int n_in,
                              void* d_out, int out_size, void* d_ws, size_t ws_size,
                              hipStream_t stream) {
  const float* A   = (const float*)d_in[0];
  const int*   gt  = (const int*)d_in[1];
  const float* Wp  = (const float*)d_in[2];
  const float* pb  = (const float*)d_in[3];
  const float* fg  = (const float*)d_in[4];
  const float* fb  = (const float*)d_in[5];
  const float* mg  = (const float*)d_in[6];
  const float* mb  = (const float*)d_in[7];
  const float* PR  = (const float*)d_in[8];
  float* out = (float*)d_out;
  char* ws = (char*)d_ws;

  double* xch    = (double*)(ws+OFF_XCH);
  double* Tp     = (double*)(ws+OFF_TP);
  double* colp   = (double*)(ws+OFF_COLP);
  float*  row16  = (float*)(ws+OFF_ROW16);
  float*  row3   = (float*)(ws+OFF_ROW3);
  float*  row5   = (float*)(ws+OFF_ROW5);
  int*    Bk     = (int*)(ws+OFF_BK);
  int*    ncnt   = (int*)(ws+OFF_NCNT);
  int*    done   = (int*)(ws+OFF_DONE);
  float*  fproto = (float*)(ws+OFF_FPROTO);
  double* vsf    = (double*)(ws+OFF_VSF);
  double* mfin   = (double*)(ws+OFF_MFIN);
  double* ssc    = (double*)(ws+OFF_SSC);
  int*    gtseg  = (int*)(ws+OFF_GTSEG);
  int*    corr   = (int*)(ws+OFF_CORR);
  double* u      = (double*)(ws+OFF_U);
  float*  Pn     = (float*)(ws+OFF_PN);
  _Float16* P16  = (_Float16*)(ws+OFF_P16);
  _Float16* C16  = (_Float16*)(ws+OFF_C16);
  float*  Qd     = (float*)(ws+OFF_QD);
  _Float16* W16  = (_Float16*)(ws+OFF_W16);

  // single memset: all atomic accumulators + done counters
  hipMemsetAsync(ws, 0, ZTOTAL, stream);

  // ---- PCA pseudo-gt: 10 passes with last-block finalize, then u + fin ----
  kPIter3<true,false><<<1024,256,0,stream>>>(A, nullptr, mfin,
      xch, Tp, colp, vsf, nullptr, done);
  for (int t=1;t<9;t++){
    kPIter3<false,false><<<1024,256,0,stream>>>(A, vsf+(size_t)(t-1)*768, mfin,
        xch+(size_t)t*8*768, Tp+t*8, nullptr, vsf+(size_t)t*768, nullptr, done+t);
  }
  kPIter3<false,true><<<1024,256,0,stream>>>(A, vsf+(size_t)8*768, mfin,
      xch+(size_t)9*8*768, Tp+9*8, nullptr, vsf+(size_t)9*768, ssc, done+9);
  kPU3<<<1024,256,0,stream>>>(A, vsf+(size_t)9*768, ssc, u);
  kFin<<<1,1024,0,stream>>>(u, gt, out+OUT_PG, gtseg, Bk);

  // ---- prep: W conv + proto normalize ----
  kPrep<<<896,256,0,stream>>>(Wp, W16, PR, Pn, P16);

  // ---- GEMM1 (f32 A, fused convert) + LN+l2n ----
  gemm1<<<512,256,0,stream>>>(A, W16, C16, pb);
  kLNl2n<<<4096,256,0,stream>>>(C16, fg, fb);

  // ---- GEMM2: proto_logits ----
  gemm2<<<2048,256,0,stream>>>(C16, P16, out+OUT_PL);

  // ---- fused max/LN/pred/transpose + sinkhorn row0 ----
  kMaxSK<<<1024,256,0,stream>>>(out+OUT_PL, mg, mb, gtseg, gt, out+OUT_SEG, corr, Qd, row16);

  // ---- sinkhorn passes + fused argmax/EMA ----
  kSKpass<<<64,256,0,stream>>>(Qd, gtseg, gt, row16, 16, row3, Bk);
  kSKpass<<<64,256,0,stream>>>(Qd, gtseg, gt, row3, 1, row5, Bk);
  kSKEMA<<<4096,256,0,stream>>>(Qd, gtseg, row5, corr, C16, out+OUT_PT, fproto, ncnt);

  // ---- EMA finalize ----
  kEMAfin<<<503,256,0,stream>>>(fproto, ncnt, Pn, out+OUT_NP);
}

// Round 8
// 443.394 us; speedup vs baseline: 1.2314x; 1.2314x over previous
//
#include <hip/hip_runtime.h>
#include <cstdint>
#include <cstddef>

typedef _Float16 half8  __attribute__((ext_vector_type(8)));
typedef _Float16 half4v __attribute__((ext_vector_type(4)));
typedef float    f32x4  __attribute__((ext_vector_type(4)));

static constexpr int HWPX = 1024;
static constexpr int NPX  = 16384;
static constexpr int DBB  = 768;
static constexpr int DD   = 512;
static constexpr int KC   = 201;
static constexpr int KM   = 2010;   // KC * 10
static constexpr int KMP  = 2048;   // padded

// ---- workspace offsets (bytes) ----
static constexpr size_t OFF_XCH    = 0;        // [10][8][768] f64 W partials (atomic)
static constexpr size_t OFF_TP     = 491520;   // [10][8] f64 T partials (atomic)
static constexpr size_t OFF_COLP   = 492160;   // [8][768] f64 colsum partials (atomic)
static constexpr size_t OFF_ROW16  = 541312;   // [16][2016] f32
static constexpr size_t OFF_ROW3   = 670336;   // [2016] f32
static constexpr size_t OFF_ROW5   = 678400;   // [2016] f32
static constexpr size_t OFF_BK     = 686464;   // 256 i32
static constexpr size_t OFF_NCNT   = 687488;   // 2016 i32
static constexpr size_t OFF_FPROTO = 695552;   // 2010*512 f32
static constexpr size_t ZTOTAL     = 4812032;  // single memset covers all above
static constexpr size_t OFF_VSF    = 4812032;  // [10][768] f64 finalized vs per pass
static constexpr size_t OFF_MFIN   = 4873472;  // 768 f64 final mean
static constexpr size_t OFF_SSC    = 4879616;  // 8 f64 (s scalar)
static constexpr size_t OFF_GTSEG  = 4879680;  // 16384 i32
static constexpr size_t OFF_CORR   = 4945216;  // 16384 i32
static constexpr size_t OFF_U      = 5010752;  // 16384 f64
static constexpr size_t OFF_PN     = 5141824;  // 2010*512 f32
static constexpr size_t OFF_P16    = 9258304;  // 2048*512 f16
static constexpr size_t OFF_C16    = 11355456; // 16384*512 f16
static constexpr size_t OFF_QD     = 28132672; // 16384*10 f32
static constexpr size_t OFF_W16    = 28788032; // 512*768 f16

// ---- d_out offsets (floats) ----
static constexpr size_t OUT_SEG = 0;
static constexpr size_t OUT_PL  = 3293184;
static constexpr size_t OUT_PT  = 36225024;
static constexpr size_t OUT_PG  = 36241408;
static constexpr size_t OUT_NP  = 36257792;

#define GLDS16(gp, lp) __builtin_amdgcn_global_load_lds( \
    (__attribute__((address_space(1))) const void*)(gp), \
    (__attribute__((address_space(3))) void*)(lp), 16, 0, 0)

static __device__ __forceinline__ float  wredf(float x){
  #pragma unroll
  for (int o=32;o;o>>=1) x += __shfl_down(x,o);
  return x;
}
static __device__ __forceinline__ double wredd(double x){
  #pragma unroll
  for (int o=32;o;o>>=1) x += __shfl_down(x,o);
  return x;
}

// ================= PCA =================
// y = Ac^T Ac x = A^T(Ax) - m*sum(Ax).  Pass kernel: read 6KB finalized vs, stream A,
// accumulate into 8 atomic partial buffers (accumulate-only; NEVER read atomics back —
// R7 lesson: device-atomic read-reduction = serial cross-XCD RMW chain, ~13us/pass).
// kRedV (1 block, plain loads, coherent via launch boundary) folds partials -> vs_next.
template<bool FIRST>
__global__ __launch_bounds__(256) void kPass(const float* __restrict__ A,
    const double* __restrict__ vsin,
    double* __restrict__ Wout, double* __restrict__ Tout, double* __restrict__ colout){
  __shared__ double vs[768];
  __shared__ double red[4][12][64];
  __shared__ double sT[4];
  int tid=threadIdx.x, lane=tid&63, w=tid>>6;
  if (FIRST){
    for (int cc=tid; cc<768; cc+=256) vs[cc] = 1.0/sqrt(768.0);
  } else {
    for (int cc=tid; cc<768; cc+=256) vs[cc] = vsin[cc];
  }
  __syncthreads();
  int rbase = blockIdx.x*16 + w*4;
  double acc[12], cacc[12]; double tloc=0.0;
  #pragma unroll
  for (int j=0;j<12;j++){ acc[j]=0.0; cacc[j]=0.0; }
  for (int i=0;i<4;i++){
    const float* Ar = A + (size_t)(rbase+i)*DBB;
    double a[12]; double wp=0.0;
    #pragma unroll
    for (int j=0;j<12;j++){ int c=j*64+lane; a[j]=(double)Ar[c]; wp += a[j]*vs[c]; }
    wp = wredd(wp); wp = __shfl(wp,0);
    #pragma unroll
    for (int j=0;j<12;j++) acc[j] += wp*a[j];
    if (FIRST){
      #pragma unroll
      for (int j=0;j<12;j++) cacc[j] += a[j];
    }
    tloc += wp;
  }
  #pragma unroll
  for (int j=0;j<12;j++) red[w][j][lane]=acc[j];
  if (lane==0) sT[w]=tloc;
  __syncthreads();
  double* dst = Wout + (size_t)(blockIdx.x&7)*768;
  for (int cc=tid; cc<768; cc+=256){
    int j=cc>>6, l=cc&63;
    atomicAdd(&dst[cc], red[0][j][l]+red[1][j][l]+red[2][j][l]+red[3][j][l]);
  }
  if (tid==0) atomicAdd(&Tout[blockIdx.x&7], sT[0]+sT[1]+sT[2]+sT[3]);
  if (FIRST){
    __syncthreads();
    #pragma unroll
    for (int j=0;j<12;j++) red[w][j][lane]=cacc[j];
    __syncthreads();
    double* cdst = colout + (size_t)(blockIdx.x&7)*768;
    for (int cc=tid; cc<768; cc+=256){
      int j=cc>>6, l=cc&63;
      atomicAdd(&cdst[cc], red[0][j][l]+red[1][j][l]+red[2][j][l]+red[3][j][l]);
    }
  }
}

// 1-block reduce: partials -> finalized vs (plain loads; launch boundary = coherence).
template<bool FIRST, bool LASTP>
__global__ __launch_bounds__(256) void kRedV(const double* __restrict__ Wp8,
    const double* __restrict__ Tp8, const double* __restrict__ colp,
    double* __restrict__ mfin, double* __restrict__ vsout, double* __restrict__ sout){
  __shared__ double sTs;
  __shared__ double sS[4];
  int tid=threadIdx.x, lane=tid&63, w=tid>>6;
  if (tid==0){
    double Ts=0.0;
    #pragma unroll
    for (int p=0;p<8;p++) Ts += Tp8[p];
    sTs = Ts;
  }
  __syncthreads();
  double Ts = sTs;
  double sloc = 0.0;
  for (int cc=tid; cc<768; cc+=256){
    double sw=0.0;
    #pragma unroll
    for (int p=0;p<8;p++) sw += Wp8[p*768+cc];
    double m;
    if (FIRST){
      double mc=0.0;
      #pragma unroll
      for (int p=0;p<8;p++) mc += colp[p*768+cc];
      m = mc*(1.0/16384.0);
      mfin[cc] = m;
    } else {
      m = mfin[cc];
    }
    double v = sw - m*Ts;
    vsout[cc] = v;
    if (LASTP) sloc += m*v;
  }
  if (LASTP){
    sloc = wredd(sloc);
    if (lane==0) sS[w]=sloc;
    __syncthreads();
    if (tid==0) sout[0] = sS[0]+sS[1]+sS[2]+sS[3];
  }
}

// u = Ac v = A v - (m.v):  vs and s finalized by kRedV<.,true>.
__global__ __launch_bounds__(256) void kPU3(const float* __restrict__ A,
    const double* __restrict__ vsin, const double* __restrict__ ssc, double* __restrict__ u){
  __shared__ double vs[768];
  int tid=threadIdx.x, lane=tid&63, w=tid>>6;
  for (int cc=tid; cc<768; cc+=256) vs[cc] = vsin[cc];
  __syncthreads();
  double s = ssc[0];
  int rbase = blockIdx.x*16 + w*4;
  for (int i=0;i<4;i++){
    const float* Ar = A + (size_t)(rbase+i)*DBB;
    double wp=0.0;
    #pragma unroll
    for (int j=0;j<12;j++){ int c=j*64+lane; wp += (double)Ar[c]*vs[c]; }
    wp = wredd(wp);
    if (lane==0) u[rbase+i] = wp - s;
  }
}

// fused global minmax + pseudo-gt + Bk (single block)
__global__ __launch_bounds__(1024) void kFin(const double* __restrict__ u, const int* __restrict__ gt,
      float* __restrict__ outPG, int* __restrict__ gtseg, int* __restrict__ Bk){
  __shared__ double smn[16], smx[16];
  __shared__ double sres[2];
  int t = threadIdx.x;
  double mn=1e300, mx=-1e300;
  for (int k=0;k<16;k++){ double x=u[k*1024+t]; mn=fmin(mn,x); mx=fmax(mx,x); }
  #pragma unroll
  for (int o=32;o;o>>=1){ mn=fmin(mn,__shfl_down(mn,o)); mx=fmax(mx,__shfl_down(mx,o)); }
  if ((t&63)==0){ smn[t>>6]=mn; smx[t>>6]=mx; }
  __syncthreads();
  if (t==0){
    for (int i=1;i<16;i++){ mn=fmin(mn,smn[i]); mx=fmax(mx,smx[i]); }
    sres[0]=mn; sres[1]=mx;
  }
  __syncthreads();
  mn=sres[0]; mx=sres[1];
  double inv = 1.0/(mx-mn);
  for (int k=0;k<16;k++){
    int n = k*1024 + t;
    int c0 = gt[k];
    double us = (u[n]-mn)*inv;
    int g = (us < 0.5) ? c0 : 200;
    outPG[n] = (float)g;
    gtseg[n] = g;
    unsigned long long b0 = __ballot(g==c0);
    unsigned long long b1 = __ballot(g==200);
    if ((t&63)==0){
      atomicAdd(&Bk[c0], (int)__popcll(b0));
      atomicAdd(&Bk[200], (int)__popcll(b1));
    }
  }
}

// ================= prep: W f32->f16 (blocks 0..383) + proto l2-normalize (blocks 384..895) =================
__global__ __launch_bounds__(256) void kPrep(const float* __restrict__ Wp, _Float16* __restrict__ W16,
    const float* __restrict__ PR, float* __restrict__ Pn, _Float16* __restrict__ P16){
  int b = blockIdx.x;
  if (b < 384){
    int i = b*256 + threadIdx.x;
    float4 vv = ((const float4*)Wp)[i];
    half4v h; h[0]=(_Float16)vv.x; h[1]=(_Float16)vv.y; h[2]=(_Float16)vv.z; h[3]=(_Float16)vv.w;
    ((half4v*)W16)[i] = h;
    return;
  }
  int w=threadIdx.x>>6, lane=threadIdx.x&63;
  int km = (b-384)*4 + w;
  if (km >= KM){
    if (km < KMP){
      half8 z;
      #pragma unroll
      for (int i=0;i<8;i++) z[i]=(_Float16)0.0f;
      *(half8*)(P16 + (size_t)km*DD + lane*8) = z;
    }
    return;
  }
  const float* r = PR + (size_t)km*DD + lane*8;
  float4 a = *(const float4*)r, b2 = *(const float4*)(r+4);
  float x[8] = {a.x,a.y,a.z,a.w,b2.x,b2.y,b2.z,b2.w};
  float ss=0;
  #pragma unroll
  for (int i=0;i<8;i++) ss += x[i]*x[i];
  ss = __shfl(wredf(ss),0);
  float nrm = fmaxf(sqrtf(ss), 1e-12f);
  float* pw = Pn + (size_t)km*DD + lane*8;
  half8 h;
  #pragma unroll
  for (int i=0;i<8;i++){ float vv = x[i]/nrm; pw[i]=vv; h[i]=(_Float16)vv; }
  *(half8*)(P16 + (size_t)km*DD + lane*8) = h;
}

// ================= GEMM1: C16[16384,512] = f16( A_f32 @ W16^T + b ) =================
__global__ __launch_bounds__(256) void gemm1(const float* __restrict__ Af, const _Float16* __restrict__ Bm,
    _Float16* __restrict__ Ch, const float* __restrict__ bias){
  __shared__ __align__(16) char As[128*128];
  __shared__ __align__(16) char Bs[128*128];
  const int tid = threadIdx.x;
  const int lane = tid & 63, w = tid >> 6;
  const int wr = w >> 1, wc = w & 1;
  const int lrow = lane & 15, kg = lane >> 4;
  const int id = blockIdx.x;
  const int xcd = id & 7, pos = id >> 3;
  const int m0 = ((xcd<<4) | (pos>>2)) * 128;
  const int n0 = (pos & 3) * 128;

  f32x4 acc[4][4];
  #pragma unroll
  for (int i=0;i<4;i++)
    #pragma unroll
    for (int j=0;j<4;j++){ f32x4 z = {0.f,0.f,0.f,0.f}; acc[i][j]=z; }

  for (int k0 = 0; k0 < DBB; k0 += 64){
    #pragma unroll
    for (int i=0;i<4;i++){
      int slot = (i*4 + w)*64 + lane;
      int r = slot >> 3, c = slot & 7;
      int cs = c ^ (r & 7);
      GLDS16(Bm + (size_t)(n0+r)*DBB + k0 + cs*8, Bs + (i*4+w)*1024);
    }
    #pragma unroll
    for (int i=0;i<8;i++){
      int slot = i*256 + tid;
      int r = slot >> 4, c4 = slot & 15;
      float4 v = *(const float4*)(Af + (size_t)(m0+r)*DBB + k0 + c4*4);
      half4v h; h[0]=(_Float16)v.x; h[1]=(_Float16)v.y; h[2]=(_Float16)v.z; h[3]=(_Float16)v.w;
      *(half4v*)(As + r*128 + (((c4>>1)^(r&7))<<4) + (c4&1)*8) = h;
    }
    __syncthreads();
    #pragma unroll
    for (int h=0; h<2; h++){
      half8 af[4], bf[4];
      #pragma unroll
      for (int mi=0;mi<4;mi++){
        int ar = wr*64 + mi*16 + lrow;
        af[mi] = *(const half8*)(As + ar*128 + (((h*4+kg) ^ (ar&7))<<4));
      }
      #pragma unroll
      for (int nj=0;nj<4;nj++){
        int br = wc*64 + nj*16 + lrow;
        bf[nj] = *(const half8*)(Bs + br*128 + (((h*4+kg) ^ (br&7))<<4));
      }
      #pragma unroll
      for (int mi=0;mi<4;mi++)
        #pragma unroll
        for (int nj=0;nj<4;nj++)
          acc[mi][nj] = __builtin_amdgcn_mfma_f32_16x16x32_f16(af[mi], bf[nj], acc[mi][nj], 0,0,0);
    }
    __syncthreads();
  }
  #pragma unroll
  for (int mi=0;mi<4;mi++){
    int gr = m0 + wr*64 + mi*16 + kg*4;
    #pragma unroll
    for (int nj=0;nj<4;nj++){
      int gc = n0 + wc*64 + nj*16 + lrow;
      float bv = bias[gc];
      #pragma unroll
      for (int r2=0;r2<4;r2++)
        Ch[(size_t)(gr+r2)*DD + gc] = (_Float16)(acc[mi][nj][r2] + bv);
    }
  }
}

// ================= GEMM2: PL[16384,2010] = _c @ protos^T =================
__global__ __launch_bounds__(256) void gemm2(const _Float16* __restrict__ Am, const _Float16* __restrict__ Bm,
    float* __restrict__ Cf){
  __shared__ __align__(16) char As[128*128];
  __shared__ __align__(16) char Bs[128*128];
  const int tid = threadIdx.x;
  const int lane = tid & 63, w = tid >> 6;
  const int wr = w >> 1, wc = w & 1;
  const int lrow = lane & 15, kg = lane >> 4;
  const int id = blockIdx.x;
  const int xcd = id & 7, pos = id >> 3;
  const int m0 = ((xcd<<4) | (pos>>4)) * 128;
  const int n0 = (pos & 15) * 128;

  f32x4 acc[4][4];
  #pragma unroll
  for (int i=0;i<4;i++)
    #pragma unroll
    for (int j=0;j<4;j++){ f32x4 z = {0.f,0.f,0.f,0.f}; acc[i][j]=z; }

  for (int k0 = 0; k0 < DD; k0 += 64){
    #pragma unroll
    for (int i=0;i<4;i++){
      int slot = (i*4 + w)*64 + lane;
      int r = slot >> 3, c = slot & 7;
      int cs = c ^ (r & 7);
      GLDS16(Am + (size_t)(m0+r)*DD + k0 + cs*8, As + (i*4+w)*1024);
      GLDS16(Bm + (size_t)(n0+r)*DD + k0 + cs*8, Bs + (i*4+w)*1024);
    }
    __syncthreads();
    #pragma unroll
    for (int h=0; h<2; h++){
      half8 af[4], bf[4];
      #pragma unroll
      for (int mi=0;mi<4;mi++){
        int ar = wr*64 + mi*16 + lrow;
        af[mi] = *(const half8*)(As + ar*128 + (((h*4+kg) ^ (ar&7))<<4));
      }
      #pragma unroll
      for (int nj=0;nj<4;nj++){
        int br = wc*64 + nj*16 + lrow;
        bf[nj] = *(const half8*)(Bs + br*128 + (((h*4+kg) ^ (br&7))<<4));
      }
      #pragma unroll
      for (int mi=0;mi<4;mi++)
        #pragma unroll
        for (int nj=0;nj<4;nj++)
          acc[mi][nj] = __builtin_amdgcn_mfma_f32_16x16x32_f16(af[mi], bf[nj], acc[mi][nj], 0,0,0);
    }
    __syncthreads();
  }
  #pragma unroll
  for (int mi=0;mi<4;mi++){
    int gr = m0 + wr*64 + mi*16 + kg*4;
    #pragma unroll
    for (int nj=0;nj<4;nj++){
      int gc = n0 + wc*64 + nj*16 + lrow;
      if (gc < KM){
        #pragma unroll
        for (int r2=0;r2<4;r2++)
          Cf[(size_t)(gr+r2)*KM + gc] = acc[mi][nj][r2];
      }
    }
  }
}

// ================= LN + l2 normalize (in-place on C16) =================
__global__ __launch_bounds__(256) void kLNl2n(_Float16* __restrict__ C16,
      const float* __restrict__ fg, const float* __restrict__ fb){
  int w=threadIdx.x>>6, lane=threadIdx.x&63;
  int n = blockIdx.x*4 + w;
  _Float16* row = C16 + (size_t)n*DD + lane*8;
  half8 h = *(const half8*)row;
  float x[8];
  #pragma unroll
  for (int i=0;i<8;i++) x[i] = (float)h[i];
  float s=0;
  #pragma unroll
  for (int i=0;i<8;i++) s += x[i];
  float mu = __shfl(wredf(s),0)/512.f;
  float q=0;
  #pragma unroll
  for (int i=0;i<8;i++){ float d=x[i]-mu; q+=d*d; }
  float var = __shfl(wredf(q),0)/512.f;
  float inv = 1.f/sqrtf(var+1e-5f);
  float4 g0 = *(const float4*)(fg+lane*8), g1 = *(const float4*)(fg+lane*8+4);
  float4 b0 = *(const float4*)(fb+lane*8), b1 = *(const float4*)(fb+lane*8+4);
  float gg[8] = {g0.x,g0.y,g0.z,g0.w,g1.x,g1.y,g1.z,g1.w};
  float bb[8] = {b0.x,b0.y,b0.z,b0.w,b1.x,b1.y,b1.z,b1.w};
  float y[8]; float ss=0;
  #pragma unroll
  for (int i=0;i<8;i++){ y[i] = (x[i]-mu)*inv*gg[i]+bb[i]; ss += y[i]*y[i]; }
  float nrm = fmaxf(sqrtf(__shfl(wredf(ss),0)), 1e-12f);
  half8 o;
  #pragma unroll
  for (int i=0;i<8;i++) o[i] = (_Float16)(y[i]/nrm);
  *(half8*)row = o;
}

// ===== fused per-class max + mask LN + pred + transpose-out + sinkhorn Qd/row0 partials =====
__global__ __launch_bounds__(256) void kMaxSK(const float* __restrict__ PL, const float* __restrict__ mg,
    const float* __restrict__ mb, const int* __restrict__ gtseg, const int* __restrict__ gt,
    float* __restrict__ outseg, int* __restrict__ corr, float* __restrict__ Qd, float* __restrict__ row16){
  __shared__ float tile[16][205];
  __shared__ float qpart[10][2];
  int tid=threadIdx.x, lane=tid&63, w=tid>>6;
  int n0 = blockIdx.x*16;
  int b = n0>>10, hw0 = n0&1023;
  int c0 = gt[b];
  if (tid<20) qpart[tid>>1][tid&1]=0.f;
  __syncthreads();
  for (int r=0;r<16;r++){
    int n = n0 + r;
    int g = gtseg[n];
    if (tid < KC){
      const float* src = PL + (size_t)n*KM + tid*10;
      float v[10];
      #pragma unroll
      for (int m2=0;m2<5;m2++){
        float2 t2 = *(const float2*)(src + m2*2);
        v[m2*2]=t2.x; v[m2*2+1]=t2.y;
      }
      float mx = v[0];
      #pragma unroll
      for (int m=1;m<10;m++) mx = fmaxf(mx,v[m]);
      tile[r][tid] = mx;
      if (tid == g){
        int cl = (g==200)?1:0;
        #pragma unroll
        for (int m=0;m<10;m++){
          float e = expf(v[m]*20.f);
          Qd[(size_t)n*10+m] = e;
          atomicAdd(&qpart[m][cl], e);
        }
      }
    }
  }
  __syncthreads();
  for (int rr=0; rr<4; ++rr){
    int r = w*4 + rr;
    int n = n0 + r;
    float xv[4]; int ncl=0;
    for (int c=lane;c<KC;c+=64) xv[ncl++] = tile[r][c];
    float ps=0;
    for (int i=0;i<ncl;i++) ps += xv[i];
    float mu = __shfl(wredf(ps),0)*(1.f/201.f);
    float pv=0;
    for (int i=0;i<ncl;i++){ float d=xv[i]-mu; pv+=d*d; }
    float var = __shfl(wredf(pv),0)*(1.f/201.f);
    float inv = 1.f/sqrtf(var+1e-5f);
    float bv=-3.0e38f; int bi=1<<30;
    ncl=0;
    for (int c=lane;c<KC;c+=64){
      float o = (xv[ncl]-mu)*inv*mg[c]+mb[c]; ncl++;
      tile[r][c] = o;
      if (o>bv){ bv=o; bi=c; }
    }
    #pragma unroll
    for (int o2=32;o2;o2>>=1){
      float ov=__shfl_down(bv,o2); int oi=__shfl_down(bi,o2);
      if (ov>bv||(ov==bv&&oi<bi)){bv=ov;bi=oi;}
    }
    if (lane==0) corr[n] = (bi==gtseg[n])?1:0;
  }
  __syncthreads();
  if (tid<20){
    int m=tid>>1, cl=tid&1;
    atomicAdd(&row16[(size_t)(blockIdx.x&15)*2016 + m*KC + (cl?200:c0)], qpart[m][cl]);
  }
  for (int idx=tid; idx<KC*16; idx+=256){
    int c=idx>>4, j=idx&15;
    outseg[(((size_t)b*KC+c)<<10) + hw0 + j] = tile[j][c];
  }
}

// one sinkhorn iteration; rin has rin_parts partial buffers of stride 2016
__global__ __launch_bounds__(256) void kSKpass(float* __restrict__ Qd, const int* __restrict__ gtseg,
      const int* __restrict__ gt, const float* __restrict__ rin, int rin_parts,
      float* __restrict__ rout, const int* __restrict__ Bk){
  __shared__ float rin2[10][2];
  __shared__ double part[4][10][2];
  int n = blockIdx.x*256+threadIdx.x;
  int c0 = gt[blockIdx.x>>2];
  if (threadIdx.x < 20){
    int m = threadIdx.x>>1, cl = threadIdx.x&1;
    int cls = cl?200:c0;
    float s=0;
    for (int p=0;p<rin_parts;p++) s += rin[(size_t)p*2016 + m*KC + cls];
    rin2[m][cl]=s;
  }
  __syncthreads();
  int g = gtseg[n];
  int cl = (g==200)?1:0;
  double q[10]; double col=0.0;
  #pragma unroll
  for (int m=0;m<10;m++){
    double r = (double)rin2[m][cl];
    double t = (double)Qd[(size_t)n*10+m];
    if (r>0.0) t = t/r;
    t = t/10.0;
    q[m]=t; col+=t;
  }
  double cs = (col>0.0)? col : 1.0;
  int bk = Bk[g];
  double bs = (bk>0)? (double)bk : 1.0;
  double inv = 1.0/(cs*bs);
  int w=threadIdx.x>>6, lane=threadIdx.x&63;
  #pragma unroll
  for (int m=0;m<10;m++){
    double t = q[m]*inv;
    Qd[(size_t)n*10+m] = (float)t;
    double p0 = (g==c0)? t:0.0;
    double p1 = (g==200)? t:0.0;
    p0=wredd(p0); p1=wredd(p1);
    if (lane==0){ part[w][m][0]=p0; part[w][m][1]=p1; }
  }
  __syncthreads();
  if (threadIdx.x < 20){
    int m = threadIdx.x>>1, cl2 = threadIdx.x&1;
    double t = part[0][m][cl2]+part[1][m][cl2]+part[2][m][cl2]+part[3][m][cl2];
    atomicAdd(&rout[m*KC + (cl2?200:c0)], (float)t);
  }
}

// fused final argmax + proto_target write + EMA accumulation (wave per pixel)
__global__ __launch_bounds__(256) void kSKEMA(const float* __restrict__ Qd, const int* __restrict__ gtseg,
      const float* __restrict__ r5, const int* __restrict__ corr, const _Float16* __restrict__ C16,
      float* __restrict__ outPT, float* __restrict__ fproto, int* __restrict__ ncnt){
  int w=threadIdx.x>>6, lane=threadIdx.x&63;
  int n = blockIdx.x*4+w;
  int g = gtseg[n];
  float tv = -1.0f;
  if (lane<10){
    float r = r5[lane*KC+g];
    float t = Qd[(size_t)n*10+lane];
    if (r>0.f) t = t/r;
    tv = t*0.1f;
  }
  float bv = tv; int bi = lane;
  #pragma unroll
  for (int o=8;o;o>>=1){
    float ov = __shfl_down(bv,o); int oi = __shfl_down(bi,o);
    if (ov>bv || (ov==bv && oi<bi)){ bv=ov; bi=oi; }
  }
  bi = __shfl(bi, 0);
  if (lane==0) outPT[n] = (float)(bi + 10*g);
  if (corr[n]){
    half8 hc = *(const half8*)(C16 + (size_t)n*DD + lane*8);
    float* dst = fproto + ((size_t)g*10+bi)*DD + lane*8;
    #pragma unroll
    for (int i=0;i<8;i++) atomicAdd(dst+i, (float)hc[i]);
    if (lane==0) atomicAdd(&ncnt[g*10+bi], 1);
  }
}

__global__ __launch_bounds__(256) void kEMAfin(const float* __restrict__ fproto, const int* __restrict__ ncnt,
     const float* __restrict__ Pn, float* __restrict__ outNP){
  int w=threadIdx.x>>6, lane=threadIdx.x&63;
  int km = blockIdx.x*4+w;
  if (km>=KM) return;
  const float* fr = fproto + (size_t)km*DD + lane*8;
  float fp[8]; float ss=0;
  #pragma unroll
  for (int i=0;i<8;i++){ fp[i]=fr[i]; ss+=fp[i]*fp[i]; }
  float n1 = fmaxf(sqrtf(__shfl(wredf(ss),0)), 1e-12f);
  int cnt = ncnt[km];
  const float* pr = Pn + (size_t)km*DD + lane*8;
  float t[8]; float s2=0;
  #pragma unroll
  for (int i=0;i<8;i++){
    float pv = pr[i];
    float tv = cnt ? (0.999f*pv + 0.001f*(fp[i]/n1)) : pv;
    t[i]=tv; s2+=tv*tv;
  }
  float n2 = fmaxf(sqrtf(__shfl(wredf(s2),0)), 1e-12f);
  float* dst = outNP + (size_t)km*DD + lane*8;
  #pragma unroll
  for (int i=0;i<8;i++) dst[i] = t[i]/n2;
}

// ================= launch =================
extern "C" void kernel_launch(void* const* d_in, const int* in_sizes, int n_in,
                              void* d_out, int out_size, void* d_ws, size_t ws_size,
                              hipStream_t stream) {
  const float* A   = (const float*)d_in[0];
  const int*   gt  = (const int*)d_in[1];
  const float* Wp  = (const float*)d_in[2];
  const float* pb  = (const float*)d_in[3];
  const float* fg  = (const float*)d_in[4];
  const float* fb  = (const float*)d_in[5];
  const float* mg  = (const float*)d_in[6];
  const float* mb  = (const float*)d_in[7];
  const float* PR  = (const float*)d_in[8];
  float* out = (float*)d_out;
  char* ws = (char*)d_ws;

  double* xch    = (double*)(ws+OFF_XCH);
  double* Tp     = (double*)(ws+OFF_TP);
  double* colp   = (double*)(ws+OFF_COLP);
  float*  row16  = (float*)(ws+OFF_ROW16);
  float*  row3   = (float*)(ws+OFF_ROW3);
  float*  row5   = (float*)(ws+OFF_ROW5);
  int*    Bk     = (int*)(ws+OFF_BK);
  int*    ncnt   = (int*)(ws+OFF_NCNT);
  float*  fproto = (float*)(ws+OFF_FPROTO);
  double* vsf    = (double*)(ws+OFF_VSF);
  double* mfin   = (double*)(ws+OFF_MFIN);
  double* ssc    = (double*)(ws+OFF_SSC);
  int*    gtseg  = (int*)(ws+OFF_GTSEG);
  int*    corr   = (int*)(ws+OFF_CORR);
  double* u      = (double*)(ws+OFF_U);
  float*  Pn     = (float*)(ws+OFF_PN);
  _Float16* P16  = (_Float16*)(ws+OFF_P16);
  _Float16* C16  = (_Float16*)(ws+OFF_C16);
  float*  Qd     = (float*)(ws+OFF_QD);
  _Float16* W16  = (_Float16*)(ws+OFF_W16);

  // single memset: all atomic accumulators
  hipMemsetAsync(ws, 0, ZTOTAL, stream);

  // ---- PCA pseudo-gt: pass -> tiny reduce, x10; then u + fin ----
  kPass<true><<<1024,256,0,stream>>>(A, nullptr, xch, Tp, colp);
  kRedV<true,false><<<1,256,0,stream>>>(xch, Tp, colp, mfin, vsf, nullptr);
  for (int t=1;t<9;t++){
    kPass<false><<<1024,256,0,stream>>>(A, vsf+(size_t)(t-1)*768,
        xch+(size_t)t*8*768, Tp+t*8, nullptr);
    kRedV<false,false><<<1,256,0,stream>>>(xch+(size_t)t*8*768, Tp+t*8, nullptr,
        mfin, vsf+(size_t)t*768, nullptr);
  }
  kPass<false><<<1024,256,0,stream>>>(A, vsf+(size_t)8*768,
      xch+(size_t)9*8*768, Tp+9*8, nullptr);
  kRedV<false,true><<<1,256,0,stream>>>(xch+(size_t)9*8*768, Tp+9*8, nullptr,
      mfin, vsf+(size_t)9*768, ssc);
  kPU3<<<1024,256,0,stream>>>(A, vsf+(size_t)9*768, ssc, u);
  kFin<<<1,1024,0,stream>>>(u, gt, out+OUT_PG, gtseg, Bk);

  // ---- prep: W conv + proto normalize ----
  kPrep<<<896,256,0,stream>>>(Wp, W16, PR, Pn, P16);

  // ---- GEMM1 (f32 A, fused convert) + LN+l2n ----
  gemm1<<<512,256,0,stream>>>(A, W16, C16, pb);
  kLNl2n<<<4096,256,0,stream>>>(C16, fg, fb);

  // ---- GEMM2: proto_logits ----
  gemm2<<<2048,256,0,stream>>>(C16, P16, out+OUT_PL);

  // ---- fused max/LN/pred/transpose + sinkhorn row0 ----
  kMaxSK<<<1024,256,0,stream>>>(out+OUT_PL, mg, mb, gtseg, gt, out+OUT_SEG, corr, Qd, row16);

  // ---- sinkhorn passes + fused argmax/EMA ----
  kSKpass<<<64,256,0,stream>>>(Qd, gtseg, gt, row16, 16, row3, Bk);
  kSKpass<<<64,256,0,stream>>>(Qd, gtseg, gt, row3, 1, row5, Bk);
  kSKEMA<<<4096,256,0,stream>>>(Qd, gtseg, row5, corr, C16, out+OUT_PT, fproto, ncnt);

  // ---- EMA finalize ----
  kEMAfin<<<503,256,0,stream>>>(fproto, ncnt, Pn, out+OUT_NP);
}

// Round 9
// 430.443 us; speedup vs baseline: 1.2684x; 1.0301x over previous
//
#include <hip/hip_runtime.h>
#include <cstdint>
#include <cstddef>

typedef _Float16 half8  __attribute__((ext_vector_type(8)));
typedef _Float16 half4v __attribute__((ext_vector_type(4)));
typedef float    f32x4  __attribute__((ext_vector_type(4)));

static constexpr int HWPX = 1024;
static constexpr int NPX  = 16384;
static constexpr int DBB  = 768;
static constexpr int DD   = 512;
static constexpr int KC   = 201;
static constexpr int KM   = 2010;   // KC * 10
static constexpr int KMP  = 2048;   // padded

// ---- workspace offsets (bytes) ----
static constexpr size_t OFF_XCH    = 0;        // [10][8][768] f64 W partials (atomic)
static constexpr size_t OFF_TP     = 491520;   // [10][8] f64 T partials (atomic)
static constexpr size_t OFF_COLP   = 492160;   // [8][768] f64 colsum partials (atomic)
static constexpr size_t OFF_ROW16  = 541312;   // [16][2016] f32
static constexpr size_t OFF_ROW3   = 670336;   // [2016] f32
static constexpr size_t OFF_ROW5   = 678400;   // [2016] f32
static constexpr size_t OFF_BK     = 686464;   // 256 i32
static constexpr size_t OFF_NCNT   = 687488;   // 2016 i32
static constexpr size_t OFF_FPROTO = 695552;   // 2010*512 f32
static constexpr size_t OFF_MAXB   = 4812032;  // 16384*201 u32 encoded class-max
static constexpr size_t ZTOTAL     = 17984768; // single memset covers all above
static constexpr size_t OFF_GTSEG  = 17984768; // 16384 i32
static constexpr size_t OFF_CORR   = 18050304; // 16384 i32
static constexpr size_t OFF_U      = 18115840; // 16384 f64
static constexpr size_t OFF_PN     = 18246912; // 2010*512 f32
static constexpr size_t OFF_P16    = 22363392; // 2048*512 f16
static constexpr size_t OFF_C16    = 24460544; // 16384*512 f16
static constexpr size_t OFF_QD     = 41237760; // 16384*10 f32
static constexpr size_t OFF_W16    = 41893120; // 512*768 f16 (end ~42.7MB << ws)

// ---- d_out offsets (floats) ----
static constexpr size_t OUT_SEG = 0;
static constexpr size_t OUT_PL  = 3293184;
static constexpr size_t OUT_PT  = 36225024;
static constexpr size_t OUT_PG  = 36241408;
static constexpr size_t OUT_NP  = 36257792;

#define GLDS16(gp, lp) __builtin_amdgcn_global_load_lds( \
    (__attribute__((address_space(1))) const void*)(gp), \
    (__attribute__((address_space(3))) void*)(lp), 16, 0, 0)

static __device__ __forceinline__ float  wredf(float x){
  #pragma unroll
  for (int o=32;o;o>>=1) x += __shfl_down(x,o);
  return x;
}
static __device__ __forceinline__ double wredd(double x){
  #pragma unroll
  for (int o=32;o;o>>=1) x += __shfl_down(x,o);
  return x;
}

// ================= PCA (R6 structure: broadcast-read partials, mean-free hot loop) =================
// y = Ac^T Ac x = A^T(Ax) - m*sum(Ax); vs_next reconstructed per-block from broadcast-cached
// partials (same 98KB read by all blocks -> L2 broadcast, cheap).  FIRST pass also colsums.
template<bool FIRST>
__global__ __launch_bounds__(256) void kPIter2(const float* __restrict__ A,
    const double* __restrict__ Win, const double* __restrict__ Tin, const double* __restrict__ colp,
    double* __restrict__ Wout, double* __restrict__ Tout, double* __restrict__ colout){
  __shared__ double vs[768];
  __shared__ double red[4][12][64];
  __shared__ double sT[4];
  int tid=threadIdx.x, lane=tid&63, w=tid>>6;
  if (FIRST){
    for (int cc=tid; cc<768; cc+=256) vs[cc] = 1.0/sqrt(768.0);
  } else {
    double Ts=0.0;
    #pragma unroll
    for (int p=0;p<8;p++) Ts += Tin[p];
    for (int cc=tid; cc<768; cc+=256){
      double sw=0.0, mc=0.0;
      #pragma unroll
      for (int p=0;p<8;p++){ sw += Win[p*768+cc]; mc += colp[p*768+cc]; }
      vs[cc] = sw - mc*(1.0/16384.0)*Ts;
    }
  }
  __syncthreads();
  int rbase = blockIdx.x*16 + w*4;
  double acc[12], cacc[12]; double tloc=0.0;
  #pragma unroll
  for (int j=0;j<12;j++){ acc[j]=0.0; cacc[j]=0.0; }
  for (int i=0;i<4;i++){
    const float* Ar = A + (size_t)(rbase+i)*DBB;
    double a[12]; double wp=0.0;
    #pragma unroll
    for (int j=0;j<12;j++){ int c=j*64+lane; a[j]=(double)Ar[c]; wp += a[j]*vs[c]; }
    wp = wredd(wp); wp = __shfl(wp,0);
    #pragma unroll
    for (int j=0;j<12;j++) acc[j] += wp*a[j];
    if (FIRST){
      #pragma unroll
      for (int j=0;j<12;j++) cacc[j] += a[j];
    }
    tloc += wp;
  }
  #pragma unroll
  for (int j=0;j<12;j++) red[w][j][lane]=acc[j];
  if (lane==0) sT[w]=tloc;
  __syncthreads();
  double* dst = Wout + (size_t)(blockIdx.x&7)*768;
  for (int cc=tid; cc<768; cc+=256){
    int j=cc>>6, l=cc&63;
    atomicAdd(&dst[cc], red[0][j][l]+red[1][j][l]+red[2][j][l]+red[3][j][l]);
  }
  if (tid==0) atomicAdd(&Tout[blockIdx.x&7], sT[0]+sT[1]+sT[2]+sT[3]);
  if (FIRST){
    __syncthreads();
    #pragma unroll
    for (int j=0;j<12;j++) red[w][j][lane]=cacc[j];
    __syncthreads();
    double* cdst = colout + (size_t)(blockIdx.x&7)*768;
    for (int cc=tid; cc<768; cc+=256){
      int j=cc>>6, l=cc&63;
      atomicAdd(&cdst[cc], red[0][j][l]+red[1][j][l]+red[2][j][l]+red[3][j][l]);
    }
  }
}

// u = Ac v = A v - (m^T v):  v reconstructed from pass-10 partials in setup.
__global__ __launch_bounds__(256) void kPU2(const float* __restrict__ A, const double* __restrict__ Wp,
    const double* __restrict__ Tp, const double* __restrict__ colp, double* __restrict__ u){
  __shared__ double vs[768];
  __shared__ double sS[4];
  int tid=threadIdx.x, lane=tid&63, w=tid>>6;
  double Ts=0.0;
  #pragma unroll
  for (int p=0;p<8;p++) Ts += Tp[p];
  double sloc=0.0;
  for (int cc=tid; cc<768; cc+=256){
    double sw=0.0, mc=0.0;
    #pragma unroll
    for (int p=0;p<8;p++){ sw += Wp[p*768+cc]; mc += colp[p*768+cc]; }
    double m = mc*(1.0/16384.0);
    double v = sw - m*Ts;
    vs[cc] = v;
    sloc += m*v;
  }
  sloc = wredd(sloc);
  if (lane==0) sS[w]=sloc;
  __syncthreads();
  double s = sS[0]+sS[1]+sS[2]+sS[3];
  int rbase = blockIdx.x*16 + w*4;
  for (int i=0;i<4;i++){
    const float* Ar = A + (size_t)(rbase+i)*DBB;
    double wp=0.0;
    #pragma unroll
    for (int j=0;j<12;j++){ int c=j*64+lane; wp += (double)Ar[c]*vs[c]; }
    wp = wredd(wp);
    if (lane==0) u[rbase+i] = wp - s;
  }
}

// fused global minmax + pseudo-gt + Bk (single block)
__global__ __launch_bounds__(1024) void kFin(const double* __restrict__ u, const int* __restrict__ gt,
      float* __restrict__ outPG, int* __restrict__ gtseg, int* __restrict__ Bk){
  __shared__ double smn[16], smx[16];
  __shared__ double sres[2];
  int t = threadIdx.x;
  double mn=1e300, mx=-1e300;
  for (int k=0;k<16;k++){ double x=u[k*1024+t]; mn=fmin(mn,x); mx=fmax(mx,x); }
  #pragma unroll
  for (int o=32;o;o>>=1){ mn=fmin(mn,__shfl_down(mn,o)); mx=fmax(mx,__shfl_down(mx,o)); }
  if ((t&63)==0){ smn[t>>6]=mn; smx[t>>6]=mx; }
  __syncthreads();
  if (t==0){
    for (int i=1;i<16;i++){ mn=fmin(mn,smn[i]); mx=fmax(mx,smx[i]); }
    sres[0]=mn; sres[1]=mx;
  }
  __syncthreads();
  mn=sres[0]; mx=sres[1];
  double inv = 1.0/(mx-mn);
  for (int k=0;k<16;k++){
    int n = k*1024 + t;
    int c0 = gt[k];
    double us = (u[n]-mn)*inv;
    int g = (us < 0.5) ? c0 : 200;
    outPG[n] = (float)g;
    gtseg[n] = g;
    unsigned long long b0 = __ballot(g==c0);
    unsigned long long b1 = __ballot(g==200);
    if ((t&63)==0){
      atomicAdd(&Bk[c0], (int)__popcll(b0));
      atomicAdd(&Bk[200], (int)__popcll(b1));
    }
  }
}

// ================= prep: W f32->f16 (blocks 0..383) + proto l2-normalize (blocks 384..895) =================
__global__ __launch_bounds__(256) void kPrep(const float* __restrict__ Wp, _Float16* __restrict__ W16,
    const float* __restrict__ PR, float* __restrict__ Pn, _Float16* __restrict__ P16){
  int b = blockIdx.x;
  if (b < 384){
    int i = b*256 + threadIdx.x;
    float4 vv = ((const float4*)Wp)[i];
    half4v h; h[0]=(_Float16)vv.x; h[1]=(_Float16)vv.y; h[2]=(_Float16)vv.z; h[3]=(_Float16)vv.w;
    ((half4v*)W16)[i] = h;
    return;
  }
  int w=threadIdx.x>>6, lane=threadIdx.x&63;
  int km = (b-384)*4 + w;
  if (km >= KM){
    if (km < KMP){
      half8 z;
      #pragma unroll
      for (int i=0;i<8;i++) z[i]=(_Float16)0.0f;
      *(half8*)(P16 + (size_t)km*DD + lane*8) = z;
    }
    return;
  }
  const float* r = PR + (size_t)km*DD + lane*8;
  float4 a = *(const float4*)r, b2 = *(const float4*)(r+4);
  float x[8] = {a.x,a.y,a.z,a.w,b2.x,b2.y,b2.z,b2.w};
  float ss=0;
  #pragma unroll
  for (int i=0;i<8;i++) ss += x[i]*x[i];
  ss = __shfl(wredf(ss),0);
  float nrm = fmaxf(sqrtf(ss), 1e-12f);
  float* pw = Pn + (size_t)km*DD + lane*8;
  half8 h;
  #pragma unroll
  for (int i=0;i<8;i++){ float vv = x[i]/nrm; pw[i]=vv; h[i]=(_Float16)vv; }
  *(half8*)(P16 + (size_t)km*DD + lane*8) = h;
}

// ================= GEMM1: C16[16384,512] = f16( A_f32 @ W16^T + b ) =================
__global__ __launch_bounds__(256) void gemm1(const float* __restrict__ Af, const _Float16* __restrict__ Bm,
    _Float16* __restrict__ Ch, const float* __restrict__ bias){
  __shared__ __align__(16) char As[128*128];
  __shared__ __align__(16) char Bs[128*128];
  const int tid = threadIdx.x;
  const int lane = tid & 63, w = tid >> 6;
  const int wr = w >> 1, wc = w & 1;
  const int lrow = lane & 15, kg = lane >> 4;
  const int id = blockIdx.x;
  const int xcd = id & 7, pos = id >> 3;
  const int m0 = ((xcd<<4) | (pos>>2)) * 128;
  const int n0 = (pos & 3) * 128;

  f32x4 acc[4][4];
  #pragma unroll
  for (int i=0;i<4;i++)
    #pragma unroll
    for (int j=0;j<4;j++){ f32x4 z = {0.f,0.f,0.f,0.f}; acc[i][j]=z; }

  for (int k0 = 0; k0 < DBB; k0 += 64){
    #pragma unroll
    for (int i=0;i<4;i++){
      int slot = (i*4 + w)*64 + lane;
      int r = slot >> 3, c = slot & 7;
      int cs = c ^ (r & 7);
      GLDS16(Bm + (size_t)(n0+r)*DBB + k0 + cs*8, Bs + (i*4+w)*1024);
    }
    #pragma unroll
    for (int i=0;i<8;i++){
      int slot = i*256 + tid;
      int r = slot >> 4, c4 = slot & 15;
      float4 v = *(const float4*)(Af + (size_t)(m0+r)*DBB + k0 + c4*4);
      half4v h; h[0]=(_Float16)v.x; h[1]=(_Float16)v.y; h[2]=(_Float16)v.z; h[3]=(_Float16)v.w;
      *(half4v*)(As + r*128 + (((c4>>1)^(r&7))<<4) + (c4&1)*8) = h;
    }
    __syncthreads();
    #pragma unroll
    for (int h=0; h<2; h++){
      half8 af[4], bf[4];
      #pragma unroll
      for (int mi=0;mi<4;mi++){
        int ar = wr*64 + mi*16 + lrow;
        af[mi] = *(const half8*)(As + ar*128 + (((h*4+kg) ^ (ar&7))<<4));
      }
      #pragma unroll
      for (int nj=0;nj<4;nj++){
        int br = wc*64 + nj*16 + lrow;
        bf[nj] = *(const half8*)(Bs + br*128 + (((h*4+kg) ^ (br&7))<<4));
      }
      #pragma unroll
      for (int mi=0;mi<4;mi++)
        #pragma unroll
        for (int nj=0;nj<4;nj++)
          acc[mi][nj] = __builtin_amdgcn_mfma_f32_16x16x32_f16(af[mi], bf[nj], acc[mi][nj], 0,0,0);
    }
    __syncthreads();
  }
  #pragma unroll
  for (int mi=0;mi<4;mi++){
    int gr = m0 + wr*64 + mi*16 + kg*4;
    #pragma unroll
    for (int nj=0;nj<4;nj++){
      int gc = n0 + wc*64 + nj*16 + lrow;
      float bv = bias[gc];
      #pragma unroll
      for (int r2=0;r2<4;r2++)
        Ch[(size_t)(gr+r2)*DD + gc] = (_Float16)(acc[mi][nj][r2] + bv);
    }
  }
}

// ================= GEMM2: PL[16384,2010] = _c @ protos^T ; fused class-max -> maxbuf ==========
// maxbuf[n][c] = atomicMax over encoded uint asuint(max_m cos + 4.0f)  (|cos|<=1.02 -> +4 > 0,
// asuint monotone on positives; zero-init decodes to -4).  Each block maxes over cols it owns;
// atomicMax merges partials across N-tiles (1-2 writers per address).
__global__ __launch_bounds__(256) void gemm2(const _Float16* __restrict__ Am, const _Float16* __restrict__ Bm,
    float* __restrict__ Cf, unsigned int* __restrict__ maxbuf){
  __shared__ __align__(16) char smem[32768];
  char* As = smem;
  char* Bs = smem + 16384;
  const int tid = threadIdx.x;
  const int lane = tid & 63, w = tid >> 6;
  const int wr = w >> 1, wc = w & 1;
  const int lrow = lane & 15, kg = lane >> 4;
  const int id = blockIdx.x;
  const int xcd = id & 7, pos = id >> 3;
  const int m0 = ((xcd<<4) | (pos>>4)) * 128;
  const int n0 = (pos & 15) * 128;

  f32x4 acc[4][4];
  #pragma unroll
  for (int i=0;i<4;i++)
    #pragma unroll
    for (int j=0;j<4;j++){ f32x4 z = {0.f,0.f,0.f,0.f}; acc[i][j]=z; }

  for (int k0 = 0; k0 < DD; k0 += 64){
    #pragma unroll
    for (int i=0;i<4;i++){
      int slot = (i*4 + w)*64 + lane;
      int r = slot >> 3, c = slot & 7;
      int cs = c ^ (r & 7);
      GLDS16(Am + (size_t)(m0+r)*DD + k0 + cs*8, As + (i*4+w)*1024);
      GLDS16(Bm + (size_t)(n0+r)*DD + k0 + cs*8, Bs + (i*4+w)*1024);
    }
    __syncthreads();
    #pragma unroll
    for (int h=0; h<2; h++){
      half8 af[4], bf[4];
      #pragma unroll
      for (int mi=0;mi<4;mi++){
        int ar = wr*64 + mi*16 + lrow;
        af[mi] = *(const half8*)(As + ar*128 + (((h*4+kg) ^ (ar&7))<<4));
      }
      #pragma unroll
      for (int nj=0;nj<4;nj++){
        int br = wc*64 + nj*16 + lrow;
        bf[nj] = *(const half8*)(Bs + br*128 + (((h*4+kg) ^ (br&7))<<4));
      }
      #pragma unroll
      for (int mi=0;mi<4;mi++)
        #pragma unroll
        for (int nj=0;nj<4;nj++)
          acc[mi][nj] = __builtin_amdgcn_mfma_f32_16x16x32_f16(af[mi], bf[nj], acc[mi][nj], 0,0,0);
    }
    __syncthreads();
  }
  // ---- PL write ----
  #pragma unroll
  for (int mi=0;mi<4;mi++){
    int gr = m0 + wr*64 + mi*16 + kg*4;
    #pragma unroll
    for (int nj=0;nj<4;nj++){
      int gc = n0 + wc*64 + nj*16 + lrow;
      if (gc < KM){
        #pragma unroll
        for (int r2=0;r2<4;r2++)
          Cf[(size_t)(gr+r2)*KM + gc] = acc[mi][nj][r2];
      }
    }
  }
  // ---- fused class-max: stage 64x128 halves in LDS (K-loop done; smem free) ----
  float* lsf = (float*)smem;                  // 64*128*4 = 32768 B
  const int cLo = n0/10;
  const int cHi = (n0+127)/10 > 200 ? 200 : (n0+127)/10;
  const int nC = cHi - cLo + 1;
  #pragma unroll
  for (int h=0; h<2; ++h){
    __syncthreads();
    if (wr == h){
      #pragma unroll
      for (int mi=0;mi<4;mi++){
        int lr = mi*16 + kg*4;
        #pragma unroll
        for (int nj=0;nj<4;nj++){
          int col = wc*64 + nj*16 + lrow;
          #pragma unroll
          for (int r2=0;r2<4;r2++) lsf[(lr+r2)*128 + col] = acc[mi][nj][r2];
        }
      }
    }
    __syncthreads();
    for (int t = tid; t < 64*nC; t += 256){
      int row = t / nC, c = cLo + t % nC;
      int lo = c*10;     if (lo < n0) lo = n0;
      int hi = c*10+9;   if (hi > n0+127) hi = n0+127;
      float mx = lsf[row*128 + (lo-n0)];
      for (int cc2 = lo+1; cc2 <= hi; ++cc2) mx = fmaxf(mx, lsf[row*128 + (cc2-n0)]);
      atomicMax(&maxbuf[(size_t)(m0 + h*64 + row)*KC + c], __float_as_uint(mx + 4.0f));
    }
  }
}

// ================= LN + l2 normalize (in-place on C16) =================
__global__ __launch_bounds__(256) void kLNl2n(_Float16* __restrict__ C16,
      const float* __restrict__ fg, const float* __restrict__ fb){
  int w=threadIdx.x>>6, lane=threadIdx.x&63;
  int n = blockIdx.x*4 + w;
  _Float16* row = C16 + (size_t)n*DD + lane*8;
  half8 h = *(const half8*)row;
  float x[8];
  #pragma unroll
  for (int i=0;i<8;i++) x[i] = (float)h[i];
  float s=0;
  #pragma unroll
  for (int i=0;i<8;i++) s += x[i];
  float mu = __shfl(wredf(s),0)/512.f;
  float q=0;
  #pragma unroll
  for (int i=0;i<8;i++){ float d=x[i]-mu; q+=d*d; }
  float var = __shfl(wredf(q),0)/512.f;
  float inv = 1.f/sqrtf(var+1e-5f);
  float4 g0 = *(const float4*)(fg+lane*8), g1 = *(const float4*)(fg+lane*8+4);
  float4 b0 = *(const float4*)(fb+lane*8), b1 = *(const float4*)(fb+lane*8+4);
  float gg[8] = {g0.x,g0.y,g0.z,g0.w,g1.x,g1.y,g1.z,g1.w};
  float bb[8] = {b0.x,b0.y,b0.z,b0.w,b1.x,b1.y,b1.z,b1.w};
  float y[8]; float ss=0;
  #pragma unroll
  for (int i=0;i<8;i++){ y[i] = (x[i]-mu)*inv*gg[i]+bb[i]; ss += y[i]*y[i]; }
  float nrm = fmaxf(sqrtf(__shfl(wredf(ss),0)), 1e-12f);
  half8 o;
  #pragma unroll
  for (int i=0;i<8;i++) o[i] = (_Float16)(y[i]/nrm);
  *(half8*)row = o;
}

// ===== per-class max (from maxbuf) + mask LN + pred + transpose-out + sinkhorn Qd/row0 =====
__global__ __launch_bounds__(256) void kMaxSK(const unsigned int* __restrict__ maxbuf,
    const float* __restrict__ PL, const float* __restrict__ mg,
    const float* __restrict__ mb, const int* __restrict__ gtseg, const int* __restrict__ gt,
    float* __restrict__ outseg, int* __restrict__ corr, float* __restrict__ Qd, float* __restrict__ row16){
  __shared__ float tile[16][205];
  __shared__ float qpart[10][2];
  int tid=threadIdx.x, lane=tid&63, w=tid>>6;
  int n0 = blockIdx.x*16;
  int b = n0>>10, hw0 = n0&1023;
  int c0 = gt[b];
  if (tid<20) qpart[tid>>1][tid&1]=0.f;
  __syncthreads();
  for (int r=0;r<16;r++){
    int n = n0 + r;
    int g = gtseg[n];
    if (tid < KC){
      tile[r][tid] = __uint_as_float(maxbuf[(size_t)n*KC + tid]) - 4.0f;
      if (tid == g){
        const float* src = PL + (size_t)n*KM + g*10;
        int cl = (g==200)?1:0;
        #pragma unroll
        for (int m2=0;m2<5;m2++){
          float2 t2 = *(const float2*)(src + m2*2);
          float e0 = expf(t2.x*20.f), e1 = expf(t2.y*20.f);
          Qd[(size_t)n*10+m2*2]   = e0;
          Qd[(size_t)n*10+m2*2+1] = e1;
          atomicAdd(&qpart[m2*2][cl], e0);
          atomicAdd(&qpart[m2*2+1][cl], e1);
        }
      }
    }
  }
  __syncthreads();
  for (int rr=0; rr<4; ++rr){
    int r = w*4 + rr;
    int n = n0 + r;
    float xv[4]; int ncl=0;
    for (int c=lane;c<KC;c+=64) xv[ncl++] = tile[r][c];
    float ps=0;
    for (int i=0;i<ncl;i++) ps += xv[i];
    float mu = __shfl(wredf(ps),0)*(1.f/201.f);
    float pv=0;
    for (int i=0;i<ncl;i++){ float d=xv[i]-mu; pv+=d*d; }
    float var = __shfl(wredf(pv),0)*(1.f/201.f);
    float inv = 1.f/sqrtf(var+1e-5f);
    float bv=-3.0e38f; int bi=1<<30;
    ncl=0;
    for (int c=lane;c<KC;c+=64){
      float o = (xv[ncl]-mu)*inv*mg[c]+mb[c]; ncl++;
      tile[r][c] = o;
      if (o>bv){ bv=o; bi=c; }
    }
    #pragma unroll
    for (int o2=32;o2;o2>>=1){
      float ov=__shfl_down(bv,o2); int oi=__shfl_down(bi,o2);
      if (ov>bv||(ov==bv&&oi<bi)){bv=ov;bi=oi;}
    }
    if (lane==0) corr[n] = (bi==gtseg[n])?1:0;
  }
  __syncthreads();
  if (tid<20){
    int m=tid>>1, cl=tid&1;
    atomicAdd(&row16[(size_t)(blockIdx.x&15)*2016 + m*KC + (cl?200:c0)], qpart[m][cl]);
  }
  for (int idx=tid; idx<KC*16; idx+=256){
    int c=idx>>4, j=idx&15;
    outseg[(((size_t)b*KC+c)<<10) + hw0 + j] = tile[j][c];
  }
}

// one sinkhorn iteration; rin has rin_parts partial buffers of stride 2016
__global__ __launch_bounds__(256) void kSKpass(float* __restrict__ Qd, const int* __restrict__ gtseg,
      const int* __restrict__ gt, const float* __restrict__ rin, int rin_parts,
      float* __restrict__ rout, const int* __restrict__ Bk){
  __shared__ float rin2[10][2];
  __shared__ double part[4][10][2];
  int n = blockIdx.x*256+threadIdx.x;
  int c0 = gt[blockIdx.x>>2];
  if (threadIdx.x < 20){
    int m = threadIdx.x>>1, cl = threadIdx.x&1;
    int cls = cl?200:c0;
    float s=0;
    for (int p=0;p<rin_parts;p++) s += rin[(size_t)p*2016 + m*KC + cls];
    rin2[m][cl]=s;
  }
  __syncthreads();
  int g = gtseg[n];
  int cl = (g==200)?1:0;
  double q[10]; double col=0.0;
  #pragma unroll
  for (int m=0;m<10;m++){
    double r = (double)rin2[m][cl];
    double t = (double)Qd[(size_t)n*10+m];
    if (r>0.0) t = t/r;
    t = t/10.0;
    q[m]=t; col+=t;
  }
  double cs = (col>0.0)? col : 1.0;
  int bk = Bk[g];
  double bs = (bk>0)? (double)bk : 1.0;
  double inv = 1.0/(cs*bs);
  int w=threadIdx.x>>6, lane=threadIdx.x&63;
  #pragma unroll
  for (int m=0;m<10;m++){
    double t = q[m]*inv;
    Qd[(size_t)n*10+m] = (float)t;
    double p0 = (g==c0)? t:0.0;
    double p1 = (g==200)? t:0.0;
    p0=wredd(p0); p1=wredd(p1);
    if (lane==0){ part[w][m][0]=p0; part[w][m][1]=p1; }
  }
  __syncthreads();
  if (threadIdx.x < 20){
    int m = threadIdx.x>>1, cl2 = threadIdx.x&1;
    double t = part[0][m][cl2]+part[1][m][cl2]+part[2][m][cl2]+part[3][m][cl2];
    atomicAdd(&rout[m*KC + (cl2?200:c0)], (float)t);
  }
}

// fused final argmax + proto_target write + EMA accumulation (wave per pixel)
__global__ __launch_bounds__(256) void kSKEMA(const float* __restrict__ Qd, const int* __restrict__ gtseg,
      const float* __restrict__ r5, const int* __restrict__ corr, const _Float16* __restrict__ C16,
      float* __restrict__ outPT, float* __restrict__ fproto, int* __restrict__ ncnt){
  int w=threadIdx.x>>6, lane=threadIdx.x&63;
  int n = blockIdx.x*4+w;
  int g = gtseg[n];
  float tv = -1.0f;
  if (lane<10){
    float r = r5[lane*KC+g];
    float t = Qd[(size_t)n*10+lane];
    if (r>0.f) t = t/r;
    tv = t*0.1f;
  }
  float bv = tv; int bi = lane;
  #pragma unroll
  for (int o=8;o;o>>=1){
    float ov = __shfl_down(bv,o); int oi = __shfl_down(bi,o);
    if (ov>bv || (ov==bv && oi<bi)){ bv=ov; bi=oi; }
  }
  bi = __shfl(bi, 0);
  if (lane==0) outPT[n] = (float)(bi + 10*g);
  if (corr[n]){
    half8 hc = *(const half8*)(C16 + (size_t)n*DD + lane*8);
    float* dst = fproto + ((size_t)g*10+bi)*DD + lane*8;
    #pragma unroll
    for (int i=0;i<8;i++) atomicAdd(dst+i, (float)hc[i]);
    if (lane==0) atomicAdd(&ncnt[g*10+bi], 1);
  }
}

__global__ __launch_bounds__(256) void kEMAfin(const float* __restrict__ fproto, const int* __restrict__ ncnt,
     const float* __restrict__ Pn, float* __restrict__ outNP){
  int w=threadIdx.x>>6, lane=threadIdx.x&63;
  int km = blockIdx.x*4+w;
  if (km>=KM) return;
  const float* fr = fproto + (size_t)km*DD + lane*8;
  float fp[8]; float ss=0;
  #pragma unroll
  for (int i=0;i<8;i++){ fp[i]=fr[i]; ss+=fp[i]*fp[i]; }
  float n1 = fmaxf(sqrtf(__shfl(wredf(ss),0)), 1e-12f);
  int cnt = ncnt[km];
  const float* pr = Pn + (size_t)km*DD + lane*8;
  float t[8]; float s2=0;
  #pragma unroll
  for (int i=0;i<8;i++){
    float pv = pr[i];
    float tv = cnt ? (0.999f*pv + 0.001f*(fp[i]/n1)) : pv;
    t[i]=tv; s2+=tv*tv;
  }
  float n2 = fmaxf(sqrtf(__shfl(wredf(s2),0)), 1e-12f);
  float* dst = outNP + (size_t)km*DD + lane*8;
  #pragma unroll
  for (int i=0;i<8;i++) dst[i] = t[i]/n2;
}

// ================= launch =================
extern "C" void kernel_launch(void* const* d_in, const int* in_sizes, int n_in,
                              void* d_out, int out_size, void* d_ws, size_t ws_size,
                              hipStream_t stream) {
  const float* A   = (const float*)d_in[0];
  const int*   gt  = (const int*)d_in[1];
  const float* Wp  = (const float*)d_in[2];
  const float* pb  = (const float*)d_in[3];
  const float* fg  = (const float*)d_in[4];
  const float* fb  = (const float*)d_in[5];
  const float* mg  = (const float*)d_in[6];
  const float* mb  = (const float*)d_in[7];
  const float* PR  = (const float*)d_in[8];
  float* out = (float*)d_out;
  char* ws = (char*)d_ws;

  double* xch    = (double*)(ws+OFF_XCH);
  double* Tp     = (double*)(ws+OFF_TP);
  double* colp   = (double*)(ws+OFF_COLP);
  float*  row16  = (float*)(ws+OFF_ROW16);
  float*  row3   = (float*)(ws+OFF_ROW3);
  float*  row5   = (float*)(ws+OFF_ROW5);
  int*    Bk     = (int*)(ws+OFF_BK);
  int*    ncnt   = (int*)(ws+OFF_NCNT);
  float*  fproto = (float*)(ws+OFF_FPROTO);
  unsigned int* maxbuf = (unsigned int*)(ws+OFF_MAXB);
  int*    gtseg  = (int*)(ws+OFF_GTSEG);
  int*    corr   = (int*)(ws+OFF_CORR);
  double* u      = (double*)(ws+OFF_U);
  float*  Pn     = (float*)(ws+OFF_PN);
  _Float16* P16  = (_Float16*)(ws+OFF_P16);
  _Float16* C16  = (_Float16*)(ws+OFF_C16);
  float*  Qd     = (float*)(ws+OFF_QD);
  _Float16* W16  = (_Float16*)(ws+OFF_W16);

  // single memset: all atomic accumulators + maxbuf
  hipMemsetAsync(ws, 0, ZTOTAL, stream);

  // ---- PCA pseudo-gt: 10 passes (broadcast-partial setup) + u + fin ----
  kPIter2<true><<<1024,256,0,stream>>>(A, nullptr, nullptr, nullptr, xch, Tp, colp);
  for (int t=1;t<10;t++){
    kPIter2<false><<<1024,256,0,stream>>>(A, xch+(size_t)(t-1)*8*768, Tp+(t-1)*8, colp,
                                          xch+(size_t)t*8*768, Tp+t*8, nullptr);
  }
  kPU2<<<1024,256,0,stream>>>(A, xch+(size_t)9*8*768, Tp+9*8, colp, u);
  kFin<<<1,1024,0,stream>>>(u, gt, out+OUT_PG, gtseg, Bk);

  // ---- prep: W conv + proto normalize ----
  kPrep<<<896,256,0,stream>>>(Wp, W16, PR, Pn, P16);

  // ---- GEMM1 (f32 A, fused convert) + LN+l2n ----
  gemm1<<<512,256,0,stream>>>(A, W16, C16, pb);
  kLNl2n<<<4096,256,0,stream>>>(C16, fg, fb);

  // ---- GEMM2: proto_logits + fused class-max ----
  gemm2<<<2048,256,0,stream>>>(C16, P16, out+OUT_PL, maxbuf);

  // ---- max/LN/pred/transpose (reads 13MB maxbuf) + sinkhorn row0 ----
  kMaxSK<<<1024,256,0,stream>>>(maxbuf, out+OUT_PL, mg, mb, gtseg, gt, out+OUT_SEG, corr, Qd, row16);

  // ---- sinkhorn passes + fused argmax/EMA ----
  kSKpass<<<64,256,0,stream>>>(Qd, gtseg, gt, row16, 16, row3, Bk);
  kSKpass<<<64,256,0,stream>>>(Qd, gtseg, gt, row3, 1, row5, Bk);
  kSKEMA<<<4096,256,0,stream>>>(Qd, gtseg, row5, corr, C16, out+OUT_PT, fproto, ncnt);

  // ---- EMA finalize ----
  kEMAfin<<<503,256,0,stream>>>(fproto, ncnt, Pn, out+OUT_NP);
}

// Round 10
// 427.722 us; speedup vs baseline: 1.2765x; 1.0064x over previous
//
#include <hip/hip_runtime.h>
#include <cstdint>
#include <cstddef>

typedef _Float16 half8  __attribute__((ext_vector_type(8)));
typedef _Float16 half4v __attribute__((ext_vector_type(4)));
typedef float    f32x4  __attribute__((ext_vector_type(4)));

static constexpr int HWPX = 1024;
static constexpr int NPX  = 16384;
static constexpr int DBB  = 768;
static constexpr int DD   = 512;
static constexpr int KC   = 201;
static constexpr int KM   = 2010;   // KC * 10
static constexpr int KMP  = 2048;   // padded

// ---- workspace offsets (bytes) ----
static constexpr size_t OFF_XCH    = 0;        // [10][8][768] f64 W partials (atomic)
static constexpr size_t OFF_TP     = 491520;   // [10][8] f64 T partials (atomic)
static constexpr size_t OFF_COLP   = 492160;   // [8][768] f64 colsum partials (atomic)
static constexpr size_t OFF_ROW16  = 541312;   // [16][2016] f32
static constexpr size_t OFF_ROW3   = 670336;   // [2016] f32
static constexpr size_t OFF_ROW5   = 678400;   // [2016] f32
static constexpr size_t OFF_BK     = 686464;   // 256 i32
static constexpr size_t OFF_NCNT   = 687488;   // 2016 i32
static constexpr size_t OFF_FPROTO = 695552;   // 2010*512 f32
static constexpr size_t OFF_MAXB   = 4812032;  // 16384*201 u32 encoded class-max
static constexpr size_t ZTOTAL     = 17984768; // single memset covers all above
static constexpr size_t OFF_GTSEG  = 17984768; // 16384 i32
static constexpr size_t OFF_CORR   = 18050304; // 16384 i32
static constexpr size_t OFF_U      = 18115840; // 16384 f64
static constexpr size_t OFF_PN     = 18246912; // 2010*512 f32
static constexpr size_t OFF_P16    = 22363392; // 2048*512 f16
static constexpr size_t OFF_C16    = 24460544; // 16384*512 f16
static constexpr size_t OFF_QD     = 41237760; // 16384*10 f32
static constexpr size_t OFF_W16    = 41893120; // 512*768 f16 (end ~42.7MB << ws)

// ---- d_out offsets (floats) ----
static constexpr size_t OUT_SEG = 0;
static constexpr size_t OUT_PL  = 3293184;
static constexpr size_t OUT_PT  = 36225024;
static constexpr size_t OUT_PG  = 36241408;
static constexpr size_t OUT_NP  = 36257792;

#define GLDS16(gp, lp) __builtin_amdgcn_global_load_lds( \
    (__attribute__((address_space(1))) const void*)(gp), \
    (__attribute__((address_space(3))) void*)(lp), 16, 0, 0)

static __device__ __forceinline__ float  wredf(float x){
  #pragma unroll
  for (int o=32;o;o>>=1) x += __shfl_down(x,o);
  return x;
}
static __device__ __forceinline__ double wredd(double x){
  #pragma unroll
  for (int o=32;o;o>>=1) x += __shfl_down(x,o);
  return x;
}

// ================= PCA =================
// y = Ac^T Ac x = A^T(Ax) - m*sum(Ax); vs_next reconstructed per-block from broadcast-cached
// partials.  A loads VECTORIZED float4 (G13): lane owns cols {chunk*256 + 4*lane + e}.
// FIRST pass also colsums.  f64 order differs from scalar version: any-order f64 dev ~1e-13
// << 1.8e-5 pseudo-gt margin.
template<bool FIRST>
__global__ __launch_bounds__(256) void kPIter2(const float* __restrict__ A,
    const double* __restrict__ Win, const double* __restrict__ Tin, const double* __restrict__ colp,
    double* __restrict__ Wout, double* __restrict__ Tout, double* __restrict__ colout){
  __shared__ double vs[768];
  __shared__ double red[4][12][64];
  __shared__ double sT[4];
  int tid=threadIdx.x, lane=tid&63, w=tid>>6;
  if (FIRST){
    for (int cc=tid; cc<768; cc+=256) vs[cc] = 1.0/sqrt(768.0);
  } else {
    double Ts=0.0;
    #pragma unroll
    for (int p=0;p<8;p++) Ts += Tin[p];
    for (int cc=tid; cc<768; cc+=256){
      double sw=0.0, mc=0.0;
      #pragma unroll
      for (int p=0;p<8;p++){ sw += Win[p*768+cc]; mc += colp[p*768+cc]; }
      vs[cc] = sw - mc*(1.0/16384.0)*Ts;
    }
  }
  __syncthreads();
  double vsr[12];
  #pragma unroll
  for (int ch=0;ch<3;ch++)
    #pragma unroll
    for (int e=0;e<4;e++) vsr[ch*4+e] = vs[ch*256 + lane*4 + e];
  int rbase = blockIdx.x*16 + w*4;
  const float* Ab = A + (size_t)rbase*DBB + lane*4;
  double acc[12], cacc[12]; double tloc=0.0;
  #pragma unroll
  for (int j=0;j<12;j++){ acc[j]=0.0; cacc[j]=0.0; }
  #pragma unroll
  for (int i=0;i<4;i++){
    const float* Ar = Ab + (size_t)i*DBB;
    float4 f0 = *(const float4*)(Ar);
    float4 f1 = *(const float4*)(Ar + 256);
    float4 f2 = *(const float4*)(Ar + 512);
    double a[12] = {(double)f0.x,(double)f0.y,(double)f0.z,(double)f0.w,
                    (double)f1.x,(double)f1.y,(double)f1.z,(double)f1.w,
                    (double)f2.x,(double)f2.y,(double)f2.z,(double)f2.w};
    double wp=0.0;
    #pragma unroll
    for (int j=0;j<12;j++) wp += a[j]*vsr[j];
    wp = wredd(wp); wp = __shfl(wp,0);
    #pragma unroll
    for (int j=0;j<12;j++) acc[j] += wp*a[j];
    if (FIRST){
      #pragma unroll
      for (int j=0;j<12;j++) cacc[j] += a[j];
    }
    tloc += wp;
  }
  #pragma unroll
  for (int j=0;j<12;j++) red[w][j][lane]=acc[j];
  if (lane==0) sT[w]=tloc;
  __syncthreads();
  double* dst = Wout + (size_t)(blockIdx.x&7)*768;
  for (int cc=tid; cc<768; cc+=256){
    int chv=cc>>8, rem=cc&255, l=rem>>2, e=rem&3, j=chv*4+e;
    atomicAdd(&dst[cc], red[0][j][l]+red[1][j][l]+red[2][j][l]+red[3][j][l]);
  }
  if (tid==0) atomicAdd(&Tout[blockIdx.x&7], sT[0]+sT[1]+sT[2]+sT[3]);
  if (FIRST){
    __syncthreads();
    #pragma unroll
    for (int j=0;j<12;j++) red[w][j][lane]=cacc[j];
    __syncthreads();
    double* cdst = colout + (size_t)(blockIdx.x&7)*768;
    for (int cc=tid; cc<768; cc+=256){
      int chv=cc>>8, rem=cc&255, l=rem>>2, e=rem&3, j=chv*4+e;
      atomicAdd(&cdst[cc], red[0][j][l]+red[1][j][l]+red[2][j][l]+red[3][j][l]);
    }
  }
}

// u = Ac v = A v - (m^T v):  v reconstructed from pass-10 partials; float4 A loads.
__global__ __launch_bounds__(256) void kPU2(const float* __restrict__ A, const double* __restrict__ Wp,
    const double* __restrict__ Tp, const double* __restrict__ colp, double* __restrict__ u){
  __shared__ double vs[768];
  __shared__ double sS[4];
  int tid=threadIdx.x, lane=tid&63, w=tid>>6;
  double Ts=0.0;
  #pragma unroll
  for (int p=0;p<8;p++) Ts += Tp[p];
  double sloc=0.0;
  for (int cc=tid; cc<768; cc+=256){
    double sw=0.0, mc=0.0;
    #pragma unroll
    for (int p=0;p<8;p++){ sw += Wp[p*768+cc]; mc += colp[p*768+cc]; }
    double m = mc*(1.0/16384.0);
    double v = sw - m*Ts;
    vs[cc] = v;
    sloc += m*v;
  }
  sloc = wredd(sloc);
  if (lane==0) sS[w]=sloc;
  __syncthreads();
  double s = sS[0]+sS[1]+sS[2]+sS[3];
  double vsr[12];
  #pragma unroll
  for (int ch=0;ch<3;ch++)
    #pragma unroll
    for (int e=0;e<4;e++) vsr[ch*4+e] = vs[ch*256 + lane*4 + e];
  int rbase = blockIdx.x*16 + w*4;
  const float* Ab = A + (size_t)rbase*DBB + lane*4;
  #pragma unroll
  for (int i=0;i<4;i++){
    const float* Ar = Ab + (size_t)i*DBB;
    float4 f0 = *(const float4*)(Ar);
    float4 f1 = *(const float4*)(Ar + 256);
    float4 f2 = *(const float4*)(Ar + 512);
    double a[12] = {(double)f0.x,(double)f0.y,(double)f0.z,(double)f0.w,
                    (double)f1.x,(double)f1.y,(double)f1.z,(double)f1.w,
                    (double)f2.x,(double)f2.y,(double)f2.z,(double)f2.w};
    double wp=0.0;
    #pragma unroll
    for (int j=0;j<12;j++) wp += a[j]*vsr[j];
    wp = wredd(wp);
    if (lane==0) u[rbase+i] = wp - s;
  }
}

// fused global minmax + pseudo-gt + Bk (single block)
__global__ __launch_bounds__(1024) void kFin(const double* __restrict__ u, const int* __restrict__ gt,
      float* __restrict__ outPG, int* __restrict__ gtseg, int* __restrict__ Bk){
  __shared__ double smn[16], smx[16];
  __shared__ double sres[2];
  int t = threadIdx.x;
  double mn=1e300, mx=-1e300;
  for (int k=0;k<16;k++){ double x=u[k*1024+t]; mn=fmin(mn,x); mx=fmax(mx,x); }
  #pragma unroll
  for (int o=32;o;o>>=1){ mn=fmin(mn,__shfl_down(mn,o)); mx=fmax(mx,__shfl_down(mx,o)); }
  if ((t&63)==0){ smn[t>>6]=mn; smx[t>>6]=mx; }
  __syncthreads();
  if (t==0){
    for (int i=1;i<16;i++){ mn=fmin(mn,smn[i]); mx=fmax(mx,smx[i]); }
    sres[0]=mn; sres[1]=mx;
  }
  __syncthreads();
  mn=sres[0]; mx=sres[1];
  double inv = 1.0/(mx-mn);
  for (int k=0;k<16;k++){
    int n = k*1024 + t;
    int c0 = gt[k];
    double us = (u[n]-mn)*inv;
    int g = (us < 0.5) ? c0 : 200;
    outPG[n] = (float)g;
    gtseg[n] = g;
    unsigned long long b0 = __ballot(g==c0);
    unsigned long long b1 = __ballot(g==200);
    if ((t&63)==0){
      atomicAdd(&Bk[c0], (int)__popcll(b0));
      atomicAdd(&Bk[200], (int)__popcll(b1));
    }
  }
}

// ================= prep: W f32->f16 (blocks 0..383) + proto l2-normalize (blocks 384..895) =================
__global__ __launch_bounds__(256) void kPrep(const float* __restrict__ Wp, _Float16* __restrict__ W16,
    const float* __restrict__ PR, float* __restrict__ Pn, _Float16* __restrict__ P16){
  int b = blockIdx.x;
  if (b < 384){
    int i = b*256 + threadIdx.x;
    float4 vv = ((const float4*)Wp)[i];
    half4v h; h[0]=(_Float16)vv.x; h[1]=(_Float16)vv.y; h[2]=(_Float16)vv.z; h[3]=(_Float16)vv.w;
    ((half4v*)W16)[i] = h;
    return;
  }
  int w=threadIdx.x>>6, lane=threadIdx.x&63;
  int km = (b-384)*4 + w;
  if (km >= KM){
    if (km < KMP){
      half8 z;
      #pragma unroll
      for (int i=0;i<8;i++) z[i]=(_Float16)0.0f;
      *(half8*)(P16 + (size_t)km*DD + lane*8) = z;
    }
    return;
  }
  const float* r = PR + (size_t)km*DD + lane*8;
  float4 a = *(const float4*)r, b2 = *(const float4*)(r+4);
  float x[8] = {a.x,a.y,a.z,a.w,b2.x,b2.y,b2.z,b2.w};
  float ss=0;
  #pragma unroll
  for (int i=0;i<8;i++) ss += x[i]*x[i];
  ss = __shfl(wredf(ss),0);
  float nrm = fmaxf(sqrtf(ss), 1e-12f);
  float* pw = Pn + (size_t)km*DD + lane*8;
  half8 h;
  #pragma unroll
  for (int i=0;i<8;i++){ float vv = x[i]/nrm; pw[i]=vv; h[i]=(_Float16)vv; }
  *(half8*)(P16 + (size_t)km*DD + lane*8) = h;
}

// ================= GEMM1: C16[16384,512] = f16( A_f32 @ W16^T + b ) =================
__global__ __launch_bounds__(256) void gemm1(const float* __restrict__ Af, const _Float16* __restrict__ Bm,
    _Float16* __restrict__ Ch, const float* __restrict__ bias){
  __shared__ __align__(16) char As[128*128];
  __shared__ __align__(16) char Bs[128*128];
  const int tid = threadIdx.x;
  const int lane = tid & 63, w = tid >> 6;
  const int wr = w >> 1, wc = w & 1;
  const int lrow = lane & 15, kg = lane >> 4;
  const int id = blockIdx.x;
  const int xcd = id & 7, pos = id >> 3;
  const int m0 = ((xcd<<4) | (pos>>2)) * 128;
  const int n0 = (pos & 3) * 128;

  f32x4 acc[4][4];
  #pragma unroll
  for (int i=0;i<4;i++)
    #pragma unroll
    for (int j=0;j<4;j++){ f32x4 z = {0.f,0.f,0.f,0.f}; acc[i][j]=z; }

  for (int k0 = 0; k0 < DBB; k0 += 64){
    #pragma unroll
    for (int i=0;i<4;i++){
      int slot = (i*4 + w)*64 + lane;
      int r = slot >> 3, c = slot & 7;
      int cs = c ^ (r & 7);
      GLDS16(Bm + (size_t)(n0+r)*DBB + k0 + cs*8, Bs + (i*4+w)*1024);
    }
    #pragma unroll
    for (int i=0;i<8;i++){
      int slot = i*256 + tid;
      int r = slot >> 4, c4 = slot & 15;
      float4 v = *(const float4*)(Af + (size_t)(m0+r)*DBB + k0 + c4*4);
      half4v h; h[0]=(_Float16)v.x; h[1]=(_Float16)v.y; h[2]=(_Float16)v.z; h[3]=(_Float16)v.w;
      *(half4v*)(As + r*128 + (((c4>>1)^(r&7))<<4) + (c4&1)*8) = h;
    }
    __syncthreads();
    #pragma unroll
    for (int h=0; h<2; h++){
      half8 af[4], bf[4];
      #pragma unroll
      for (int mi=0;mi<4;mi++){
        int ar = wr*64 + mi*16 + lrow;
        af[mi] = *(const half8*)(As + ar*128 + (((h*4+kg) ^ (ar&7))<<4));
      }
      #pragma unroll
      for (int nj=0;nj<4;nj++){
        int br = wc*64 + nj*16 + lrow;
        bf[nj] = *(const half8*)(Bs + br*128 + (((h*4+kg) ^ (br&7))<<4));
      }
      #pragma unroll
      for (int mi=0;mi<4;mi++)
        #pragma unroll
        for (int nj=0;nj<4;nj++)
          acc[mi][nj] = __builtin_amdgcn_mfma_f32_16x16x32_f16(af[mi], bf[nj], acc[mi][nj], 0,0,0);
    }
    __syncthreads();
  }
  #pragma unroll
  for (int mi=0;mi<4;mi++){
    int gr = m0 + wr*64 + mi*16 + kg*4;
    #pragma unroll
    for (int nj=0;nj<4;nj++){
      int gc = n0 + wc*64 + nj*16 + lrow;
      float bv = bias[gc];
      #pragma unroll
      for (int r2=0;r2<4;r2++)
        Ch[(size_t)(gr+r2)*DD + gc] = (_Float16)(acc[mi][nj][r2] + bv);
    }
  }
}

// ================= GEMM2: PL[16384,2010] = _c @ protos^T ; fused class-max -> maxbuf ==========
__global__ __launch_bounds__(256) void gemm2(const _Float16* __restrict__ Am, const _Float16* __restrict__ Bm,
    float* __restrict__ Cf, unsigned int* __restrict__ maxbuf){
  __shared__ __align__(16) char smem[32768];
  char* As = smem;
  char* Bs = smem + 16384;
  const int tid = threadIdx.x;
  const int lane = tid & 63, w = tid >> 6;
  const int wr = w >> 1, wc = w & 1;
  const int lrow = lane & 15, kg = lane >> 4;
  const int id = blockIdx.x;
  const int xcd = id & 7, pos = id >> 3;
  const int m0 = ((xcd<<4) | (pos>>4)) * 128;
  const int n0 = (pos & 15) * 128;

  f32x4 acc[4][4];
  #pragma unroll
  for (int i=0;i<4;i++)
    #pragma unroll
    for (int j=0;j<4;j++){ f32x4 z = {0.f,0.f,0.f,0.f}; acc[i][j]=z; }

  for (int k0 = 0; k0 < DD; k0 += 64){
    #pragma unroll
    for (int i=0;i<4;i++){
      int slot = (i*4 + w)*64 + lane;
      int r = slot >> 3, c = slot & 7;
      int cs = c ^ (r & 7);
      GLDS16(Am + (size_t)(m0+r)*DD + k0 + cs*8, As + (i*4+w)*1024);
      GLDS16(Bm + (size_t)(n0+r)*DD + k0 + cs*8, Bs + (i*4+w)*1024);
    }
    __syncthreads();
    #pragma unroll
    for (int h=0; h<2; h++){
      half8 af[4], bf[4];
      #pragma unroll
      for (int mi=0;mi<4;mi++){
        int ar = wr*64 + mi*16 + lrow;
        af[mi] = *(const half8*)(As + ar*128 + (((h*4+kg) ^ (ar&7))<<4));
      }
      #pragma unroll
      for (int nj=0;nj<4;nj++){
        int br = wc*64 + nj*16 + lrow;
        bf[nj] = *(const half8*)(Bs + br*128 + (((h*4+kg) ^ (br&7))<<4));
      }
      #pragma unroll
      for (int mi=0;mi<4;mi++)
        #pragma unroll
        for (int nj=0;nj<4;nj++)
          acc[mi][nj] = __builtin_amdgcn_mfma_f32_16x16x32_f16(af[mi], bf[nj], acc[mi][nj], 0,0,0);
    }
    __syncthreads();
  }
  // ---- PL write ----
  #pragma unroll
  for (int mi=0;mi<4;mi++){
    int gr = m0 + wr*64 + mi*16 + kg*4;
    #pragma unroll
    for (int nj=0;nj<4;nj++){
      int gc = n0 + wc*64 + nj*16 + lrow;
      if (gc < KM){
        #pragma unroll
        for (int r2=0;r2<4;r2++)
          Cf[(size_t)(gr+r2)*KM + gc] = acc[mi][nj][r2];
      }
    }
  }
  // ---- fused class-max: stage 64x128 halves in LDS (K-loop done; smem free) ----
  float* lsf = (float*)smem;                  // 64*128*4 = 32768 B
  const int cLo = n0/10;
  const int cHi = (n0+127)/10 > 200 ? 200 : (n0+127)/10;
  const int nC = cHi - cLo + 1;
  #pragma unroll
  for (int h=0; h<2; ++h){
    __syncthreads();
    if (wr == h){
      #pragma unroll
      for (int mi=0;mi<4;mi++){
        int lr = mi*16 + kg*4;
        #pragma unroll
        for (int nj=0;nj<4;nj++){
          int col = wc*64 + nj*16 + lrow;
          #pragma unroll
          for (int r2=0;r2<4;r2++) lsf[(lr+r2)*128 + col] = acc[mi][nj][r2];
        }
      }
    }
    __syncthreads();
    for (int t = tid; t < 64*nC; t += 256){
      int row = t / nC, c = cLo + t % nC;
      int lo = c*10;     if (lo < n0) lo = n0;
      int hi = c*10+9;   if (hi > n0+127) hi = n0+127;
      float mx = lsf[row*128 + (lo-n0)];
      for (int cc2 = lo+1; cc2 <= hi; ++cc2) mx = fmaxf(mx, lsf[row*128 + (cc2-n0)]);
      atomicMax(&maxbuf[(size_t)(m0 + h*64 + row)*KC + c], __float_as_uint(mx + 4.0f));
    }
  }
}

// ================= LN + l2 normalize (in-place on C16) =================
__global__ __launch_bounds__(256) void kLNl2n(_Float16* __restrict__ C16,
      const float* __restrict__ fg, const float* __restrict__ fb){
  int w=threadIdx.x>>6, lane=threadIdx.x&63;
  int n = blockIdx.x*4 + w;
  _Float16* row = C16 + (size_t)n*DD + lane*8;
  half8 h = *(const half8*)row;
  float x[8];
  #pragma unroll
  for (int i=0;i<8;i++) x[i] = (float)h[i];
  float s=0;
  #pragma unroll
  for (int i=0;i<8;i++) s += x[i];
  float mu = __shfl(wredf(s),0)/512.f;
  float q=0;
  #pragma unroll
  for (int i=0;i<8;i++){ float d=x[i]-mu; q+=d*d; }
  float var = __shfl(wredf(q),0)/512.f;
  float inv = 1.f/sqrtf(var+1e-5f);
  float4 g0 = *(const float4*)(fg+lane*8), g1 = *(const float4*)(fg+lane*8+4);
  float4 b0 = *(const float4*)(fb+lane*8), b1 = *(const float4*)(fb+lane*8+4);
  float gg[8] = {g0.x,g0.y,g0.z,g0.w,g1.x,g1.y,g1.z,g1.w};
  float bb[8] = {b0.x,b0.y,b0.z,b0.w,b1.x,b1.y,b1.z,b1.w};
  float y[8]; float ss=0;
  #pragma unroll
  for (int i=0;i<8;i++){ y[i] = (x[i]-mu)*inv*gg[i]+bb[i]; ss += y[i]*y[i]; }
  float nrm = fmaxf(sqrtf(__shfl(wredf(ss),0)), 1e-12f);
  half8 o;
  #pragma unroll
  for (int i=0;i<8;i++) o[i] = (_Float16)(y[i]/nrm);
  *(half8*)row = o;
}

// ===== per-class max (from maxbuf) + mask LN + pred + transpose-out + sinkhorn Qd/row0 =====
__global__ __launch_bounds__(256) void kMaxSK(const unsigned int* __restrict__ maxbuf,
    const float* __restrict__ PL, const float* __restrict__ mg,
    const float* __restrict__ mb, const int* __restrict__ gtseg, const int* __restrict__ gt,
    float* __restrict__ outseg, int* __restrict__ corr, float* __restrict__ Qd, float* __restrict__ row16){
  __shared__ float tile[16][205];
  __shared__ float qpart[10][2];
  int tid=threadIdx.x, lane=tid&63, w=tid>>6;
  int n0 = blockIdx.x*16;
  int b = n0>>10, hw0 = n0&1023;
  int c0 = gt[b];
  if (tid<20) qpart[tid>>1][tid&1]=0.f;
  __syncthreads();
  for (int r=0;r<16;r++){
    int n = n0 + r;
    int g = gtseg[n];
    if (tid < KC){
      tile[r][tid] = __uint_as_float(maxbuf[(size_t)n*KC + tid]) - 4.0f;
      if (tid == g){
        const float* src = PL + (size_t)n*KM + g*10;
        int cl = (g==200)?1:0;
        #pragma unroll
        for (int m2=0;m2<5;m2++){
          float2 t2 = *(const float2*)(src + m2*2);
          float e0 = expf(t2.x*20.f), e1 = expf(t2.y*20.f);
          Qd[(size_t)n*10+m2*2]   = e0;
          Qd[(size_t)n*10+m2*2+1] = e1;
          atomicAdd(&qpart[m2*2][cl], e0);
          atomicAdd(&qpart[m2*2+1][cl], e1);
        }
      }
    }
  }
  __syncthreads();
  for (int rr=0; rr<4; ++rr){
    int r = w*4 + rr;
    int n = n0 + r;
    float xv[4]; int ncl=0;
    for (int c=lane;c<KC;c+=64) xv[ncl++] = tile[r][c];
    float ps=0;
    for (int i=0;i<ncl;i++) ps += xv[i];
    float mu = __shfl(wredf(ps),0)*(1.f/201.f);
    float pv=0;
    for (int i=0;i<ncl;i++){ float d=xv[i]-mu; pv+=d*d; }
    float var = __shfl(wredf(pv),0)*(1.f/201.f);
    float inv = 1.f/sqrtf(var+1e-5f);
    float bv=-3.0e38f; int bi=1<<30;
    ncl=0;
    for (int c=lane;c<KC;c+=64){
      float o = (xv[ncl]-mu)*inv*mg[c]+mb[c]; ncl++;
      tile[r][c] = o;
      if (o>bv){ bv=o; bi=c; }
    }
    #pragma unroll
    for (int o2=32;o2;o2>>=1){
      float ov=__shfl_down(bv,o2); int oi=__shfl_down(bi,o2);
      if (ov>bv||(ov==bv&&oi<bi)){bv=ov;bi=oi;}
    }
    if (lane==0) corr[n] = (bi==gtseg[n])?1:0;
  }
  __syncthreads();
  if (tid<20){
    int m=tid>>1, cl=tid&1;
    atomicAdd(&row16[(size_t)(blockIdx.x&15)*2016 + m*KC + (cl?200:c0)], qpart[m][cl]);
  }
  for (int idx=tid; idx<KC*16; idx+=256){
    int c=idx>>4, j=idx&15;
    outseg[(((size_t)b*KC+c)<<10) + hw0 + j] = tile[j][c];
  }
}

// one sinkhorn iteration; rin has rin_parts partial buffers of stride 2016
__global__ __launch_bounds__(256) void kSKpass(float* __restrict__ Qd, const int* __restrict__ gtseg,
      const int* __restrict__ gt, const float* __restrict__ rin, int rin_parts,
      float* __restrict__ rout, const int* __restrict__ Bk){
  __shared__ float rin2[10][2];
  __shared__ double part[4][10][2];
  int n = blockIdx.x*256+threadIdx.x;
  int c0 = gt[blockIdx.x>>2];
  if (threadIdx.x < 20){
    int m = threadIdx.x>>1, cl = threadIdx.x&1;
    int cls = cl?200:c0;
    float s=0;
    for (int p=0;p<rin_parts;p++) s += rin[(size_t)p*2016 + m*KC + cls];
    rin2[m][cl]=s;
  }
  __syncthreads();
  int g = gtseg[n];
  int cl = (g==200)?1:0;
  double q[10]; double col=0.0;
  #pragma unroll
  for (int m=0;m<10;m++){
    double r = (double)rin2[m][cl];
    double t = (double)Qd[(size_t)n*10+m];
    if (r>0.0) t = t/r;
    t = t/10.0;
    q[m]=t; col+=t;
  }
  double cs = (col>0.0)? col : 1.0;
  int bk = Bk[g];
  double bs = (bk>0)? (double)bk : 1.0;
  double inv = 1.0/(cs*bs);
  int w=threadIdx.x>>6, lane=threadIdx.x&63;
  #pragma unroll
  for (int m=0;m<10;m++){
    double t = q[m]*inv;
    Qd[(size_t)n*10+m] = (float)t;
    double p0 = (g==c0)? t:0.0;
    double p1 = (g==200)? t:0.0;
    p0=wredd(p0); p1=wredd(p1);
    if (lane==0){ part[w][m][0]=p0; part[w][m][1]=p1; }
  }
  __syncthreads();
  if (threadIdx.x < 20){
    int m = threadIdx.x>>1, cl2 = threadIdx.x&1;
    double t = part[0][m][cl2]+part[1][m][cl2]+part[2][m][cl2]+part[3][m][cl2];
    atomicAdd(&rout[m*KC + (cl2?200:c0)], (float)t);
  }
}

// fused final argmax + proto_target write + EMA accumulation (wave per pixel)
__global__ __launch_bounds__(256) void kSKEMA(const float* __restrict__ Qd, const int* __restrict__ gtseg,
      const float* __restrict__ r5, const int* __restrict__ corr, const _Float16* __restrict__ C16,
      float* __restrict__ outPT, float* __restrict__ fproto, int* __restrict__ ncnt){
  int w=threadIdx.x>>6, lane=threadIdx.x&63;
  int n = blockIdx.x*4+w;
  int g = gtseg[n];
  float tv = -1.0f;
  if (lane<10){
    float r = r5[lane*KC+g];
    float t = Qd[(size_t)n*10+lane];
    if (r>0.f) t = t/r;
    tv = t*0.1f;
  }
  float bv = tv; int bi = lane;
  #pragma unroll
  for (int o=8;o;o>>=1){
    float ov = __shfl_down(bv,o); int oi = __shfl_down(bi,o);
    if (ov>bv || (ov==bv && oi<bi)){ bv=ov; bi=oi; }
  }
  bi = __shfl(bi, 0);
  if (lane==0) outPT[n] = (float)(bi + 10*g);
  if (corr[n]){
    half8 hc = *(const half8*)(C16 + (size_t)n*DD + lane*8);
    float* dst = fproto + ((size_t)g*10+bi)*DD + lane*8;
    #pragma unroll
    for (int i=0;i<8;i++) atomicAdd(dst+i, (float)hc[i]);
    if (lane==0) atomicAdd(&ncnt[g*10+bi], 1);
  }
}

__global__ __launch_bounds__(256) void kEMAfin(const float* __restrict__ fproto, const int* __restrict__ ncnt,
     const float* __restrict__ Pn, float* __restrict__ outNP){
  int w=threadIdx.x>>6, lane=threadIdx.x&63;
  int km = blockIdx.x*4+w;
  if (km>=KM) return;
  const float* fr = fproto + (size_t)km*DD + lane*8;
  float fp[8]; float ss=0;
  #pragma unroll
  for (int i=0;i<8;i++){ fp[i]=fr[i]; ss+=fp[i]*fp[i]; }
  float n1 = fmaxf(sqrtf(__shfl(wredf(ss),0)), 1e-12f);
  int cnt = ncnt[km];
  const float* pr = Pn + (size_t)km*DD + lane*8;
  float t[8]; float s2=0;
  #pragma unroll
  for (int i=0;i<8;i++){
    float pv = pr[i];
    float tv = cnt ? (0.999f*pv + 0.001f*(fp[i]/n1)) : pv;
    t[i]=tv; s2+=tv*tv;
  }
  float n2 = fmaxf(sqrtf(__shfl(wredf(s2),0)), 1e-12f);
  float* dst = outNP + (size_t)km*DD + lane*8;
  #pragma unroll
  for (int i=0;i<8;i++) dst[i] = t[i]/n2;
}

// ================= launch =================
extern "C" void kernel_launch(void* const* d_in, const int* in_sizes, int n_in,
                              void* d_out, int out_size, void* d_ws, size_t ws_size,
                              hipStream_t stream) {
  const float* A   = (const float*)d_in[0];
  const int*   gt  = (const int*)d_in[1];
  const float* Wp  = (const float*)d_in[2];
  const float* pb  = (const float*)d_in[3];
  const float* fg  = (const float*)d_in[4];
  const float* fb  = (const float*)d_in[5];
  const float* mg  = (const float*)d_in[6];
  const float* mb  = (const float*)d_in[7];
  const float* PR  = (const float*)d_in[8];
  float* out = (float*)d_out;
  char* ws = (char*)d_ws;

  double* xch    = (double*)(ws+OFF_XCH);
  double* Tp     = (double*)(ws+OFF_TP);
  double* colp   = (double*)(ws+OFF_COLP);
  float*  row16  = (float*)(ws+OFF_ROW16);
  float*  row3   = (float*)(ws+OFF_ROW3);
  float*  row5   = (float*)(ws+OFF_ROW5);
  int*    Bk     = (int*)(ws+OFF_BK);
  int*    ncnt   = (int*)(ws+OFF_NCNT);
  float*  fproto = (float*)(ws+OFF_FPROTO);
  unsigned int* maxbuf = (unsigned int*)(ws+OFF_MAXB);
  int*    gtseg  = (int*)(ws+OFF_GTSEG);
  int*    corr   = (int*)(ws+OFF_CORR);
  double* u      = (double*)(ws+OFF_U);
  float*  Pn     = (float*)(ws+OFF_PN);
  _Float16* P16  = (_Float16*)(ws+OFF_P16);
  _Float16* C16  = (_Float16*)(ws+OFF_C16);
  float*  Qd     = (float*)(ws+OFF_QD);
  _Float16* W16  = (_Float16*)(ws+OFF_W16);

  // single memset: all atomic accumulators + maxbuf
  hipMemsetAsync(ws, 0, ZTOTAL, stream);

  // ---- PCA pseudo-gt: 10 passes (float4 loads, broadcast-partial setup) + u + fin ----
  kPIter2<true><<<1024,256,0,stream>>>(A, nullptr, nullptr, nullptr, xch, Tp, colp);
  for (int t=1;t<10;t++){
    kPIter2<false><<<1024,256,0,stream>>>(A, xch+(size_t)(t-1)*8*768, Tp+(t-1)*8, colp,
                                          xch+(size_t)t*8*768, Tp+t*8, nullptr);
  }
  kPU2<<<1024,256,0,stream>>>(A, xch+(size_t)9*8*768, Tp+9*8, colp, u);
  kFin<<<1,1024,0,stream>>>(u, gt, out+OUT_PG, gtseg, Bk);

  // ---- prep: W conv + proto normalize ----
  kPrep<<<896,256,0,stream>>>(Wp, W16, PR, Pn, P16);

  // ---- GEMM1 (f32 A, fused convert) + LN+l2n ----
  gemm1<<<512,256,0,stream>>>(A, W16, C16, pb);
  kLNl2n<<<4096,256,0,stream>>>(C16, fg, fb);

  // ---- GEMM2: proto_logits + fused class-max ----
  gemm2<<<2048,256,0,stream>>>(C16, P16, out+OUT_PL, maxbuf);

  // ---- max/LN/pred/transpose (reads maxbuf) + sinkhorn row0 ----
  kMaxSK<<<1024,256,0,stream>>>(maxbuf, out+OUT_PL, mg, mb, gtseg, gt, out+OUT_SEG, corr, Qd, row16);

  // ---- sinkhorn passes + fused argmax/EMA ----
  kSKpass<<<64,256,0,stream>>>(Qd, gtseg, gt, row16, 16, row3, Bk);
  kSKpass<<<64,256,0,stream>>>(Qd, gtseg, gt, row3, 1, row5, Bk);
  kSKEMA<<<4096,256,0,stream>>>(Qd, gtseg, row5, corr, C16, out+OUT_PT, fproto, ncnt);

  // ---- EMA finalize ----
  kEMAfin<<<503,256,0,stream>>>(fproto, ncnt, Pn, out+OUT_NP);
}

// Round 11
// 424.095 us; speedup vs baseline: 1.2874x; 1.0086x over previous
//
#include <hip/hip_runtime.h>
#include <cstdint>
#include <cstddef>

typedef _Float16 half8  __attribute__((ext_vector_type(8)));
typedef _Float16 half4v __attribute__((ext_vector_type(4)));
typedef float    f32x4  __attribute__((ext_vector_type(4)));

static constexpr int HWPX = 1024;
static constexpr int NPX  = 16384;
static constexpr int DBB  = 768;
static constexpr int DD   = 512;
static constexpr int KC   = 201;
static constexpr int KM   = 2010;   // KC * 10
static constexpr int KMP  = 2048;   // padded

// ---- workspace offsets (bytes) ----
static constexpr size_t OFF_XCH    = 0;        // [10][8][768] f64 W partials (atomic)
static constexpr size_t OFF_TP     = 491520;   // [10][8] f64 T partials (atomic)
static constexpr size_t OFF_COLP   = 492160;   // [8][768] f64 colsum partials (atomic)
static constexpr size_t OFF_ROW16  = 541312;   // [16][2016] f32
static constexpr size_t OFF_ROW3   = 670336;   // [2016] f32
static constexpr size_t OFF_ROW5   = 678400;   // [2016] f32
static constexpr size_t OFF_BK     = 686464;   // 256 i32
static constexpr size_t OFF_NCNT   = 687488;   // 2016 i32
static constexpr size_t OFF_FPROTO = 695552;   // 2010*512 f32
static constexpr size_t OFF_MAXB   = 4812032;  // 16384*201 u32 encoded class-max
static constexpr size_t ZTOTAL     = 17984768; // single memset covers all above
static constexpr size_t OFF_GTSEG  = 17984768; // 16384 i32
static constexpr size_t OFF_CORR   = 18050304; // 16384 i32
static constexpr size_t OFF_U      = 18115840; // 16384 f64
static constexpr size_t OFF_PN     = 18246912; // 2010*512 f32
static constexpr size_t OFF_P16    = 22363392; // 2048*512 f16
static constexpr size_t OFF_C16    = 24460544; // 16384*512 f16
static constexpr size_t OFF_QD     = 41237760; // 16384*10 f32
static constexpr size_t OFF_W16    = 41893120; // 512*768 f16
static constexpr size_t OFF_MSF    = 42679552; // 768 f64 finalized mean (written whole by kRedM)

// ---- d_out offsets (floats) ----
static constexpr size_t OUT_SEG = 0;
static constexpr size_t OUT_PL  = 3293184;
static constexpr size_t OUT_PT  = 36225024;
static constexpr size_t OUT_PG  = 36241408;
static constexpr size_t OUT_NP  = 36257792;

#define GLDS16(gp, lp) __builtin_amdgcn_global_load_lds( \
    (__attribute__((address_space(1))) const void*)(gp), \
    (__attribute__((address_space(3))) void*)(lp), 16, 0, 0)

static __device__ __forceinline__ float  wredf(float x){
  #pragma unroll
  for (int o=32;o;o>>=1) x += __shfl_down(x,o);
  return x;
}
static __device__ __forceinline__ double wredd(double x){
  #pragma unroll
  for (int o=32;o;o>>=1) x += __shfl_down(x,o);
  return x;
}

// ================= PCA =================
// y = Ac^T Ac x = A^T w - m*(1^T w), w = A x  (exact given exact x; HW-validated R6-R10).
// FIRST pass also accumulates colsums (x0 const).  kRedM finalizes the mean ONCE; passes 2..10
// read 49KB W-partials + 6KB msf (NOT colp: R6-R10 re-read colp per block per pass -> ~80us
// regression vs R5's once-finalized mean.  R8 lesson: per-pass tiny kernels also regress;
// kRedM runs exactly once).  float4 A loads; lane owns cols {ch*256 + 4*lane + e}.
template<bool FIRST>
__global__ __launch_bounds__(256) void kPIter2(const float* __restrict__ A,
    const double* __restrict__ Win, const double* __restrict__ Tin, const double* __restrict__ msf,
    double* __restrict__ Wout, double* __restrict__ Tout, double* __restrict__ colout){
  __shared__ double vs[768];
  __shared__ double red[4][12][64];
  __shared__ double sT[4];
  int tid=threadIdx.x, lane=tid&63, w=tid>>6;
  if (FIRST){
    for (int cc=tid; cc<768; cc+=256) vs[cc] = 1.0/sqrt(768.0);
  } else {
    double Ts=0.0;
    #pragma unroll
    for (int p=0;p<8;p++) Ts += Tin[p];
    for (int cc=tid; cc<768; cc+=256){
      double sw=0.0;
      #pragma unroll
      for (int p=0;p<8;p++) sw += Win[p*768+cc];
      vs[cc] = sw - msf[cc]*Ts;
    }
  }
  __syncthreads();
  double vsr[12];
  #pragma unroll
  for (int ch=0;ch<3;ch++)
    #pragma unroll
    for (int e=0;e<4;e++) vsr[ch*4+e] = vs[ch*256 + lane*4 + e];
  int rbase = blockIdx.x*16 + w*4;
  const float* Ab = A + (size_t)rbase*DBB + lane*4;
  double acc[12], cacc[12]; double tloc=0.0;
  #pragma unroll
  for (int j=0;j<12;j++){ acc[j]=0.0; cacc[j]=0.0; }
  #pragma unroll
  for (int i=0;i<4;i++){
    const float* Ar = Ab + (size_t)i*DBB;
    float4 f0 = *(const float4*)(Ar);
    float4 f1 = *(const float4*)(Ar + 256);
    float4 f2 = *(const float4*)(Ar + 512);
    double a[12] = {(double)f0.x,(double)f0.y,(double)f0.z,(double)f0.w,
                    (double)f1.x,(double)f1.y,(double)f1.z,(double)f1.w,
                    (double)f2.x,(double)f2.y,(double)f2.z,(double)f2.w};
    double wp=0.0;
    #pragma unroll
    for (int j=0;j<12;j++) wp += a[j]*vsr[j];
    wp = wredd(wp); wp = __shfl(wp,0);
    #pragma unroll
    for (int j=0;j<12;j++) acc[j] += wp*a[j];
    if (FIRST){
      #pragma unroll
      for (int j=0;j<12;j++) cacc[j] += a[j];
    }
    tloc += wp;
  }
  #pragma unroll
  for (int j=0;j<12;j++) red[w][j][lane]=acc[j];
  if (lane==0) sT[w]=tloc;
  __syncthreads();
  double* dst = Wout + (size_t)(blockIdx.x&7)*768;
  for (int cc=tid; cc<768; cc+=256){
    int chv=cc>>8, rem=cc&255, l=rem>>2, e=rem&3, j=chv*4+e;
    atomicAdd(&dst[cc], red[0][j][l]+red[1][j][l]+red[2][j][l]+red[3][j][l]);
  }
  if (tid==0) atomicAdd(&Tout[blockIdx.x&7], sT[0]+sT[1]+sT[2]+sT[3]);
  if (FIRST){
    __syncthreads();
    #pragma unroll
    for (int j=0;j<12;j++) red[w][j][lane]=cacc[j];
    __syncthreads();
    double* cdst = colout + (size_t)(blockIdx.x&7)*768;
    for (int cc=tid; cc<768; cc+=256){
      int chv=cc>>8, rem=cc&255, l=rem>>2, e=rem&3, j=chv*4+e;
      atomicAdd(&cdst[cc], red[0][j][l]+red[1][j][l]+red[2][j][l]+red[3][j][l]);
    }
  }
}

// once: finalize mean from colsum partials (1 block, plain loads; launch boundary = coherence)
__global__ __launch_bounds__(256) void kRedM(const double* __restrict__ colp, double* __restrict__ msf){
  for (int cc=threadIdx.x; cc<768; cc+=256){
    double s=0.0;
    #pragma unroll
    for (int p=0;p<8;p++) s += colp[p*768+cc];
    msf[cc] = s * (1.0/16384.0);
  }
}

// u = Ac v = A v - (m.v):  v from pass-10 partials + msf.
__global__ __launch_bounds__(256) void kPU2(const float* __restrict__ A, const double* __restrict__ Wp,
    const double* __restrict__ Tp, const double* __restrict__ msf, double* __restrict__ u){
  __shared__ double vs[768];
  __shared__ double sS[4];
  int tid=threadIdx.x, lane=tid&63, w=tid>>6;
  double Ts=0.0;
  #pragma unroll
  for (int p=0;p<8;p++) Ts += Tp[p];
  double sloc=0.0;
  for (int cc=tid; cc<768; cc+=256){
    double sw=0.0;
    #pragma unroll
    for (int p=0;p<8;p++) sw += Wp[p*768+cc];
    double m = msf[cc];
    double v = sw - m*Ts;
    vs[cc] = v;
    sloc += m*v;
  }
  sloc = wredd(sloc);
  if (lane==0) sS[w]=sloc;
  __syncthreads();
  double s = sS[0]+sS[1]+sS[2]+sS[3];
  double vsr[12];
  #pragma unroll
  for (int ch=0;ch<3;ch++)
    #pragma unroll
    for (int e=0;e<4;e++) vsr[ch*4+e] = vs[ch*256 + lane*4 + e];
  int rbase = blockIdx.x*16 + w*4;
  const float* Ab = A + (size_t)rbase*DBB + lane*4;
  #pragma unroll
  for (int i=0;i<4;i++){
    const float* Ar = Ab + (size_t)i*DBB;
    float4 f0 = *(const float4*)(Ar);
    float4 f1 = *(const float4*)(Ar + 256);
    float4 f2 = *(const float4*)(Ar + 512);
    double a[12] = {(double)f0.x,(double)f0.y,(double)f0.z,(double)f0.w,
                    (double)f1.x,(double)f1.y,(double)f1.z,(double)f1.w,
                    (double)f2.x,(double)f2.y,(double)f2.z,(double)f2.w};
    double wp=0.0;
    #pragma unroll
    for (int j=0;j<12;j++) wp += a[j]*vsr[j];
    wp = wredd(wp);
    if (lane==0) u[rbase+i] = wp - s;
  }
}

// fused global minmax + pseudo-gt + Bk (single block)
__global__ __launch_bounds__(1024) void kFin(const double* __restrict__ u, const int* __restrict__ gt,
      float* __restrict__ outPG, int* __restrict__ gtseg, int* __restrict__ Bk){
  __shared__ double smn[16], smx[16];
  __shared__ double sres[2];
  int t = threadIdx.x;
  double mn=1e300, mx=-1e300;
  for (int k=0;k<16;k++){ double x=u[k*1024+t]; mn=fmin(mn,x); mx=fmax(mx,x); }
  #pragma unroll
  for (int o=32;o;o>>=1){ mn=fmin(mn,__shfl_down(mn,o)); mx=fmax(mx,__shfl_down(mx,o)); }
  if ((t&63)==0){ smn[t>>6]=mn; smx[t>>6]=mx; }
  __syncthreads();
  if (t==0){
    for (int i=1;i<16;i++){ mn=fmin(mn,smn[i]); mx=fmax(mx,smx[i]); }
    sres[0]=mn; sres[1]=mx;
  }
  __syncthreads();
  mn=sres[0]; mx=sres[1];
  double inv = 1.0/(mx-mn);
  for (int k=0;k<16;k++){
    int n = k*1024 + t;
    int c0 = gt[k];
    double us = (u[n]-mn)*inv;
    int g = (us < 0.5) ? c0 : 200;
    outPG[n] = (float)g;
    gtseg[n] = g;
    unsigned long long b0 = __ballot(g==c0);
    unsigned long long b1 = __ballot(g==200);
    if ((t&63)==0){
      atomicAdd(&Bk[c0], (int)__popcll(b0));
      atomicAdd(&Bk[200], (int)__popcll(b1));
    }
  }
}

// ================= prep: W f32->f16 (blocks 0..383) + proto l2-normalize (blocks 384..895) =================
__global__ __launch_bounds__(256) void kPrep(const float* __restrict__ Wp, _Float16* __restrict__ W16,
    const float* __restrict__ PR, float* __restrict__ Pn, _Float16* __restrict__ P16){
  int b = blockIdx.x;
  if (b < 384){
    int i = b*256 + threadIdx.x;
    float4 vv = ((const float4*)Wp)[i];
    half4v h; h[0]=(_Float16)vv.x; h[1]=(_Float16)vv.y; h[2]=(_Float16)vv.z; h[3]=(_Float16)vv.w;
    ((half4v*)W16)[i] = h;
    return;
  }
  int w=threadIdx.x>>6, lane=threadIdx.x&63;
  int km = (b-384)*4 + w;
  if (km >= KM){
    if (km < KMP){
      half8 z;
      #pragma unroll
      for (int i=0;i<8;i++) z[i]=(_Float16)0.0f;
      *(half8*)(P16 + (size_t)km*DD + lane*8) = z;
    }
    return;
  }
  const float* r = PR + (size_t)km*DD + lane*8;
  float4 a = *(const float4*)r, b2 = *(const float4*)(r+4);
  float x[8] = {a.x,a.y,a.z,a.w,b2.x,b2.y,b2.z,b2.w};
  float ss=0;
  #pragma unroll
  for (int i=0;i<8;i++) ss += x[i]*x[i];
  ss = __shfl(wredf(ss),0);
  float nrm = fmaxf(sqrtf(ss), 1e-12f);
  float* pw = Pn + (size_t)km*DD + lane*8;
  half8 h;
  #pragma unroll
  for (int i=0;i<8;i++){ float vv = x[i]/nrm; pw[i]=vv; h[i]=(_Float16)vv; }
  *(half8*)(P16 + (size_t)km*DD + lane*8) = h;
}

// ================= GEMM1: C16[16384,512] = f16( A_f32 @ W16^T + b ) =================
__global__ __launch_bounds__(256) void gemm1(const float* __restrict__ Af, const _Float16* __restrict__ Bm,
    _Float16* __restrict__ Ch, const float* __restrict__ bias){
  __shared__ __align__(16) char As[128*128];
  __shared__ __align__(16) char Bs[128*128];
  const int tid = threadIdx.x;
  const int lane = tid & 63, w = tid >> 6;
  const int wr = w >> 1, wc = w & 1;
  const int lrow = lane & 15, kg = lane >> 4;
  const int id = blockIdx.x;
  const int xcd = id & 7, pos = id >> 3;
  const int m0 = ((xcd<<4) | (pos>>2)) * 128;
  const int n0 = (pos & 3) * 128;

  f32x4 acc[4][4];
  #pragma unroll
  for (int i=0;i<4;i++)
    #pragma unroll
    for (int j=0;j<4;j++){ f32x4 z = {0.f,0.f,0.f,0.f}; acc[i][j]=z; }

  for (int k0 = 0; k0 < DBB; k0 += 64){
    #pragma unroll
    for (int i=0;i<4;i++){
      int slot = (i*4 + w)*64 + lane;
      int r = slot >> 3, c = slot & 7;
      int cs = c ^ (r & 7);
      GLDS16(Bm + (size_t)(n0+r)*DBB + k0 + cs*8, Bs + (i*4+w)*1024);
    }
    #pragma unroll
    for (int i=0;i<8;i++){
      int slot = i*256 + tid;
      int r = slot >> 4, c4 = slot & 15;
      float4 v = *(const float4*)(Af + (size_t)(m0+r)*DBB + k0 + c4*4);
      half4v h; h[0]=(_Float16)v.x; h[1]=(_Float16)v.y; h[2]=(_Float16)v.z; h[3]=(_Float16)v.w;
      *(half4v*)(As + r*128 + (((c4>>1)^(r&7))<<4) + (c4&1)*8) = h;
    }
    __syncthreads();
    #pragma unroll
    for (int h=0; h<2; h++){
      half8 af[4], bf[4];
      #pragma unroll
      for (int mi=0;mi<4;mi++){
        int ar = wr*64 + mi*16 + lrow;
        af[mi] = *(const half8*)(As + ar*128 + (((h*4+kg) ^ (ar&7))<<4));
      }
      #pragma unroll
      for (int nj=0;nj<4;nj++){
        int br = wc*64 + nj*16 + lrow;
        bf[nj] = *(const half8*)(Bs + br*128 + (((h*4+kg) ^ (br&7))<<4));
      }
      #pragma unroll
      for (int mi=0;mi<4;mi++)
        #pragma unroll
        for (int nj=0;nj<4;nj++)
          acc[mi][nj] = __builtin_amdgcn_mfma_f32_16x16x32_f16(af[mi], bf[nj], acc[mi][nj], 0,0,0);
    }
    __syncthreads();
  }
  #pragma unroll
  for (int mi=0;mi<4;mi++){
    int gr = m0 + wr*64 + mi*16 + kg*4;
    #pragma unroll
    for (int nj=0;nj<4;nj++){
      int gc = n0 + wc*64 + nj*16 + lrow;
      float bv = bias[gc];
      #pragma unroll
      for (int r2=0;r2<4;r2++)
        Ch[(size_t)(gr+r2)*DD + gc] = (_Float16)(acc[mi][nj][r2] + bv);
    }
  }
}

// ================= GEMM2: PL[16384,2010] = _c @ protos^T ; fused class-max -> maxbuf ==========
__global__ __launch_bounds__(256) void gemm2(const _Float16* __restrict__ Am, const _Float16* __restrict__ Bm,
    float* __restrict__ Cf, unsigned int* __restrict__ maxbuf){
  __shared__ __align__(16) char smem[32768];
  char* As = smem;
  char* Bs = smem + 16384;
  const int tid = threadIdx.x;
  const int lane = tid & 63, w = tid >> 6;
  const int wr = w >> 1, wc = w & 1;
  const int lrow = lane & 15, kg = lane >> 4;
  const int id = blockIdx.x;
  const int xcd = id & 7, pos = id >> 3;
  const int m0 = ((xcd<<4) | (pos>>4)) * 128;
  const int n0 = (pos & 15) * 128;

  f32x4 acc[4][4];
  #pragma unroll
  for (int i=0;i<4;i++)
    #pragma unroll
    for (int j=0;j<4;j++){ f32x4 z = {0.f,0.f,0.f,0.f}; acc[i][j]=z; }

  for (int k0 = 0; k0 < DD; k0 += 64){
    #pragma unroll
    for (int i=0;i<4;i++){
      int slot = (i*4 + w)*64 + lane;
      int r = slot >> 3, c = slot & 7;
      int cs = c ^ (r & 7);
      GLDS16(Am + (size_t)(m0+r)*DD + k0 + cs*8, As + (i*4+w)*1024);
      GLDS16(Bm + (size_t)(n0+r)*DD + k0 + cs*8, Bs + (i*4+w)*1024);
    }
    __syncthreads();
    #pragma unroll
    for (int h=0; h<2; h++){
      half8 af[4], bf[4];
      #pragma unroll
      for (int mi=0;mi<4;mi++){
        int ar = wr*64 + mi*16 + lrow;
        af[mi] = *(const half8*)(As + ar*128 + (((h*4+kg) ^ (ar&7))<<4));
      }
      #pragma unroll
      for (int nj=0;nj<4;nj++){
        int br = wc*64 + nj*16 + lrow;
        bf[nj] = *(const half8*)(Bs + br*128 + (((h*4+kg) ^ (br&7))<<4));
      }
      #pragma unroll
      for (int mi=0;mi<4;mi++)
        #pragma unroll
        for (int nj=0;nj<4;nj++)
          acc[mi][nj] = __builtin_amdgcn_mfma_f32_16x16x32_f16(af[mi], bf[nj], acc[mi][nj], 0,0,0);
    }
    __syncthreads();
  }
  // ---- PL write ----
  #pragma unroll
  for (int mi=0;mi<4;mi++){
    int gr = m0 + wr*64 + mi*16 + kg*4;
    #pragma unroll
    for (int nj=0;nj<4;nj++){
      int gc = n0 + wc*64 + nj*16 + lrow;
      if (gc < KM){
        #pragma unroll
        for (int r2=0;r2<4;r2++)
          Cf[(size_t)(gr+r2)*KM + gc] = acc[mi][nj][r2];
      }
    }
  }
  // ---- fused class-max: stage 64x128 halves in LDS (K-loop done; smem free) ----
  float* lsf = (float*)smem;                  // 64*128*4 = 32768 B
  const int cLo = n0/10;
  const int cHi = (n0+127)/10 > 200 ? 200 : (n0+127)/10;
  const int nC = cHi - cLo + 1;
  #pragma unroll
  for (int h=0; h<2; ++h){
    __syncthreads();
    if (wr == h){
      #pragma unroll
      for (int mi=0;mi<4;mi++){
        int lr = mi*16 + kg*4;
        #pragma unroll
        for (int nj=0;nj<4;nj++){
          int col = wc*64 + nj*16 + lrow;
          #pragma unroll
          for (int r2=0;r2<4;r2++) lsf[(lr+r2)*128 + col] = acc[mi][nj][r2];
        }
      }
    }
    __syncthreads();
    for (int t = tid; t < 64*nC; t += 256){
      int row = t / nC, c = cLo + t % nC;
      int lo = c*10;     if (lo < n0) lo = n0;
      int hi = c*10+9;   if (hi > n0+127) hi = n0+127;
      float mx = lsf[row*128 + (lo-n0)];
      for (int cc2 = lo+1; cc2 <= hi; ++cc2) mx = fmaxf(mx, lsf[row*128 + (cc2-n0)]);
      atomicMax(&maxbuf[(size_t)(m0 + h*64 + row)*KC + c], __float_as_uint(mx + 4.0f));
    }
  }
}

// ================= LN + l2 normalize (in-place on C16) =================
__global__ __launch_bounds__(256) void kLNl2n(_Float16* __restrict__ C16,
      const float* __restrict__ fg, const float* __restrict__ fb){
  int w=threadIdx.x>>6, lane=threadIdx.x&63;
  int n = blockIdx.x*4 + w;
  _Float16* row = C16 + (size_t)n*DD + lane*8;
  half8 h = *(const half8*)row;
  float x[8];
  #pragma unroll
  for (int i=0;i<8;i++) x[i] = (float)h[i];
  float s=0;
  #pragma unroll
  for (int i=0;i<8;i++) s += x[i];
  float mu = __shfl(wredf(s),0)/512.f;
  float q=0;
  #pragma unroll
  for (int i=0;i<8;i++){ float d=x[i]-mu; q+=d*d; }
  float var = __shfl(wredf(q),0)/512.f;
  float inv = 1.f/sqrtf(var+1e-5f);
  float4 g0 = *(const float4*)(fg+lane*8), g1 = *(const float4*)(fg+lane*8+4);
  float4 b0 = *(const float4*)(fb+lane*8), b1 = *(const float4*)(fb+lane*8+4);
  float gg[8] = {g0.x,g0.y,g0.z,g0.w,g1.x,g1.y,g1.z,g1.w};
  float bb[8] = {b0.x,b0.y,b0.z,b0.w,b1.x,b1.y,b1.z,b1.w};
  float y[8]; float ss=0;
  #pragma unroll
  for (int i=0;i<8;i++){ y[i] = (x[i]-mu)*inv*gg[i]+bb[i]; ss += y[i]*y[i]; }
  float nrm = fmaxf(sqrtf(__shfl(wredf(ss),0)), 1e-12f);
  half8 o;
  #pragma unroll
  for (int i=0;i<8;i++) o[i] = (_Float16)(y[i]/nrm);
  *(half8*)row = o;
}

// ===== per-class max (from maxbuf) + mask LN + pred + transpose-out + sinkhorn Qd/row0 =====
__global__ __launch_bounds__(256) void kMaxSK(const unsigned int* __restrict__ maxbuf,
    const float* __restrict__ PL, const float* __restrict__ mg,
    const float* __restrict__ mb, const int* __restrict__ gtseg, const int* __restrict__ gt,
    float* __restrict__ outseg, int* __restrict__ corr, float* __restrict__ Qd, float* __restrict__ row16){
  __shared__ float tile[16][205];
  __shared__ float qpart[10][2];
  int tid=threadIdx.x, lane=tid&63, w=tid>>6;
  int n0 = blockIdx.x*16;
  int b = n0>>10, hw0 = n0&1023;
  int c0 = gt[b];
  if (tid<20) qpart[tid>>1][tid&1]=0.f;
  __syncthreads();
  for (int r=0;r<16;r++){
    int n = n0 + r;
    int g = gtseg[n];
    if (tid < KC){
      tile[r][tid] = __uint_as_float(maxbuf[(size_t)n*KC + tid]) - 4.0f;
      if (tid == g){
        const float* src = PL + (size_t)n*KM + g*10;
        int cl = (g==200)?1:0;
        #pragma unroll
        for (int m2=0;m2<5;m2++){
          float2 t2 = *(const float2*)(src + m2*2);
          float e0 = expf(t2.x*20.f), e1 = expf(t2.y*20.f);
          Qd[(size_t)n*10+m2*2]   = e0;
          Qd[(size_t)n*10+m2*2+1] = e1;
          atomicAdd(&qpart[m2*2][cl], e0);
          atomicAdd(&qpart[m2*2+1][cl], e1);
        }
      }
    }
  }
  __syncthreads();
  for (int rr=0; rr<4; ++rr){
    int r = w*4 + rr;
    int n = n0 + r;
    float xv[4]; int ncl=0;
    for (int c=lane;c<KC;c+=64) xv[ncl++] = tile[r][c];
    float ps=0;
    for (int i=0;i<ncl;i++) ps += xv[i];
    float mu = __shfl(wredf(ps),0)*(1.f/201.f);
    float pv=0;
    for (int i=0;i<ncl;i++){ float d=xv[i]-mu; pv+=d*d; }
    float var = __shfl(wredf(pv),0)*(1.f/201.f);
    float inv = 1.f/sqrtf(var+1e-5f);
    float bv=-3.0e38f; int bi=1<<30;
    ncl=0;
    for (int c=lane;c<KC;c+=64){
      float o = (xv[ncl]-mu)*inv*mg[c]+mb[c]; ncl++;
      tile[r][c] = o;
      if (o>bv){ bv=o; bi=c; }
    }
    #pragma unroll
    for (int o2=32;o2;o2>>=1){
      float ov=__shfl_down(bv,o2); int oi=__shfl_down(bi,o2);
      if (ov>bv||(ov==bv&&oi<bi)){bv=ov;bi=oi;}
    }
    if (lane==0) corr[n] = (bi==gtseg[n])?1:0;
  }
  __syncthreads();
  if (tid<20){
    int m=tid>>1, cl=tid&1;
    atomicAdd(&row16[(size_t)(blockIdx.x&15)*2016 + m*KC + (cl?200:c0)], qpart[m][cl]);
  }
  for (int idx=tid; idx<KC*16; idx+=256){
    int c=idx>>4, j=idx&15;
    outseg[(((size_t)b*KC+c)<<10) + hw0 + j] = tile[j][c];
  }
}

// one sinkhorn iteration; rin has rin_parts partial buffers of stride 2016
__global__ __launch_bounds__(256) void kSKpass(float* __restrict__ Qd, const int* __restrict__ gtseg,
      const int* __restrict__ gt, const float* __restrict__ rin, int rin_parts,
      float* __restrict__ rout, const int* __restrict__ Bk){
  __shared__ float rin2[10][2];
  __shared__ double part[4][10][2];
  int n = blockIdx.x*256+threadIdx.x;
  int c0 = gt[blockIdx.x>>2];
  if (threadIdx.x < 20){
    int m = threadIdx.x>>1, cl = threadIdx.x&1;
    int cls = cl?200:c0;
    float s=0;
    for (int p=0;p<rin_parts;p++) s += rin[(size_t)p*2016 + m*KC + cls];
    rin2[m][cl]=s;
  }
  __syncthreads();
  int g = gtseg[n];
  int cl = (g==200)?1:0;
  double q[10]; double col=0.0;
  #pragma unroll
  for (int m=0;m<10;m++){
    double r = (double)rin2[m][cl];
    double t = (double)Qd[(size_t)n*10+m];
    if (r>0.0) t = t/r;
    t = t/10.0;
    q[m]=t; col+=t;
  }
  double cs = (col>0.0)? col : 1.0;
  int bk = Bk[g];
  double bs = (bk>0)? (double)bk : 1.0;
  double inv = 1.0/(cs*bs);
  int w=threadIdx.x>>6, lane=threadIdx.x&63;
  #pragma unroll
  for (int m=0;m<10;m++){
    double t = q[m]*inv;
    Qd[(size_t)n*10+m] = (float)t;
    double p0 = (g==c0)? t:0.0;
    double p1 = (g==200)? t:0.0;
    p0=wredd(p0); p1=wredd(p1);
    if (lane==0){ part[w][m][0]=p0; part[w][m][1]=p1; }
  }
  __syncthreads();
  if (threadIdx.x < 20){
    int m = threadIdx.x>>1, cl2 = threadIdx.x&1;
    double t = part[0][m][cl2]+part[1][m][cl2]+part[2][m][cl2]+part[3][m][cl2];
    atomicAdd(&rout[m*KC + (cl2?200:c0)], (float)t);
  }
}

// fused final argmax + proto_target write + EMA accumulation (wave per pixel)
__global__ __launch_bounds__(256) void kSKEMA(const float* __restrict__ Qd, const int* __restrict__ gtseg,
      const float* __restrict__ r5, const int* __restrict__ corr, const _Float16* __restrict__ C16,
      float* __restrict__ outPT, float* __restrict__ fproto, int* __restrict__ ncnt){
  int w=threadIdx.x>>6, lane=threadIdx.x&63;
  int n = blockIdx.x*4+w;
  int g = gtseg[n];
  float tv = -1.0f;
  if (lane<10){
    float r = r5[lane*KC+g];
    float t = Qd[(size_t)n*10+lane];
    if (r>0.f) t = t/r;
    tv = t*0.1f;
  }
  float bv = tv; int bi = lane;
  #pragma unroll
  for (int o=8;o;o>>=1){
    float ov = __shfl_down(bv,o); int oi = __shfl_down(bi,o);
    if (ov>bv || (ov==bv && oi<bi)){ bv=ov; bi=oi; }
  }
  bi = __shfl(bi, 0);
  if (lane==0) outPT[n] = (float)(bi + 10*g);
  if (corr[n]){
    half8 hc = *(const half8*)(C16 + (size_t)n*DD + lane*8);
    float* dst = fproto + ((size_t)g*10+bi)*DD + lane*8;
    #pragma unroll
    for (int i=0;i<8;i++) atomicAdd(dst+i, (float)hc[i]);
    if (lane==0) atomicAdd(&ncnt[g*10+bi], 1);
  }
}

__global__ __launch_bounds__(256) void kEMAfin(const float* __restrict__ fproto, const int* __restrict__ ncnt,
     const float* __restrict__ Pn, float* __restrict__ outNP){
  int w=threadIdx.x>>6, lane=threadIdx.x&63;
  int km = blockIdx.x*4+w;
  if (km>=KM) return;
  const float* fr = fproto + (size_t)km*DD + lane*8;
  float fp[8]; float ss=0;
  #pragma unroll
  for (int i=0;i<8;i++){ fp[i]=fr[i]; ss+=fp[i]*fp[i]; }
  float n1 = fmaxf(sqrtf(__shfl(wredf(ss),0)), 1e-12f);
  int cnt = ncnt[km];
  const float* pr = Pn + (size_t)km*DD + lane*8;
  float t[8]; float s2=0;
  #pragma unroll
  for (int i=0;i<8;i++){
    float pv = pr[i];
    float tv = cnt ? (0.999f*pv + 0.001f*(fp[i]/n1)) : pv;
    t[i]=tv; s2+=tv*tv;
  }
  float n2 = fmaxf(sqrtf(__shfl(wredf(s2),0)), 1e-12f);
  float* dst = outNP + (size_t)km*DD + lane*8;
  #pragma unroll
  for (int i=0;i<8;i++) dst[i] = t[i]/n2;
}

// ================= launch =================
extern "C" void kernel_launch(void* const* d_in, const int* in_sizes, int n_in,
                              void* d_out, int out_size, void* d_ws, size_t ws_size,
                              hipStream_t stream) {
  const float* A   = (const float*)d_in[0];
  const int*   gt  = (const int*)d_in[1];
  const float* Wp  = (const float*)d_in[2];
  const float* pb  = (const float*)d_in[3];
  const float* fg  = (const float*)d_in[4];
  const float* fb  = (const float*)d_in[5];
  const float* mg  = (const float*)d_in[6];
  const float* mb  = (const float*)d_in[7];
  const float* PR  = (const float*)d_in[8];
  float* out = (float*)d_out;
  char* ws = (char*)d_ws;

  double* xch    = (double*)(ws+OFF_XCH);
  double* Tp     = (double*)(ws+OFF_TP);
  double* colp   = (double*)(ws+OFF_COLP);
  float*  row16  = (float*)(ws+OFF_ROW16);
  float*  row3   = (float*)(ws+OFF_ROW3);
  float*  row5   = (float*)(ws+OFF_ROW5);
  int*    Bk     = (int*)(ws+OFF_BK);
  int*    ncnt   = (int*)(ws+OFF_NCNT);
  float*  fproto = (float*)(ws+OFF_FPROTO);
  unsigned int* maxbuf = (unsigned int*)(ws+OFF_MAXB);
  int*    gtseg  = (int*)(ws+OFF_GTSEG);
  int*    corr   = (int*)(ws+OFF_CORR);
  double* u      = (double*)(ws+OFF_U);
  float*  Pn     = (float*)(ws+OFF_PN);
  _Float16* P16  = (_Float16*)(ws+OFF_P16);
  _Float16* C16  = (_Float16*)(ws+OFF_C16);
  float*  Qd     = (float*)(ws+OFF_QD);
  _Float16* W16  = (_Float16*)(ws+OFF_W16);
  double* msf    = (double*)(ws+OFF_MSF);

  // single memset: all atomic accumulators + maxbuf
  hipMemsetAsync(ws, 0, ZTOTAL, stream);

  // ---- PCA pseudo-gt: pass1(+colsum) -> kRedM once -> passes 2..10 -> u -> fin ----
  kPIter2<true><<<1024,256,0,stream>>>(A, nullptr, nullptr, nullptr, xch, Tp, colp);
  kRedM<<<1,256,0,stream>>>(colp, msf);
  for (int t=1;t<10;t++){
    kPIter2<false><<<1024,256,0,stream>>>(A, xch+(size_t)(t-1)*8*768, Tp+(t-1)*8, msf,
                                          xch+(size_t)t*8*768, Tp+t*8, nullptr);
  }
  kPU2<<<1024,256,0,stream>>>(A, xch+(size_t)9*8*768, Tp+9*8, msf, u);
  kFin<<<1,1024,0,stream>>>(u, gt, out+OUT_PG, gtseg, Bk);

  // ---- prep: W conv + proto normalize ----
  kPrep<<<896,256,0,stream>>>(Wp, W16, PR, Pn, P16);

  // ---- GEMM1 (f32 A, fused convert) + LN+l2n ----
  gemm1<<<512,256,0,stream>>>(A, W16, C16, pb);
  kLNl2n<<<4096,256,0,stream>>>(C16, fg, fb);

  // ---- GEMM2: proto_logits + fused class-max ----
  gemm2<<<2048,256,0,stream>>>(C16, P16, out+OUT_PL, maxbuf);

  // ---- max/LN/pred/transpose (reads maxbuf) + sinkhorn row0 ----
  kMaxSK<<<1024,256,0,stream>>>(maxbuf, out+OUT_PL, mg, mb, gtseg, gt, out+OUT_SEG, corr, Qd, row16);

  // ---- sinkhorn passes + fused argmax/EMA ----
  kSKpass<<<64,256,0,stream>>>(Qd, gtseg, gt, row16, 16, row3, Bk);
  kSKpass<<<64,256,0,stream>>>(Qd, gtseg, gt, row3, 1, row5, Bk);
  kSKEMA<<<4096,256,0,stream>>>(Qd, gtseg, row5, corr, C16, out+OUT_PT, fproto, ncnt);

  // ---- EMA finalize ----
  kEMAfin<<<503,256,0,stream>>>(fproto, ncnt, Pn, out+OUT_NP);
}

// Round 12
// 415.321 us; speedup vs baseline: 1.3146x; 1.0211x over previous
//
#include <hip/hip_runtime.h>
#include <cstdint>
#include <cstddef>

typedef _Float16 half8  __attribute__((ext_vector_type(8)));
typedef _Float16 half4v __attribute__((ext_vector_type(4)));
typedef float    f32x4  __attribute__((ext_vector_type(4)));

static constexpr int HWPX = 1024;
static constexpr int NPX  = 16384;
static constexpr int DBB  = 768;
static constexpr int DD   = 512;
static constexpr int KC   = 201;
static constexpr int KM   = 2010;   // KC * 10
static constexpr int KMP  = 2048;   // padded

// ---- workspace offsets (bytes) ----
static constexpr size_t OFF_XCH    = 0;        // [10][8][768] f64 W partials (atomic)
static constexpr size_t OFF_TP     = 491520;   // [10][8] f64 T partials (atomic)
static constexpr size_t OFF_COLP   = 492160;   // [8][768] f64 colsum partials (atomic)
static constexpr size_t OFF_ROW16  = 541312;   // [16][2016] f32
static constexpr size_t OFF_ROW3   = 670336;   // [2016] f32
static constexpr size_t OFF_ROW5   = 678400;   // [2016] f32
static constexpr size_t OFF_BK     = 686464;   // 256 i32
static constexpr size_t OFF_NCNT   = 687488;   // 2016 i32
static constexpr size_t OFF_FPROTO = 695552;   // 2010*512 f32
static constexpr size_t OFF_MAXB   = 4812032;  // 16384*201 u32 encoded class-max
static constexpr size_t ZTOTAL     = 17984768; // single memset covers all above
static constexpr size_t OFF_GTSEG  = 17984768; // 16384 i32
static constexpr size_t OFF_CORR   = 18050304; // 16384 i32
static constexpr size_t OFF_U      = 18115840; // 16384 f64
static constexpr size_t OFF_PN     = 18246912; // 2010*512 f32
static constexpr size_t OFF_P16    = 22363392; // 2048*512 f16
static constexpr size_t OFF_C16    = 24460544; // 16384*512 f16
static constexpr size_t OFF_QD     = 41237760; // 16384*10 f32
static constexpr size_t OFF_W16    = 41893120; // 512*768 f16
static constexpr size_t OFF_MSF    = 42679552; // 768 f64 finalized mean (written whole by kRedM)

// ---- d_out offsets (floats) ----
static constexpr size_t OUT_SEG = 0;
static constexpr size_t OUT_PL  = 3293184;
static constexpr size_t OUT_PT  = 36225024;
static constexpr size_t OUT_PG  = 36241408;
static constexpr size_t OUT_NP  = 36257792;

#define GLDS16(gp, lp) __builtin_amdgcn_global_load_lds( \
    (__attribute__((address_space(1))) const void*)(gp), \
    (__attribute__((address_space(3))) void*)(lp), 16, 0, 0)

static __device__ __forceinline__ float  wredf(float x){
  #pragma unroll
  for (int o=32;o;o>>=1) x += __shfl_down(x,o);
  return x;
}
static __device__ __forceinline__ double wredd(double x){
  #pragma unroll
  for (int o=32;o;o>>=1) x += __shfl_down(x,o);
  return x;
}

// ================= PCA (R11 structure, unchanged — proven 424us/absmax 8) =================
template<bool FIRST>
__global__ __launch_bounds__(256) void kPIter2(const float* __restrict__ A,
    const double* __restrict__ Win, const double* __restrict__ Tin, const double* __restrict__ msf,
    double* __restrict__ Wout, double* __restrict__ Tout, double* __restrict__ colout){
  __shared__ double vs[768];
  __shared__ double red[4][12][64];
  __shared__ double sT[4];
  int tid=threadIdx.x, lane=tid&63, w=tid>>6;
  if (FIRST){
    for (int cc=tid; cc<768; cc+=256) vs[cc] = 1.0/sqrt(768.0);
  } else {
    double Ts=0.0;
    #pragma unroll
    for (int p=0;p<8;p++) Ts += Tin[p];
    for (int cc=tid; cc<768; cc+=256){
      double sw=0.0;
      #pragma unroll
      for (int p=0;p<8;p++) sw += Win[p*768+cc];
      vs[cc] = sw - msf[cc]*Ts;
    }
  }
  __syncthreads();
  double vsr[12];
  #pragma unroll
  for (int ch=0;ch<3;ch++)
    #pragma unroll
    for (int e=0;e<4;e++) vsr[ch*4+e] = vs[ch*256 + lane*4 + e];
  int rbase = blockIdx.x*16 + w*4;
  const float* Ab = A + (size_t)rbase*DBB + lane*4;
  double acc[12], cacc[12]; double tloc=0.0;
  #pragma unroll
  for (int j=0;j<12;j++){ acc[j]=0.0; cacc[j]=0.0; }
  #pragma unroll
  for (int i=0;i<4;i++){
    const float* Ar = Ab + (size_t)i*DBB;
    float4 f0 = *(const float4*)(Ar);
    float4 f1 = *(const float4*)(Ar + 256);
    float4 f2 = *(const float4*)(Ar + 512);
    double a[12] = {(double)f0.x,(double)f0.y,(double)f0.z,(double)f0.w,
                    (double)f1.x,(double)f1.y,(double)f1.z,(double)f1.w,
                    (double)f2.x,(double)f2.y,(double)f2.z,(double)f2.w};
    double wp=0.0;
    #pragma unroll
    for (int j=0;j<12;j++) wp += a[j]*vsr[j];
    wp = wredd(wp); wp = __shfl(wp,0);
    #pragma unroll
    for (int j=0;j<12;j++) acc[j] += wp*a[j];
    if (FIRST){
      #pragma unroll
      for (int j=0;j<12;j++) cacc[j] += a[j];
    }
    tloc += wp;
  }
  #pragma unroll
  for (int j=0;j<12;j++) red[w][j][lane]=acc[j];
  if (lane==0) sT[w]=tloc;
  __syncthreads();
  double* dst = Wout + (size_t)(blockIdx.x&7)*768;
  for (int cc=tid; cc<768; cc+=256){
    int chv=cc>>8, rem=cc&255, l=rem>>2, e=rem&3, j=chv*4+e;
    atomicAdd(&dst[cc], red[0][j][l]+red[1][j][l]+red[2][j][l]+red[3][j][l]);
  }
  if (tid==0) atomicAdd(&Tout[blockIdx.x&7], sT[0]+sT[1]+sT[2]+sT[3]);
  if (FIRST){
    __syncthreads();
    #pragma unroll
    for (int j=0;j<12;j++) red[w][j][lane]=cacc[j];
    __syncthreads();
    double* cdst = colout + (size_t)(blockIdx.x&7)*768;
    for (int cc=tid; cc<768; cc+=256){
      int chv=cc>>8, rem=cc&255, l=rem>>2, e=rem&3, j=chv*4+e;
      atomicAdd(&cdst[cc], red[0][j][l]+red[1][j][l]+red[2][j][l]+red[3][j][l]);
    }
  }
}

// once: finalize mean from colsum partials (1 block, plain loads; launch boundary = coherence)
__global__ __launch_bounds__(256) void kRedM(const double* __restrict__ colp, double* __restrict__ msf){
  for (int cc=threadIdx.x; cc<768; cc+=256){
    double s=0.0;
    #pragma unroll
    for (int p=0;p<8;p++) s += colp[p*768+cc];
    msf[cc] = s * (1.0/16384.0);
  }
}

// u = Ac v = A v - (m.v)
__global__ __launch_bounds__(256) void kPU2(const float* __restrict__ A, const double* __restrict__ Wp,
    const double* __restrict__ Tp, const double* __restrict__ msf, double* __restrict__ u){
  __shared__ double vs[768];
  __shared__ double sS[4];
  int tid=threadIdx.x, lane=tid&63, w=tid>>6;
  double Ts=0.0;
  #pragma unroll
  for (int p=0;p<8;p++) Ts += Tp[p];
  double sloc=0.0;
  for (int cc=tid; cc<768; cc+=256){
    double sw=0.0;
    #pragma unroll
    for (int p=0;p<8;p++) sw += Wp[p*768+cc];
    double m = msf[cc];
    double v = sw - m*Ts;
    vs[cc] = v;
    sloc += m*v;
  }
  sloc = wredd(sloc);
  if (lane==0) sS[w]=sloc;
  __syncthreads();
  double s = sS[0]+sS[1]+sS[2]+sS[3];
  double vsr[12];
  #pragma unroll
  for (int ch=0;ch<3;ch++)
    #pragma unroll
    for (int e=0;e<4;e++) vsr[ch*4+e] = vs[ch*256 + lane*4 + e];
  int rbase = blockIdx.x*16 + w*4;
  const float* Ab = A + (size_t)rbase*DBB + lane*4;
  #pragma unroll
  for (int i=0;i<4;i++){
    const float* Ar = Ab + (size_t)i*DBB;
    float4 f0 = *(const float4*)(Ar);
    float4 f1 = *(const float4*)(Ar + 256);
    float4 f2 = *(const float4*)(Ar + 512);
    double a[12] = {(double)f0.x,(double)f0.y,(double)f0.z,(double)f0.w,
                    (double)f1.x,(double)f1.y,(double)f1.z,(double)f1.w,
                    (double)f2.x,(double)f2.y,(double)f2.z,(double)f2.w};
    double wp=0.0;
    #pragma unroll
    for (int j=0;j<12;j++) wp += a[j]*vsr[j];
    wp = wredd(wp);
    if (lane==0) u[rbase+i] = wp - s;
  }
}

// fused global minmax + pseudo-gt + Bk (single block)
__global__ __launch_bounds__(1024) void kFin(const double* __restrict__ u, const int* __restrict__ gt,
      float* __restrict__ outPG, int* __restrict__ gtseg, int* __restrict__ Bk){
  __shared__ double smn[16], smx[16];
  __shared__ double sres[2];
  int t = threadIdx.x;
  double mn=1e300, mx=-1e300;
  for (int k=0;k<16;k++){ double x=u[k*1024+t]; mn=fmin(mn,x); mx=fmax(mx,x); }
  #pragma unroll
  for (int o=32;o;o>>=1){ mn=fmin(mn,__shfl_down(mn,o)); mx=fmax(mx,__shfl_down(mx,o)); }
  if ((t&63)==0){ smn[t>>6]=mn; smx[t>>6]=mx; }
  __syncthreads();
  if (t==0){
    for (int i=1;i<16;i++){ mn=fmin(mn,smn[i]); mx=fmax(mx,smx[i]); }
    sres[0]=mn; sres[1]=mx;
  }
  __syncthreads();
  mn=sres[0]; mx=sres[1];
  double inv = 1.0/(mx-mn);
  for (int k=0;k<16;k++){
    int n = k*1024 + t;
    int c0 = gt[k];
    double us = (u[n]-mn)*inv;
    int g = (us < 0.5) ? c0 : 200;
    outPG[n] = (float)g;
    gtseg[n] = g;
    unsigned long long b0 = __ballot(g==c0);
    unsigned long long b1 = __ballot(g==200);
    if ((t&63)==0){
      atomicAdd(&Bk[c0], (int)__popcll(b0));
      atomicAdd(&Bk[200], (int)__popcll(b1));
    }
  }
}

// ================= prep: W f32->f16 (blocks 0..383) + proto l2-normalize (blocks 384..895) =================
__global__ __launch_bounds__(256) void kPrep(const float* __restrict__ Wp, _Float16* __restrict__ W16,
    const float* __restrict__ PR, float* __restrict__ Pn, _Float16* __restrict__ P16){
  int b = blockIdx.x;
  if (b < 384){
    int i = b*256 + threadIdx.x;
    float4 vv = ((const float4*)Wp)[i];
    half4v h; h[0]=(_Float16)vv.x; h[1]=(_Float16)vv.y; h[2]=(_Float16)vv.z; h[3]=(_Float16)vv.w;
    ((half4v*)W16)[i] = h;
    return;
  }
  int w=threadIdx.x>>6, lane=threadIdx.x&63;
  int km = (b-384)*4 + w;
  if (km >= KM){
    if (km < KMP){
      half8 z;
      #pragma unroll
      for (int i=0;i<8;i++) z[i]=(_Float16)0.0f;
      *(half8*)(P16 + (size_t)km*DD + lane*8) = z;
    }
    return;
  }
  const float* r = PR + (size_t)km*DD + lane*8;
  float4 a = *(const float4*)r, b2 = *(const float4*)(r+4);
  float x[8] = {a.x,a.y,a.z,a.w,b2.x,b2.y,b2.z,b2.w};
  float ss=0;
  #pragma unroll
  for (int i=0;i<8;i++) ss += x[i]*x[i];
  ss = __shfl(wredf(ss),0);
  float nrm = fmaxf(sqrtf(ss), 1e-12f);
  float* pw = Pn + (size_t)km*DD + lane*8;
  half8 h;
  #pragma unroll
  for (int i=0;i<8;i++){ float vv = x[i]/nrm; pw[i]=vv; h[i]=(_Float16)vv; }
  *(half8*)(P16 + (size_t)km*DD + lane*8) = h;
}

// ================= GEMM1: C16[16384,512] = f16( A_f32 @ W16^T + b ) =================
// Epilogue: stage f16 half-tiles in LDS (stride 136 f16, 16B-aligned rows), coalesced half8 writes.
__global__ __launch_bounds__(256) void gemm1(const float* __restrict__ Af, const _Float16* __restrict__ Bm,
    _Float16* __restrict__ Ch, const float* __restrict__ bias){
  __shared__ __align__(16) char smem[32768];
  char* As = smem;
  char* Bs = smem + 16384;
  const int tid = threadIdx.x;
  const int lane = tid & 63, w = tid >> 6;
  const int wr = w >> 1, wc = w & 1;
  const int lrow = lane & 15, kg = lane >> 4;
  const int id = blockIdx.x;
  const int xcd = id & 7, pos = id >> 3;
  const int m0 = ((xcd<<4) | (pos>>2)) * 128;
  const int n0 = (pos & 3) * 128;

  f32x4 acc[4][4];
  #pragma unroll
  for (int i=0;i<4;i++)
    #pragma unroll
    for (int j=0;j<4;j++){ f32x4 z = {0.f,0.f,0.f,0.f}; acc[i][j]=z; }

  for (int k0 = 0; k0 < DBB; k0 += 64){
    #pragma unroll
    for (int i=0;i<4;i++){
      int slot = (i*4 + w)*64 + lane;
      int r = slot >> 3, c = slot & 7;
      int cs = c ^ (r & 7);
      GLDS16(Bm + (size_t)(n0+r)*DBB + k0 + cs*8, Bs + (i*4+w)*1024);
    }
    #pragma unroll
    for (int i=0;i<8;i++){
      int slot = i*256 + tid;
      int r = slot >> 4, c4 = slot & 15;
      float4 v = *(const float4*)(Af + (size_t)(m0+r)*DBB + k0 + c4*4);
      half4v h; h[0]=(_Float16)v.x; h[1]=(_Float16)v.y; h[2]=(_Float16)v.z; h[3]=(_Float16)v.w;
      *(half4v*)(As + r*128 + (((c4>>1)^(r&7))<<4) + (c4&1)*8) = h;
    }
    __syncthreads();
    #pragma unroll
    for (int h=0; h<2; h++){
      half8 af[4], bf[4];
      #pragma unroll
      for (int mi=0;mi<4;mi++){
        int ar = wr*64 + mi*16 + lrow;
        af[mi] = *(const half8*)(As + ar*128 + (((h*4+kg) ^ (ar&7))<<4));
      }
      #pragma unroll
      for (int nj=0;nj<4;nj++){
        int br = wc*64 + nj*16 + lrow;
        bf[nj] = *(const half8*)(Bs + br*128 + (((h*4+kg) ^ (br&7))<<4));
      }
      #pragma unroll
      for (int mi=0;mi<4;mi++)
        #pragma unroll
        for (int nj=0;nj<4;nj++)
          acc[mi][nj] = __builtin_amdgcn_mfma_f32_16x16x32_f16(af[mi], bf[nj], acc[mi][nj], 0,0,0);
    }
    __syncthreads();
  }
  // ---- epilogue: stage (f16, +bias) -> coalesced half8 writes ----
  _Float16* lsf = (_Float16*)smem;     // 64*136*2 = 17408 B
  #pragma unroll
  for (int h=0; h<2; ++h){
    __syncthreads();
    if (wr == h){
      #pragma unroll
      for (int mi=0;mi<4;mi++){
        int lr = mi*16 + kg*4;
        #pragma unroll
        for (int nj=0;nj<4;nj++){
          int col = wc*64 + nj*16 + lrow;
          float bv = bias[n0 + col];
          #pragma unroll
          for (int r2=0;r2<4;r2++) lsf[(lr+r2)*136 + col] = (_Float16)(acc[mi][nj][r2] + bv);
        }
      }
    }
    __syncthreads();
    #pragma unroll
    for (int it=0; it<4; ++it){
      int idx = it*256 + tid;
      int row = idx >> 4, c8 = idx & 15;
      half8 v = *(const half8*)(lsf + row*136 + c8*8);
      *(half8*)(Ch + (size_t)(m0 + h*64 + row)*DD + n0 + c8*8) = v;
    }
  }
}

// ================= GEMM2: PL[16384,2010] = _c @ protos^T ; LDS-staged epilogue ==========
// Epilogue per 64x128 half: stage in LDS (stride 132 f32, 16B rows), then (a) coalesced
// float4 PL writes (512B/row segments), (b) class-max + atomicMax merge into maxbuf.
__global__ __launch_bounds__(256) void gemm2(const _Float16* __restrict__ Am, const _Float16* __restrict__ Bm,
    float* __restrict__ Cf, unsigned int* __restrict__ maxbuf){
  __shared__ __align__(16) char smem[33792];
  char* As = smem;
  char* Bs = smem + 16384;
  const int tid = threadIdx.x;
  const int lane = tid & 63, w = tid >> 6;
  const int wr = w >> 1, wc = w & 1;
  const int lrow = lane & 15, kg = lane >> 4;
  const int id = blockIdx.x;
  const int xcd = id & 7, pos = id >> 3;
  const int m0 = ((xcd<<4) | (pos>>4)) * 128;
  const int n0 = (pos & 15) * 128;

  f32x4 acc[4][4];
  #pragma unroll
  for (int i=0;i<4;i++)
    #pragma unroll
    for (int j=0;j<4;j++){ f32x4 z = {0.f,0.f,0.f,0.f}; acc[i][j]=z; }

  for (int k0 = 0; k0 < DD; k0 += 64){
    #pragma unroll
    for (int i=0;i<4;i++){
      int slot = (i*4 + w)*64 + lane;
      int r = slot >> 3, c = slot & 7;
      int cs = c ^ (r & 7);
      GLDS16(Am + (size_t)(m0+r)*DD + k0 + cs*8, As + (i*4+w)*1024);
      GLDS16(Bm + (size_t)(n0+r)*DD + k0 + cs*8, Bs + (i*4+w)*1024);
    }
    __syncthreads();
    #pragma unroll
    for (int h=0; h<2; h++){
      half8 af[4], bf[4];
      #pragma unroll
      for (int mi=0;mi<4;mi++){
        int ar = wr*64 + mi*16 + lrow;
        af[mi] = *(const half8*)(As + ar*128 + (((h*4+kg) ^ (ar&7))<<4));
      }
      #pragma unroll
      for (int nj=0;nj<4;nj++){
        int br = wc*64 + nj*16 + lrow;
        bf[nj] = *(const half8*)(Bs + br*128 + (((h*4+kg) ^ (br&7))<<4));
      }
      #pragma unroll
      for (int mi=0;mi<4;mi++)
        #pragma unroll
        for (int nj=0;nj<4;nj++)
          acc[mi][nj] = __builtin_amdgcn_mfma_f32_16x16x32_f16(af[mi], bf[nj], acc[mi][nj], 0,0,0);
    }
    __syncthreads();
  }
  // ---- epilogue ----
  float* lsf = (float*)smem;                  // 64*132*4 = 33792 B
  const int cLo = n0/10;
  const int cHi = (n0+127)/10 > 200 ? 200 : (n0+127)/10;
  const int nC = cHi - cLo + 1;
  for (int h=0; h<2; ++h){
    __syncthreads();
    if (wr == h){
      #pragma unroll
      for (int mi=0;mi<4;mi++){
        int lr = mi*16 + kg*4;
        #pragma unroll
        for (int nj=0;nj<4;nj++){
          int col = wc*64 + nj*16 + lrow;
          #pragma unroll
          for (int r2=0;r2<4;r2++) lsf[(lr+r2)*132 + col] = acc[mi][nj][r2];
        }
      }
    }
    __syncthreads();
    // (a) coalesced PL writes: 2048 float4 over 256 threads
    #pragma unroll
    for (int it=0; it<8; ++it){
      int idx = it*256 + tid;
      int row = idx >> 5, c4 = idx & 31;
      int gc = n0 + c4*4;
      f32x4 v = *(const f32x4*)(lsf + row*132 + c4*4);
      float* dstp = Cf + (size_t)(m0 + h*64 + row)*KM + gc;
      if (gc + 3 < KM) *(f32x4*)dstp = v;
      else {
        #pragma unroll
        for (int e=0;e<4;e++) if (gc+e < KM) dstp[e] = v[e];
      }
    }
    // (b) class-max + merge
    for (int t = tid; t < 64*nC; t += 256){
      int row = t / nC, c = cLo + t % nC;
      int lo = c*10;     if (lo < n0) lo = n0;
      int hi = c*10+9;   if (hi > n0+127) hi = n0+127;
      float mx = lsf[row*132 + (lo-n0)];
      for (int cc2 = lo+1; cc2 <= hi; ++cc2) mx = fmaxf(mx, lsf[row*132 + (cc2-n0)]);
      atomicMax(&maxbuf[(size_t)(m0 + h*64 + row)*KC + c], __float_as_uint(mx + 4.0f));
    }
  }
}

// ================= LN + l2 normalize (in-place on C16) =================
__global__ __launch_bounds__(256) void kLNl2n(_Float16* __restrict__ C16,
      const float* __restrict__ fg, const float* __restrict__ fb){
  int w=threadIdx.x>>6, lane=threadIdx.x&63;
  int n = blockIdx.x*4 + w;
  _Float16* row = C16 + (size_t)n*DD + lane*8;
  half8 h = *(const half8*)row;
  float x[8];
  #pragma unroll
  for (int i=0;i<8;i++) x[i] = (float)h[i];
  float s=0;
  #pragma unroll
  for (int i=0;i<8;i++) s += x[i];
  float mu = __shfl(wredf(s),0)/512.f;
  float q=0;
  #pragma unroll
  for (int i=0;i<8;i++){ float d=x[i]-mu; q+=d*d; }
  float var = __shfl(wredf(q),0)/512.f;
  float inv = 1.f/sqrtf(var+1e-5f);
  float4 g0 = *(const float4*)(fg+lane*8), g1 = *(const float4*)(fg+lane*8+4);
  float4 b0 = *(const float4*)(fb+lane*8), b1 = *(const float4*)(fb+lane*8+4);
  float gg[8] = {g0.x,g0.y,g0.z,g0.w,g1.x,g1.y,g1.z,g1.w};
  float bb[8] = {b0.x,b0.y,b0.z,b0.w,b1.x,b1.y,b1.z,b1.w};
  float y[8]; float ss=0;
  #pragma unroll
  for (int i=0;i<8;i++){ y[i] = (x[i]-mu)*inv*gg[i]+bb[i]; ss += y[i]*y[i]; }
  float nrm = fmaxf(sqrtf(__shfl(wredf(ss),0)), 1e-12f);
  half8 o;
  #pragma unroll
  for (int i=0;i<8;i++) o[i] = (_Float16)(y[i]/nrm);
  *(half8*)row = o;
}

// ===== per-class max (from maxbuf) + mask LN + pred + transpose-out + sinkhorn Qd/row0 =====
__global__ __launch_bounds__(256) void kMaxSK(const unsigned int* __restrict__ maxbuf,
    const float* __restrict__ PL, const float* __restrict__ mg,
    const float* __restrict__ mb, const int* __restrict__ gtseg, const int* __restrict__ gt,
    float* __restrict__ outseg, int* __restrict__ corr, float* __restrict__ Qd, float* __restrict__ row16){
  __shared__ float tile[16][205];
  __shared__ float qpart[10][2];
  int tid=threadIdx.x, lane=tid&63, w=tid>>6;
  int n0 = blockIdx.x*16;
  int b = n0>>10, hw0 = n0&1023;
  int c0 = gt[b];
  if (tid<20) qpart[tid>>1][tid&1]=0.f;
  __syncthreads();
  for (int r=0;r<16;r++){
    int n = n0 + r;
    int g = gtseg[n];
    if (tid < KC){
      tile[r][tid] = __uint_as_float(maxbuf[(size_t)n*KC + tid]) - 4.0f;
      if (tid == g){
        const float* src = PL + (size_t)n*KM + g*10;
        int cl = (g==200)?1:0;
        #pragma unroll
        for (int m2=0;m2<5;m2++){
          float2 t2 = *(const float2*)(src + m2*2);
          float e0 = expf(t2.x*20.f), e1 = expf(t2.y*20.f);
          Qd[(size_t)n*10+m2*2]   = e0;
          Qd[(size_t)n*10+m2*2+1] = e1;
          atomicAdd(&qpart[m2*2][cl], e0);
          atomicAdd(&qpart[m2*2+1][cl], e1);
        }
      }
    }
  }
  __syncthreads();
  for (int rr=0; rr<4; ++rr){
    int r = w*4 + rr;
    int n = n0 + r;
    float xv[4]; int ncl=0;
    for (int c=lane;c<KC;c+=64) xv[ncl++] = tile[r][c];
    float ps=0;
    for (int i=0;i<ncl;i++) ps += xv[i];
    float mu = __shfl(wredf(ps),0)*(1.f/201.f);
    float pv=0;
    for (int i=0;i<ncl;i++){ float d=xv[i]-mu; pv+=d*d; }
    float var = __shfl(wredf(pv),0)*(1.f/201.f);
    float inv = 1.f/sqrtf(var+1e-5f);
    float bv=-3.0e38f; int bi=1<<30;
    ncl=0;
    for (int c=lane;c<KC;c+=64){
      float o = (xv[ncl]-mu)*inv*mg[c]+mb[c]; ncl++;
      tile[r][c] = o;
      if (o>bv){ bv=o; bi=c; }
    }
    #pragma unroll
    for (int o2=32;o2;o2>>=1){
      float ov=__shfl_down(bv,o2); int oi=__shfl_down(bi,o2);
      if (ov>bv||(ov==bv&&oi<bi)){bv=ov;bi=oi;}
    }
    if (lane==0) corr[n] = (bi==gtseg[n])?1:0;
  }
  __syncthreads();
  if (tid<20){
    int m=tid>>1, cl=tid&1;
    atomicAdd(&row16[(size_t)(blockIdx.x&15)*2016 + m*KC + (cl?200:c0)], qpart[m][cl]);
  }
  for (int idx=tid; idx<KC*4; idx+=256){
    int c = idx>>2, j4 = idx&3;
    float4 v;
    v.x = tile[j4*4+0][c];
    v.y = tile[j4*4+1][c];
    v.z = tile[j4*4+2][c];
    v.w = tile[j4*4+3][c];
    *(float4*)(outseg + (((size_t)b*KC+c)<<10) + hw0 + j4*4) = v;
  }
}

// one sinkhorn iteration; rin has rin_parts partial buffers of stride 2016
__global__ __launch_bounds__(256) void kSKpass(float* __restrict__ Qd, const int* __restrict__ gtseg,
      const int* __restrict__ gt, const float* __restrict__ rin, int rin_parts,
      float* __restrict__ rout, const int* __restrict__ Bk){
  __shared__ float rin2[10][2];
  __shared__ double part[4][10][2];
  int n = blockIdx.x*256+threadIdx.x;
  int c0 = gt[blockIdx.x>>2];
  if (threadIdx.x < 20){
    int m = threadIdx.x>>1, cl = threadIdx.x&1;
    int cls = cl?200:c0;
    float s=0;
    for (int p=0;p<rin_parts;p++) s += rin[(size_t)p*2016 + m*KC + cls];
    rin2[m][cl]=s;
  }
  __syncthreads();
  int g = gtseg[n];
  int cl = (g==200)?1:0;
  double q[10]; double col=0.0;
  #pragma unroll
  for (int m=0;m<10;m++){
    double r = (double)rin2[m][cl];
    double t = (double)Qd[(size_t)n*10+m];
    if (r>0.0) t = t/r;
    t = t/10.0;
    q[m]=t; col+=t;
  }
  double cs = (col>0.0)? col : 1.0;
  int bk = Bk[g];
  double bs = (bk>0)? (double)bk : 1.0;
  double inv = 1.0/(cs*bs);
  int w=threadIdx.x>>6, lane=threadIdx.x&63;
  #pragma unroll
  for (int m=0;m<10;m++){
    double t = q[m]*inv;
    Qd[(size_t)n*10+m] = (float)t;
    double p0 = (g==c0)? t:0.0;
    double p1 = (g==200)? t:0.0;
    p0=wredd(p0); p1=wredd(p1);
    if (lane==0){ part[w][m][0]=p0; part[w][m][1]=p1; }
  }
  __syncthreads();
  if (threadIdx.x < 20){
    int m = threadIdx.x>>1, cl2 = threadIdx.x&1;
    double t = part[0][m][cl2]+part[1][m][cl2]+part[2][m][cl2]+part[3][m][cl2];
    atomicAdd(&rout[m*KC + (cl2?200:c0)], (float)t);
  }
}

// fused final argmax + proto_target write + EMA accumulation (wave per pixel)
__global__ __launch_bounds__(256) void kSKEMA(const float* __restrict__ Qd, const int* __restrict__ gtseg,
      const float* __restrict__ r5, const int* __restrict__ corr, const _Float16* __restrict__ C16,
      float* __restrict__ outPT, float* __restrict__ fproto, int* __restrict__ ncnt){
  int w=threadIdx.x>>6, lane=threadIdx.x&63;
  int n = blockIdx.x*4+w;
  int g = gtseg[n];
  float tv = -1.0f;
  if (lane<10){
    float r = r5[lane*KC+g];
    float t = Qd[(size_t)n*10+lane];
    if (r>0.f) t = t/r;
    tv = t*0.1f;
  }
  float bv = tv; int bi = lane;
  #pragma unroll
  for (int o=8;o;o>>=1){
    float ov = __shfl_down(bv,o); int oi = __shfl_down(bi,o);
    if (ov>bv || (ov==bv && oi<bi)){ bv=ov; bi=oi; }
  }
  bi = __shfl(bi, 0);
  if (lane==0) outPT[n] = (float)(bi + 10*g);
  if (corr[n]){
    half8 hc = *(const half8*)(C16 + (size_t)n*DD + lane*8);
    float* dst = fproto + ((size_t)g*10+bi)*DD + lane*8;
    #pragma unroll
    for (int i=0;i<8;i++) atomicAdd(dst+i, (float)hc[i]);
    if (lane==0) atomicAdd(&ncnt[g*10+bi], 1);
  }
}

__global__ __launch_bounds__(256) void kEMAfin(const float* __restrict__ fproto, const int* __restrict__ ncnt,
     const float* __restrict__ Pn, float* __restrict__ outNP){
  int w=threadIdx.x>>6, lane=threadIdx.x&63;
  int km = blockIdx.x*4+w;
  if (km>=KM) return;
  const float* fr = fproto + (size_t)km*DD + lane*8;
  float fp[8]; float ss=0;
  #pragma unroll
  for (int i=0;i<8;i++){ fp[i]=fr[i]; ss+=fp[i]*fp[i]; }
  float n1 = fmaxf(sqrtf(__shfl(wredf(ss),0)), 1e-12f);
  int cnt = ncnt[km];
  const float* pr = Pn + (size_t)km*DD + lane*8;
  float t[8]; float s2=0;
  #pragma unroll
  for (int i=0;i<8;i++){
    float pv = pr[i];
    float tv = cnt ? (0.999f*pv + 0.001f*(fp[i]/n1)) : pv;
    t[i]=tv; s2+=tv*tv;
  }
  float n2 = fmaxf(sqrtf(__shfl(wredf(s2),0)), 1e-12f);
  float* dst = outNP + (size_t)km*DD + lane*8;
  #pragma unroll
  for (int i=0;i<8;i++) dst[i] = t[i]/n2;
}

// ================= launch =================
extern "C" void kernel_launch(void* const* d_in, const int* in_sizes, int n_in,
                              void* d_out, int out_size, void* d_ws, size_t ws_size,
                              hipStream_t stream) {
  const float* A   = (const float*)d_in[0];
  const int*   gt  = (const int*)d_in[1];
  const float* Wp  = (const float*)d_in[2];
  const float* pb  = (const float*)d_in[3];
  const float* fg  = (const float*)d_in[4];
  const float* fb  = (const float*)d_in[5];
  const float* mg  = (const float*)d_in[6];
  const float* mb  = (const float*)d_in[7];
  const float* PR  = (const float*)d_in[8];
  float* out = (float*)d_out;
  char* ws = (char*)d_ws;

  double* xch    = (double*)(ws+OFF_XCH);
  double* Tp     = (double*)(ws+OFF_TP);
  double* colp   = (double*)(ws+OFF_COLP);
  float*  row16  = (float*)(ws+OFF_ROW16);
  float*  row3   = (float*)(ws+OFF_ROW3);
  float*  row5   = (float*)(ws+OFF_ROW5);
  int*    Bk     = (int*)(ws+OFF_BK);
  int*    ncnt   = (int*)(ws+OFF_NCNT);
  float*  fproto = (float*)(ws+OFF_FPROTO);
  unsigned int* maxbuf = (unsigned int*)(ws+OFF_MAXB);
  int*    gtseg  = (int*)(ws+OFF_GTSEG);
  int*    corr   = (int*)(ws+OFF_CORR);
  double* u      = (double*)(ws+OFF_U);
  float*  Pn     = (float*)(ws+OFF_PN);
  _Float16* P16  = (_Float16*)(ws+OFF_P16);
  _Float16* C16  = (_Float16*)(ws+OFF_C16);
  float*  Qd     = (float*)(ws+OFF_QD);
  _Float16* W16  = (_Float16*)(ws+OFF_W16);
  double* msf    = (double*)(ws+OFF_MSF);

  // single memset: all atomic accumulators + maxbuf
  hipMemsetAsync(ws, 0, ZTOTAL, stream);

  // ---- PCA pseudo-gt: pass1(+colsum) -> kRedM once -> passes 2..10 -> u -> fin ----
  kPIter2<true><<<1024,256,0,stream>>>(A, nullptr, nullptr, nullptr, xch, Tp, colp);
  kRedM<<<1,256,0,stream>>>(colp, msf);
  for (int t=1;t<10;t++){
    kPIter2<false><<<1024,256,0,stream>>>(A, xch+(size_t)(t-1)*8*768, Tp+(t-1)*8, msf,
                                          xch+(size_t)t*8*768, Tp+t*8, nullptr);
  }
  kPU2<<<1024,256,0,stream>>>(A, xch+(size_t)9*8*768, Tp+9*8, msf, u);
  kFin<<<1,1024,0,stream>>>(u, gt, out+OUT_PG, gtseg, Bk);

  // ---- prep: W conv + proto normalize ----
  kPrep<<<896,256,0,stream>>>(Wp, W16, PR, Pn, P16);

  // ---- GEMM1 (f32 A, fused convert) + LN+l2n ----
  gemm1<<<512,256,0,stream>>>(A, W16, C16, pb);
  kLNl2n<<<4096,256,0,stream>>>(C16, fg, fb);

  // ---- GEMM2: proto_logits + fused class-max (LDS-staged coalesced epilogue) ----
  gemm2<<<2048,256,0,stream>>>(C16, P16, out+OUT_PL, maxbuf);

  // ---- max/LN/pred/transpose (reads maxbuf) + sinkhorn row0 ----
  kMaxSK<<<1024,256,0,stream>>>(maxbuf, out+OUT_PL, mg, mb, gtseg, gt, out+OUT_SEG, corr, Qd, row16);

  // ---- sinkhorn passes + fused argmax/EMA ----
  kSKpass<<<64,256,0,stream>>>(Qd, gtseg, gt, row16, 16, row3, Bk);
  kSKpass<<<64,256,0,stream>>>(Qd, gtseg, gt, row3, 1, row5, Bk);
  kSKEMA<<<4096,256,0,stream>>>(Qd, gtseg, row5, corr, C16, out+OUT_PT, fproto, ncnt);

  // ---- EMA finalize ----
  kEMAfin<<<503,256,0,stream>>>(fproto, ncnt, Pn, out+OUT_NP);
}

// Round 13
// 408.805 us; speedup vs baseline: 1.3356x; 1.0159x over previous
//
#include <hip/hip_runtime.h>
#include <cstdint>
#include <cstddef>

typedef _Float16 half8  __attribute__((ext_vector_type(8)));
typedef _Float16 half4v __attribute__((ext_vector_type(4)));
typedef float    f32x4  __attribute__((ext_vector_type(4)));

static constexpr int HWPX = 1024;
static constexpr int NPX  = 16384;
static constexpr int DBB  = 768;
static constexpr int DD   = 512;
static constexpr int KC   = 201;
static constexpr int KM   = 2010;   // KC * 10
static constexpr int KMP  = 2048;   // padded

// ---- workspace offsets (bytes) ----
static constexpr size_t OFF_XCH    = 0;        // [10][8][768] f64 W partials (atomic)
static constexpr size_t OFF_TP     = 491520;   // [10][8] f64 T partials (atomic)
static constexpr size_t OFF_COLP   = 492160;   // [8][768] f64 colsum partials (atomic)
static constexpr size_t OFF_ROW16  = 541312;   // [16][2016] f32
static constexpr size_t OFF_ROW3   = 670336;   // [2016] f32
static constexpr size_t OFF_ROW5   = 678400;   // [2016] f32
static constexpr size_t OFF_BK     = 686464;   // 256 i32
static constexpr size_t OFF_NCNT   = 687488;   // 2016 i32
static constexpr size_t OFF_FPROTO = 695552;   // 2010*512 f32
static constexpr size_t OFF_MAXB   = 4812032;  // 16384*201 u32 encoded class-max
static constexpr size_t ZTOTAL     = 17984768; // single memset covers all above
static constexpr size_t OFF_GTSEG  = 17984768; // 16384 i32
static constexpr size_t OFF_CORR   = 18050304; // 16384 i32
static constexpr size_t OFF_U      = 18115840; // 16384 f64
static constexpr size_t OFF_PN     = 18246912; // 2010*512 f32
static constexpr size_t OFF_P16    = 22363392; // 2048*512 f16
static constexpr size_t OFF_C16    = 24460544; // 16384*512 f16
static constexpr size_t OFF_QD     = 41237760; // 16384*10 f32
static constexpr size_t OFF_W16    = 41893120; // 512*768 f16
static constexpr size_t OFF_MSF    = 42679552; // 768 f64 finalized mean (written whole by kRedM)

// ---- d_out offsets (floats) ----
static constexpr size_t OUT_SEG = 0;
static constexpr size_t OUT_PL  = 3293184;
static constexpr size_t OUT_PT  = 36225024;
static constexpr size_t OUT_PG  = 36241408;
static constexpr size_t OUT_NP  = 36257792;

#define GLDS16(gp, lp) __builtin_amdgcn_global_load_lds( \
    (__attribute__((address_space(1))) const void*)(gp), \
    (__attribute__((address_space(3))) void*)(lp), 16, 0, 0)

static __device__ __forceinline__ float  wredf(float x){
  #pragma unroll
  for (int o=32;o;o>>=1) x += __shfl_down(x,o);
  return x;
}
static __device__ __forceinline__ double wredd(double x){
  #pragma unroll
  for (int o=32;o;o>>=1) x += __shfl_down(x,o);
  return x;
}

// ================= PCA (R11 structure, unchanged — proven) =================
template<bool FIRST>
__global__ __launch_bounds__(256) void kPIter2(const float* __restrict__ A,
    const double* __restrict__ Win, const double* __restrict__ Tin, const double* __restrict__ msf,
    double* __restrict__ Wout, double* __restrict__ Tout, double* __restrict__ colout){
  __shared__ double vs[768];
  __shared__ double red[4][12][64];
  __shared__ double sT[4];
  int tid=threadIdx.x, lane=tid&63, w=tid>>6;
  if (FIRST){
    for (int cc=tid; cc<768; cc+=256) vs[cc] = 1.0/sqrt(768.0);
  } else {
    double Ts=0.0;
    #pragma unroll
    for (int p=0;p<8;p++) Ts += Tin[p];
    for (int cc=tid; cc<768; cc+=256){
      double sw=0.0;
      #pragma unroll
      for (int p=0;p<8;p++) sw += Win[p*768+cc];
      vs[cc] = sw - msf[cc]*Ts;
    }
  }
  __syncthreads();
  double vsr[12];
  #pragma unroll
  for (int ch=0;ch<3;ch++)
    #pragma unroll
    for (int e=0;e<4;e++) vsr[ch*4+e] = vs[ch*256 + lane*4 + e];
  int rbase = blockIdx.x*16 + w*4;
  const float* Ab = A + (size_t)rbase*DBB + lane*4;
  double acc[12], cacc[12]; double tloc=0.0;
  #pragma unroll
  for (int j=0;j<12;j++){ acc[j]=0.0; cacc[j]=0.0; }
  #pragma unroll
  for (int i=0;i<4;i++){
    const float* Ar = Ab + (size_t)i*DBB;
    float4 f0 = *(const float4*)(Ar);
    float4 f1 = *(const float4*)(Ar + 256);
    float4 f2 = *(const float4*)(Ar + 512);
    double a[12] = {(double)f0.x,(double)f0.y,(double)f0.z,(double)f0.w,
                    (double)f1.x,(double)f1.y,(double)f1.z,(double)f1.w,
                    (double)f2.x,(double)f2.y,(double)f2.z,(double)f2.w};
    double wp=0.0;
    #pragma unroll
    for (int j=0;j<12;j++) wp += a[j]*vsr[j];
    wp = wredd(wp); wp = __shfl(wp,0);
    #pragma unroll
    for (int j=0;j<12;j++) acc[j] += wp*a[j];
    if (FIRST){
      #pragma unroll
      for (int j=0;j<12;j++) cacc[j] += a[j];
    }
    tloc += wp;
  }
  #pragma unroll
  for (int j=0;j<12;j++) red[w][j][lane]=acc[j];
  if (lane==0) sT[w]=tloc;
  __syncthreads();
  double* dst = Wout + (size_t)(blockIdx.x&7)*768;
  for (int cc=tid; cc<768; cc+=256){
    int chv=cc>>8, rem=cc&255, l=rem>>2, e=rem&3, j=chv*4+e;
    atomicAdd(&dst[cc], red[0][j][l]+red[1][j][l]+red[2][j][l]+red[3][j][l]);
  }
  if (tid==0) atomicAdd(&Tout[blockIdx.x&7], sT[0]+sT[1]+sT[2]+sT[3]);
  if (FIRST){
    __syncthreads();
    #pragma unroll
    for (int j=0;j<12;j++) red[w][j][lane]=cacc[j];
    __syncthreads();
    double* cdst = colout + (size_t)(blockIdx.x&7)*768;
    for (int cc=tid; cc<768; cc+=256){
      int chv=cc>>8, rem=cc&255, l=rem>>2, e=rem&3, j=chv*4+e;
      atomicAdd(&cdst[cc], red[0][j][l]+red[1][j][l]+red[2][j][l]+red[3][j][l]);
    }
  }
}

// once: finalize mean from colsum partials
__global__ __launch_bounds__(256) void kRedM(const double* __restrict__ colp, double* __restrict__ msf){
  for (int cc=threadIdx.x; cc<768; cc+=256){
    double s=0.0;
    #pragma unroll
    for (int p=0;p<8;p++) s += colp[p*768+cc];
    msf[cc] = s * (1.0/16384.0);
  }
}

// u = Ac v = A v - (m.v)
__global__ __launch_bounds__(256) void kPU2(const float* __restrict__ A, const double* __restrict__ Wp,
    const double* __restrict__ Tp, const double* __restrict__ msf, double* __restrict__ u){
  __shared__ double vs[768];
  __shared__ double sS[4];
  int tid=threadIdx.x, lane=tid&63, w=tid>>6;
  double Ts=0.0;
  #pragma unroll
  for (int p=0;p<8;p++) Ts += Tp[p];
  double sloc=0.0;
  for (int cc=tid; cc<768; cc+=256){
    double sw=0.0;
    #pragma unroll
    for (int p=0;p<8;p++) sw += Wp[p*768+cc];
    double m = msf[cc];
    double v = sw - m*Ts;
    vs[cc] = v;
    sloc += m*v;
  }
  sloc = wredd(sloc);
  if (lane==0) sS[w]=sloc;
  __syncthreads();
  double s = sS[0]+sS[1]+sS[2]+sS[3];
  double vsr[12];
  #pragma unroll
  for (int ch=0;ch<3;ch++)
    #pragma unroll
    for (int e=0;e<4;e++) vsr[ch*4+e] = vs[ch*256 + lane*4 + e];
  int rbase = blockIdx.x*16 + w*4;
  const float* Ab = A + (size_t)rbase*DBB + lane*4;
  #pragma unroll
  for (int i=0;i<4;i++){
    const float* Ar = Ab + (size_t)i*DBB;
    float4 f0 = *(const float4*)(Ar);
    float4 f1 = *(const float4*)(Ar + 256);
    float4 f2 = *(const float4*)(Ar + 512);
    double a[12] = {(double)f0.x,(double)f0.y,(double)f0.z,(double)f0.w,
                    (double)f1.x,(double)f1.y,(double)f1.z,(double)f1.w,
                    (double)f2.x,(double)f2.y,(double)f2.z,(double)f2.w};
    double wp=0.0;
    #pragma unroll
    for (int j=0;j<12;j++) wp += a[j]*vsr[j];
    wp = wredd(wp);
    if (lane==0) u[rbase+i] = wp - s;
  }
}

// fused global minmax + pseudo-gt + Bk (single block)
__global__ __launch_bounds__(1024) void kFin(const double* __restrict__ u, const int* __restrict__ gt,
      float* __restrict__ outPG, int* __restrict__ gtseg, int* __restrict__ Bk){
  __shared__ double smn[16], smx[16];
  __shared__ double sres[2];
  int t = threadIdx.x;
  double mn=1e300, mx=-1e300;
  for (int k=0;k<16;k++){ double x=u[k*1024+t]; mn=fmin(mn,x); mx=fmax(mx,x); }
  #pragma unroll
  for (int o=32;o;o>>=1){ mn=fmin(mn,__shfl_down(mn,o)); mx=fmax(mx,__shfl_down(mx,o)); }
  if ((t&63)==0){ smn[t>>6]=mn; smx[t>>6]=mx; }
  __syncthreads();
  if (t==0){
    for (int i=1;i<16;i++){ mn=fmin(mn,smn[i]); mx=fmax(mx,smx[i]); }
    sres[0]=mn; sres[1]=mx;
  }
  __syncthreads();
  mn=sres[0]; mx=sres[1];
  double inv = 1.0/(mx-mn);
  for (int k=0;k<16;k++){
    int n = k*1024 + t;
    int c0 = gt[k];
    double us = (u[n]-mn)*inv;
    int g = (us < 0.5) ? c0 : 200;
    outPG[n] = (float)g;
    gtseg[n] = g;
    unsigned long long b0 = __ballot(g==c0);
    unsigned long long b1 = __ballot(g==200);
    if ((t&63)==0){
      atomicAdd(&Bk[c0], (int)__popcll(b0));
      atomicAdd(&Bk[200], (int)__popcll(b1));
    }
  }
}

// ================= prep =================
__global__ __launch_bounds__(256) void kPrep(const float* __restrict__ Wp, _Float16* __restrict__ W16,
    const float* __restrict__ PR, float* __restrict__ Pn, _Float16* __restrict__ P16){
  int b = blockIdx.x;
  if (b < 384){
    int i = b*256 + threadIdx.x;
    float4 vv = ((const float4*)Wp)[i];
    half4v h; h[0]=(_Float16)vv.x; h[1]=(_Float16)vv.y; h[2]=(_Float16)vv.z; h[3]=(_Float16)vv.w;
    ((half4v*)W16)[i] = h;
    return;
  }
  int w=threadIdx.x>>6, lane=threadIdx.x&63;
  int km = (b-384)*4 + w;
  if (km >= KM){
    if (km < KMP){
      half8 z;
      #pragma unroll
      for (int i=0;i<8;i++) z[i]=(_Float16)0.0f;
      *(half8*)(P16 + (size_t)km*DD + lane*8) = z;
    }
    return;
  }
  const float* r = PR + (size_t)km*DD + lane*8;
  float4 a = *(const float4*)r, b2 = *(const float4*)(r+4);
  float x[8] = {a.x,a.y,a.z,a.w,b2.x,b2.y,b2.z,b2.w};
  float ss=0;
  #pragma unroll
  for (int i=0;i<8;i++) ss += x[i]*x[i];
  ss = __shfl(wredf(ss),0);
  float nrm = fmaxf(sqrtf(ss), 1e-12f);
  float* pw = Pn + (size_t)km*DD + lane*8;
  half8 h;
  #pragma unroll
  for (int i=0;i<8;i++){ float vv = x[i]/nrm; pw[i]=vv; h[i]=(_Float16)vv; }
  *(half8*)(P16 + (size_t)km*DD + lane*8) = h;
}

// ================= GEMM1 (R12 version, unchanged) =================
__global__ __launch_bounds__(256) void gemm1(const float* __restrict__ Af, const _Float16* __restrict__ Bm,
    _Float16* __restrict__ Ch, const float* __restrict__ bias){
  __shared__ __align__(16) char smem[32768];
  char* As = smem;
  char* Bs = smem + 16384;
  const int tid = threadIdx.x;
  const int lane = tid & 63, w = tid >> 6;
  const int wr = w >> 1, wc = w & 1;
  const int lrow = lane & 15, kg = lane >> 4;
  const int id = blockIdx.x;
  const int xcd = id & 7, pos = id >> 3;
  const int m0 = ((xcd<<4) | (pos>>2)) * 128;
  const int n0 = (pos & 3) * 128;

  f32x4 acc[4][4];
  #pragma unroll
  for (int i=0;i<4;i++)
    #pragma unroll
    for (int j=0;j<4;j++){ f32x4 z = {0.f,0.f,0.f,0.f}; acc[i][j]=z; }

  for (int k0 = 0; k0 < DBB; k0 += 64){
    #pragma unroll
    for (int i=0;i<4;i++){
      int slot = (i*4 + w)*64 + lane;
      int r = slot >> 3, c = slot & 7;
      int cs = c ^ (r & 7);
      GLDS16(Bm + (size_t)(n0+r)*DBB + k0 + cs*8, Bs + (i*4+w)*1024);
    }
    #pragma unroll
    for (int i=0;i<8;i++){
      int slot = i*256 + tid;
      int r = slot >> 4, c4 = slot & 15;
      float4 v = *(const float4*)(Af + (size_t)(m0+r)*DBB + k0 + c4*4);
      half4v h; h[0]=(_Float16)v.x; h[1]=(_Float16)v.y; h[2]=(_Float16)v.z; h[3]=(_Float16)v.w;
      *(half4v*)(As + r*128 + (((c4>>1)^(r&7))<<4) + (c4&1)*8) = h;
    }
    __syncthreads();
    #pragma unroll
    for (int h=0; h<2; h++){
      half8 af[4], bf[4];
      #pragma unroll
      for (int mi=0;mi<4;mi++){
        int ar = wr*64 + mi*16 + lrow;
        af[mi] = *(const half8*)(As + ar*128 + (((h*4+kg) ^ (ar&7))<<4));
      }
      #pragma unroll
      for (int nj=0;nj<4;nj++){
        int br = wc*64 + nj*16 + lrow;
        bf[nj] = *(const half8*)(Bs + br*128 + (((h*4+kg) ^ (br&7))<<4));
      }
      #pragma unroll
      for (int mi=0;mi<4;mi++)
        #pragma unroll
        for (int nj=0;nj<4;nj++)
          acc[mi][nj] = __builtin_amdgcn_mfma_f32_16x16x32_f16(af[mi], bf[nj], acc[mi][nj], 0,0,0);
    }
    __syncthreads();
  }
  _Float16* lsf = (_Float16*)smem;
  #pragma unroll
  for (int h=0; h<2; ++h){
    __syncthreads();
    if (wr == h){
      #pragma unroll
      for (int mi=0;mi<4;mi++){
        int lr = mi*16 + kg*4;
        #pragma unroll
        for (int nj=0;nj<4;nj++){
          int col = wc*64 + nj*16 + lrow;
          float bv = bias[n0 + col];
          #pragma unroll
          for (int r2=0;r2<4;r2++) lsf[(lr+r2)*136 + col] = (_Float16)(acc[mi][nj][r2] + bv);
        }
      }
    }
    __syncthreads();
    #pragma unroll
    for (int it=0; it<4; ++it){
      int idx = it*256 + tid;
      int row = idx >> 4, c8 = idx & 15;
      half8 v = *(const half8*)(lsf + row*136 + c8*8);
      *(half8*)(Ch + (size_t)(m0 + h*64 + row)*DD + n0 + c8*8) = v;
    }
  }
}

// ================= GEMM2: 256x256 tile, 8 waves, dbuf + early-issue staging (T1+T2+T3min+T5) ====
// PL[16384,2010] = _c @ protos^T ; fused class-max -> maxbuf.
// K-loop: stage(kt+1) into non-active buffer ISSUED BEFORE compute(kt); single
// __syncthreads per K-tile (drains vmcnt+lgkmcnt) -> loads fly under MFMA.
__global__ __launch_bounds__(512, 2) void gemm2(const _Float16* __restrict__ Am, const _Float16* __restrict__ Bm,
    float* __restrict__ Cf, unsigned int* __restrict__ maxbuf){
  __shared__ __align__(16) char lds[131072];   // [2 buf][A 32KB | B 32KB]
  const int tid = threadIdx.x;
  const int lane = tid & 63, wid = tid >> 6;   // 8 waves
  const int wr = wid >> 2, wc = wid & 3;       // 2 x 4
  const int lrow = lane & 15, kg = lane >> 4;
  const int id = blockIdx.x;
  const int nt = id & 7, mt = id >> 3;         // each XCD owns one 256-col B panel (L2-resident)
  const int m0 = mt * 256, n0 = nt * 256;

  f32x4 acc[8][4];
  #pragma unroll
  for (int i=0;i<8;i++)
    #pragma unroll
    for (int j=0;j<4;j++){ f32x4 z = {0.f,0.f,0.f,0.f}; acc[i][j]=z; }

  // ---- staging: whole 256x64 K-tile for A and B; linear LDS dest, pre-swizzled source ----
  #define STAGE2(kt, buf) { \
    int k0 = (kt)*64; \
    char* dA = lds + (buf)*65536; \
    char* dB = dA + 32768; \
    _Pragma("unroll") \
    for (int i=0;i<4;i++){ \
      int slot = i*512 + tid; \
      int r = slot >> 3, c = slot & 7; \
      int cs = c ^ (r & 7); \
      GLDS16(Am + (size_t)(m0+r)*DD + k0 + cs*8, dA + slot*16); \
      GLDS16(Bm + (size_t)(n0+r)*DD + k0 + cs*8, dB + slot*16); \
    } }

  STAGE2(0, 0);
  __syncthreads();
  for (int kt = 0; kt < 8; ++kt){
    if (kt < 7) STAGE2(kt+1, (kt+1)&1);
    const char* sA = lds + (kt&1)*65536;
    const char* sB = sA + 32768;
    __builtin_amdgcn_s_setprio(1);
    #pragma unroll
    for (int ks=0; ks<2; ks++){
      half8 bf[4];
      #pragma unroll
      for (int nj=0;nj<4;nj++){
        int br = wc*64 + nj*16 + lrow;
        bf[nj] = *(const half8*)(sB + br*128 + (((ks*4+kg) ^ (br&7))<<4));
      }
      #pragma unroll
      for (int mi=0;mi<8;mi++){
        int ar = wr*128 + mi*16 + lrow;
        half8 af = *(const half8*)(sA + ar*128 + (((ks*4+kg) ^ (ar&7))<<4));
        #pragma unroll
        for (int nj=0;nj<4;nj++)
          acc[mi][nj] = __builtin_amdgcn_mfma_f32_16x16x32_f16(af, bf[nj], acc[mi][nj], 0,0,0);
      }
    }
    __builtin_amdgcn_s_setprio(0);
    __syncthreads();   // drains vmcnt+lgkmcnt: buffer swap safe
  }
  #undef STAGE2

  // ---- epilogue: 4 rounds of 64 rows staged in LDS (stride 260 f32), coalesced PL + class-max ----
  float* lsf = (float*)lds;                    // 64*260*4 = 66560 B
  const int cLo = n0/10;
  int cHiA = (n0+255)/10; if (cHiA > 200) cHiA = 200;
  const int nC = cHiA - cLo + 1;
  for (int e=0; e<4; ++e){
    __syncthreads();
    if (wr == (e>>1)){
      int mbase = (e&1)*4;
      #pragma unroll
      for (int mq=0; mq<4; mq++){
        int lr = mq*16 + kg*4;
        #pragma unroll
        for (int nj=0;nj<4;nj++){
          int col = wc*64 + nj*16 + lrow;
          #pragma unroll
          for (int r2=0;r2<4;r2++)
            lsf[(lr+r2)*260 + col] = acc[mbase+mq][nj][r2];
        }
      }
    }
    __syncthreads();
    int grow0 = m0 + e*64;
    #pragma unroll
    for (int it=0; it<8; ++it){
      int idx = it*512 + tid;                 // 0..4095
      int row = idx >> 6, c4 = idx & 63;
      int gc = n0 + c4*4;
      if (gc < KM){
        f32x4 v = *(const f32x4*)(lsf + row*260 + c4*4);
        float* dstp = Cf + (size_t)(grow0+row)*KM + gc;
        if (gc + 3 < KM) *(f32x4*)dstp = v;
        else {
          #pragma unroll
          for (int e2=0;e2<4;e2++) if (gc+e2 < KM) dstp[e2] = v[e2];
        }
      }
    }
    for (int t = tid; t < 64*nC; t += 512){
      int row = t / nC, c = cLo + t % nC;
      int lo = c*10;     if (lo < n0) lo = n0;
      int hi = c*10+9;   if (hi > n0+255) hi = n0+255;
      float mx = lsf[row*260 + (lo-n0)];
      for (int cc2 = lo+1; cc2 <= hi; ++cc2) mx = fmaxf(mx, lsf[row*260 + (cc2-n0)]);
      atomicMax(&maxbuf[(size_t)(grow0+row)*KC + c], __float_as_uint(mx + 4.0f));
    }
  }
}

// ================= LN + l2 normalize (in-place on C16) =================
__global__ __launch_bounds__(256) void kLNl2n(_Float16* __restrict__ C16,
      const float* __restrict__ fg, const float* __restrict__ fb){
  int w=threadIdx.x>>6, lane=threadIdx.x&63;
  int n = blockIdx.x*4 + w;
  _Float16* row = C16 + (size_t)n*DD + lane*8;
  half8 h = *(const half8*)row;
  float x[8];
  #pragma unroll
  for (int i=0;i<8;i++) x[i] = (float)h[i];
  float s=0;
  #pragma unroll
  for (int i=0;i<8;i++) s += x[i];
  float mu = __shfl(wredf(s),0)/512.f;
  float q=0;
  #pragma unroll
  for (int i=0;i<8;i++){ float d=x[i]-mu; q+=d*d; }
  float var = __shfl(wredf(q),0)/512.f;
  float inv = 1.f/sqrtf(var+1e-5f);
  float4 g0 = *(const float4*)(fg+lane*8), g1 = *(const float4*)(fg+lane*8+4);
  float4 b0 = *(const float4*)(fb+lane*8), b1 = *(const float4*)(fb+lane*8+4);
  float gg[8] = {g0.x,g0.y,g0.z,g0.w,g1.x,g1.y,g1.z,g1.w};
  float bb[8] = {b0.x,b0.y,b0.z,b0.w,b1.x,b1.y,b1.z,b1.w};
  float y[8]; float ss=0;
  #pragma unroll
  for (int i=0;i<8;i++){ y[i] = (x[i]-mu)*inv*gg[i]+bb[i]; ss += y[i]*y[i]; }
  float nrm = fmaxf(sqrtf(__shfl(wredf(ss),0)), 1e-12f);
  half8 o;
  #pragma unroll
  for (int i=0;i<8;i++) o[i] = (_Float16)(y[i]/nrm);
  *(half8*)row = o;
}

// ===== per-class max (from maxbuf) + mask LN + pred + transpose-out + sinkhorn Qd/row0 =====
__global__ __launch_bounds__(256) void kMaxSK(const unsigned int* __restrict__ maxbuf,
    const float* __restrict__ PL, const float* __restrict__ mg,
    const float* __restrict__ mb, const int* __restrict__ gtseg, const int* __restrict__ gt,
    float* __restrict__ outseg, int* __restrict__ corr, float* __restrict__ Qd, float* __restrict__ row16){
  __shared__ float tile[16][205];
  __shared__ float qpart[10][2];
  int tid=threadIdx.x, lane=tid&63, w=tid>>6;
  int n0 = blockIdx.x*16;
  int b = n0>>10, hw0 = n0&1023;
  int c0 = gt[b];
  if (tid<20) qpart[tid>>1][tid&1]=0.f;
  __syncthreads();
  for (int r=0;r<16;r++){
    int n = n0 + r;
    int g = gtseg[n];
    if (tid < KC){
      tile[r][tid] = __uint_as_float(maxbuf[(size_t)n*KC + tid]) - 4.0f;
      if (tid == g){
        const float* src = PL + (size_t)n*KM + g*10;
        int cl = (g==200)?1:0;
        #pragma unroll
        for (int m2=0;m2<5;m2++){
          float2 t2 = *(const float2*)(src + m2*2);
          float e0 = expf(t2.x*20.f), e1 = expf(t2.y*20.f);
          Qd[(size_t)n*10+m2*2]   = e0;
          Qd[(size_t)n*10+m2*2+1] = e1;
          atomicAdd(&qpart[m2*2][cl], e0);
          atomicAdd(&qpart[m2*2+1][cl], e1);
        }
      }
    }
  }
  __syncthreads();
  for (int rr=0; rr<4; ++rr){
    int r = w*4 + rr;
    int n = n0 + r;
    float xv[4]; int ncl=0;
    for (int c=lane;c<KC;c+=64) xv[ncl++] = tile[r][c];
    float ps=0;
    for (int i=0;i<ncl;i++) ps += xv[i];
    float mu = __shfl(wredf(ps),0)*(1.f/201.f);
    float pv=0;
    for (int i=0;i<ncl;i++){ float d=xv[i]-mu; pv+=d*d; }
    float var = __shfl(wredf(pv),0)*(1.f/201.f);
    float inv = 1.f/sqrtf(var+1e-5f);
    float bv=-3.0e38f; int bi=1<<30;
    ncl=0;
    for (int c=lane;c<KC;c+=64){
      float o = (xv[ncl]-mu)*inv*mg[c]+mb[c]; ncl++;
      tile[r][c] = o;
      if (o>bv){ bv=o; bi=c; }
    }
    #pragma unroll
    for (int o2=32;o2;o2>>=1){
      float ov=__shfl_down(bv,o2); int oi=__shfl_down(bi,o2);
      if (ov>bv||(ov==bv&&oi<bi)){bv=ov;bi=oi;}
    }
    if (lane==0) corr[n] = (bi==gtseg[n])?1:0;
  }
  __syncthreads();
  if (tid<20){
    int m=tid>>1, cl=tid&1;
    atomicAdd(&row16[(size_t)(blockIdx.x&15)*2016 + m*KC + (cl?200:c0)], qpart[m][cl]);
  }
  for (int idx=tid; idx<KC*4; idx+=256){
    int c = idx>>2, j4 = idx&3;
    float4 v;
    v.x = tile[j4*4+0][c];
    v.y = tile[j4*4+1][c];
    v.z = tile[j4*4+2][c];
    v.w = tile[j4*4+3][c];
    *(float4*)(outseg + (((size_t)b*KC+c)<<10) + hw0 + j4*4) = v;
  }
}

// one sinkhorn iteration; rin has rin_parts partial buffers of stride 2016
__global__ __launch_bounds__(256) void kSKpass(float* __restrict__ Qd, const int* __restrict__ gtseg,
      const int* __restrict__ gt, const float* __restrict__ rin, int rin_parts,
      float* __restrict__ rout, const int* __restrict__ Bk){
  __shared__ float rin2[10][2];
  __shared__ double part[4][10][2];
  int n = blockIdx.x*256+threadIdx.x;
  int c0 = gt[blockIdx.x>>2];
  if (threadIdx.x < 20){
    int m = threadIdx.x>>1, cl = threadIdx.x&1;
    int cls = cl?200:c0;
    float s=0;
    for (int p=0;p<rin_parts;p++) s += rin[(size_t)p*2016 + m*KC + cls];
    rin2[m][cl]=s;
  }
  __syncthreads();
  int g = gtseg[n];
  int cl = (g==200)?1:0;
  double q[10]; double col=0.0;
  #pragma unroll
  for (int m=0;m<10;m++){
    double r = (double)rin2[m][cl];
    double t = (double)Qd[(size_t)n*10+m];
    if (r>0.0) t = t/r;
    t = t/10.0;
    q[m]=t; col+=t;
  }
  double cs = (col>0.0)? col : 1.0;
  int bk = Bk[g];
  double bs = (bk>0)? (double)bk : 1.0;
  double inv = 1.0/(cs*bs);
  int w=threadIdx.x>>6, lane=threadIdx.x&63;
  #pragma unroll
  for (int m=0;m<10;m++){
    double t = q[m]*inv;
    Qd[(size_t)n*10+m] = (float)t;
    double p0 = (g==c0)? t:0.0;
    double p1 = (g==200)? t:0.0;
    p0=wredd(p0); p1=wredd(p1);
    if (lane==0){ part[w][m][0]=p0; part[w][m][1]=p1; }
  }
  __syncthreads();
  if (threadIdx.x < 20){
    int m = threadIdx.x>>1, cl2 = threadIdx.x&1;
    double t = part[0][m][cl2]+part[1][m][cl2]+part[2][m][cl2]+part[3][m][cl2];
    atomicAdd(&rout[m*KC + (cl2?200:c0)], (float)t);
  }
}

// fused final argmax + proto_target write + EMA accumulation (wave per pixel)
__global__ __launch_bounds__(256) void kSKEMA(const float* __restrict__ Qd, const int* __restrict__ gtseg,
      const float* __restrict__ r5, const int* __restrict__ corr, const _Float16* __restrict__ C16,
      float* __restrict__ outPT, float* __restrict__ fproto, int* __restrict__ ncnt){
  int w=threadIdx.x>>6, lane=threadIdx.x&63;
  int n = blockIdx.x*4+w;
  int g = gtseg[n];
  float tv = -1.0f;
  if (lane<10){
    float r = r5[lane*KC+g];
    float t = Qd[(size_t)n*10+lane];
    if (r>0.f) t = t/r;
    tv = t*0.1f;
  }
  float bv = tv; int bi = lane;
  #pragma unroll
  for (int o=8;o;o>>=1){
    float ov = __shfl_down(bv,o); int oi = __shfl_down(bi,o);
    if (ov>bv || (ov==bv && oi<bi)){ bv=ov; bi=oi; }
  }
  bi = __shfl(bi, 0);
  if (lane==0) outPT[n] = (float)(bi + 10*g);
  if (corr[n]){
    half8 hc = *(const half8*)(C16 + (size_t)n*DD + lane*8);
    float* dst = fproto + ((size_t)g*10+bi)*DD + lane*8;
    #pragma unroll
    for (int i=0;i<8;i++) atomicAdd(dst+i, (float)hc[i]);
    if (lane==0) atomicAdd(&ncnt[g*10+bi], 1);
  }
}

__global__ __launch_bounds__(256) void kEMAfin(const float* __restrict__ fproto, const int* __restrict__ ncnt,
     const float* __restrict__ Pn, float* __restrict__ outNP){
  int w=threadIdx.x>>6, lane=threadIdx.x&63;
  int km = blockIdx.x*4+w;
  if (km>=KM) return;
  const float* fr = fproto + (size_t)km*DD + lane*8;
  float fp[8]; float ss=0;
  #pragma unroll
  for (int i=0;i<8;i++){ fp[i]=fr[i]; ss+=fp[i]*fp[i]; }
  float n1 = fmaxf(sqrtf(__shfl(wredf(ss),0)), 1e-12f);
  int cnt = ncnt[km];
  const float* pr = Pn + (size_t)km*DD + lane*8;
  float t[8]; float s2=0;
  #pragma unroll
  for (int i=0;i<8;i++){
    float pv = pr[i];
    float tv = cnt ? (0.999f*pv + 0.001f*(fp[i]/n1)) : pv;
    t[i]=tv; s2+=tv*tv;
  }
  float n2 = fmaxf(sqrtf(__shfl(wredf(s2),0)), 1e-12f);
  float* dst = outNP + (size_t)km*DD + lane*8;
  #pragma unroll
  for (int i=0;i<8;i++) dst[i] = t[i]/n2;
}

// ================= launch =================
extern "C" void kernel_launch(void* const* d_in, const int* in_sizes, int n_in,
                              void* d_out, int out_size, void* d_ws, size_t ws_size,
                              hipStream_t stream) {
  const float* A   = (const float*)d_in[0];
  const int*   gt  = (const int*)d_in[1];
  const float* Wp  = (const float*)d_in[2];
  const float* pb  = (const float*)d_in[3];
  const float* fg  = (const float*)d_in[4];
  const float* fb  = (const float*)d_in[5];
  const float* mg  = (const float*)d_in[6];
  const float* mb  = (const float*)d_in[7];
  const float* PR  = (const float*)d_in[8];
  float* out = (float*)d_out;
  char* ws = (char*)d_ws;

  double* xch    = (double*)(ws+OFF_XCH);
  double* Tp     = (double*)(ws+OFF_TP);
  double* colp   = (double*)(ws+OFF_COLP);
  float*  row16  = (float*)(ws+OFF_ROW16);
  float*  row3   = (float*)(ws+OFF_ROW3);
  float*  row5   = (float*)(ws+OFF_ROW5);
  int*    Bk     = (int*)(ws+OFF_BK);
  int*    ncnt   = (int*)(ws+OFF_NCNT);
  float*  fproto = (float*)(ws+OFF_FPROTO);
  unsigned int* maxbuf = (unsigned int*)(ws+OFF_MAXB);
  int*    gtseg  = (int*)(ws+OFF_GTSEG);
  int*    corr   = (int*)(ws+OFF_CORR);
  double* u      = (double*)(ws+OFF_U);
  float*  Pn     = (float*)(ws+OFF_PN);
  _Float16* P16  = (_Float16*)(ws+OFF_P16);
  _Float16* C16  = (_Float16*)(ws+OFF_C16);
  float*  Qd     = (float*)(ws+OFF_QD);
  _Float16* W16  = (_Float16*)(ws+OFF_W16);
  double* msf    = (double*)(ws+OFF_MSF);

  // single memset: all atomic accumulators + maxbuf
  hipMemsetAsync(ws, 0, ZTOTAL, stream);

  // ---- PCA pseudo-gt ----
  kPIter2<true><<<1024,256,0,stream>>>(A, nullptr, nullptr, nullptr, xch, Tp, colp);
  kRedM<<<1,256,0,stream>>>(colp, msf);
  for (int t=1;t<10;t++){
    kPIter2<false><<<1024,256,0,stream>>>(A, xch+(size_t)(t-1)*8*768, Tp+(t-1)*8, msf,
                                          xch+(size_t)t*8*768, Tp+t*8, nullptr);
  }
  kPU2<<<1024,256,0,stream>>>(A, xch+(size_t)9*8*768, Tp+9*8, msf, u);
  kFin<<<1,1024,0,stream>>>(u, gt, out+OUT_PG, gtseg, Bk);

  // ---- prep ----
  kPrep<<<896,256,0,stream>>>(Wp, W16, PR, Pn, P16);

  // ---- GEMM1 + LN+l2n ----
  gemm1<<<512,256,0,stream>>>(A, W16, C16, pb);
  kLNl2n<<<4096,256,0,stream>>>(C16, fg, fb);

  // ---- GEMM2 (256^2 dbuf early-issue) + fused class-max ----
  gemm2<<<512,512,0,stream>>>(C16, P16, out+OUT_PL, maxbuf);

  // ---- max/LN/pred/transpose + sinkhorn row0 ----
  kMaxSK<<<1024,256,0,stream>>>(maxbuf, out+OUT_PL, mg, mb, gtseg, gt, out+OUT_SEG, corr, Qd, row16);

  // ---- sinkhorn passes + fused argmax/EMA ----
  kSKpass<<<64,256,0,stream>>>(Qd, gtseg, gt, row16, 16, row3, Bk);
  kSKpass<<<64,256,0,stream>>>(Qd, gtseg, gt, row3, 1, row5, Bk);
  kSKEMA<<<4096,256,0,stream>>>(Qd, gtseg, row5, corr, C16, out+OUT_PT, fproto, ncnt);

  // ---- EMA finalize ----
  kEMAfin<<<503,256,0,stream>>>(fproto, ncnt, Pn, out+OUT_NP);
}